// Round 15
// baseline (998.575 us; speedup 1.0000x reference)
//
#include <hip/hip_runtime.h>
#include <cstdint>
#include <cstddef>

#define NN 50000
#define EE 500000
#define NPART 1024
#define NTILE 31250   // EE/16

typedef unsigned short ushort_t;
typedef __attribute__((ext_vector_type(8))) short short8;
typedef __attribute__((ext_vector_type(4))) float f32x4;
typedef __attribute__((ext_vector_type(4))) unsigned short us4;

__device__ __forceinline__ ushort_t f2bf(float f) {
    unsigned u = __float_as_uint(f);
    unsigned r = (u + 0x7fffu + ((u >> 16) & 1u)) >> 16;
    return (ushort_t)r;
}
__device__ __forceinline__ float bf2f(ushort_t b) {
    return __uint_as_float(((unsigned)b) << 16);
}

// ---------------- workspace layout (float offsets) ----------------
static constexpr size_t NF   = (size_t)NN * 64;
static constexpr size_t OQ   = 0;                          // q   NF
static constexpr size_t OKV  = OQ   + NF;                  // kv  2*NF ([node][128] interleaved)
static constexpr size_t OSK  = OKV  + 2 * NF;              // sk  NF
static constexpr size_t OBA  = OSK  + NF;
static constexpr size_t OBB  = OBA  + NF;
static constexpr size_t ORP  = OBB  + NF;                  // rp EE
static constexpr size_t OPART= ORP  + (size_t)EE;          // 1024*2 doubles
static constexpr size_t OSTF = OPART+ 4096;                // statsf 2 floats
static constexpr size_t OBN  = OSTF + 2;                   // bn sums 128 floats
static constexpr size_t OI   = OBN  + 128;                 // int area
static constexpr size_t ODEG = OI;                         // NN
static constexpr size_t OOFF = ODEG + NN;                  // NN+2
static constexpr size_t OCNT = OOFF + NN + 2;              // NN
static constexpr size_t OPOS = OCNT + NN;                  // EE
static constexpr size_t ORL  = OPOS + (size_t)EE;          // EE
static constexpr size_t OES  = ORL  + (size_t)EE;          // e_srt bf16: EE*64 ushorts, [slot][col][j]

__device__ __forceinline__ void gemv64(const float (&xv)[64],
                                       const float* __restrict__ W,
                                       const float* __restrict__ b,
                                       float* __restrict__ dst) {
    for (int jch = 0; jch < 4; ++jch) {
        float ov[16];
#pragma unroll
        for (int jj = 0; jj < 16; ++jj) ov[jj] = b[jch * 16 + jj];
#pragma unroll
        for (int kk = 0; kk < 64; ++kk) {
            float xk = xv[kk];
            const float* wr = W + kk * 64 + jch * 16;
#pragma unroll
            for (int jj = 0; jj < 16; ++jj) ov[jj] = fmaf(xk, wr[jj], ov[jj]);
        }
        float4* pd = reinterpret_cast<float4*>(dst + jch * 16);
        pd[0] = make_float4(ov[0], ov[1], ov[2], ov[3]);
        pd[1] = make_float4(ov[4], ov[5], ov[6], ov[7]);
        pd[2] = make_float4(ov[8], ov[9], ov[10], ov[11]);
        pd[3] = make_float4(ov[12], ov[13], ov[14], ov[15]);
    }
}

__device__ __forceinline__ void gemv64_s2(const float (&xv)[64],
                                          const float* __restrict__ W,
                                          const float* __restrict__ b,
                                          float* __restrict__ dst) {
    for (int jch = 0; jch < 4; ++jch) {
        float ov[16];
#pragma unroll
        for (int jj = 0; jj < 16; ++jj) ov[jj] = b[jch * 16 + jj];
#pragma unroll
        for (int kk = 0; kk < 64; ++kk) {
            float xk = xv[kk];
            const float* wr = W + kk * 64 + jch * 16;
#pragma unroll
            for (int jj = 0; jj < 16; ++jj) ov[jj] = fmaf(xk, wr[jj], ov[jj]);
        }
#pragma unroll
        for (int jj = 0; jj < 16; ++jj) dst[(jch * 16 + jj) * 2] = ov[jj];
    }
}

// ---------------- rp: wave-per-8-edges, row-coalesced loads ----------------
__global__ __launch_bounds__(256) void k_rp(const float* __restrict__ x,
                                            const int* __restrict__ ei,
                                            float* __restrict__ rp,
                                            double* __restrict__ partial) {
    int tid = threadIdx.x;
    int lane = tid & 63;
    int wid = tid >> 6;
    size_t wgid = (size_t)blockIdx.x * 4 + wid;
    size_t nw = (size_t)gridDim.x * 4;
    double c1 = 0.0, c2 = 0.0;
    for (size_t e0 = wgid * 8; e0 < (size_t)EE; e0 += nw * 8) {
        float rvs = 0.f;
#pragma unroll
        for (int j = 0; j < 8; ++j) {
            int r = __builtin_amdgcn_readfirstlane(ei[e0 + j]);
            int c = __builtin_amdgcn_readfirstlane(ei[EE + e0 + j]);
            float a = x[(size_t)r * 64 + lane];
            float b = x[(size_t)c * 64 + lane];
            float d = a - b;
            float ss = d * d;
            ss += __shfl_xor(ss, 1);  ss += __shfl_xor(ss, 2);
            ss += __shfl_xor(ss, 4);  ss += __shfl_xor(ss, 8);
            ss += __shfl_xor(ss, 16); ss += __shfl_xor(ss, 32);
            float rv = sqrtf(ss);
            c1 += (double)rv; c2 += (double)rv * (double)rv;
            rvs = (lane == j) ? rv : rvs;
        }
        if (lane < 8) rp[e0 + lane] = rvs;
    }
    __shared__ double l1[4], l2[4];
    if (lane == 0) { l1[wid] = c1; l2[wid] = c2; }
    __syncthreads();
    if (tid == 0) {
        partial[blockIdx.x * 2]     = l1[0] + l1[1] + l1[2] + l1[3];
        partial[blockIdx.x * 2 + 1] = l2[0] + l2[1] + l2[2] + l2[3];
    }
}

__global__ __launch_bounds__(256) void k_statsf(const double* __restrict__ partial,
                                                float* __restrict__ statsf) {
    __shared__ double l1[256], l2[256];
    int tid = threadIdx.x;
    double a = 0.0, b = 0.0;
    for (int i = tid; i < NPART; i += 256) { a += partial[2 * i]; b += partial[2 * i + 1]; }
    l1[tid] = a; l2[tid] = b;
    __syncthreads();
    for (int o = 128; o > 0; o >>= 1) {
        if (tid < o) { l1[tid] += l1[tid + o]; l2[tid] += l2[tid + o]; }
        __syncthreads();
    }
    if (tid == 0) {
        double s = l1[0], q = l2[0];
        double mean = s / (double)EE;
        double var = (q - (double)EE * mean * mean) / (double)(EE - 1);
        if (var < 0) var = 0;
        statsf[0] = (float)mean;
        statsf[1] = (float)(1.0 / (sqrt(var) + 1e-6));
    }
}

// ---------------- edge-encoder MLP via MFMA, 2 tiles/wave, dedicated H buffer ----------------
__device__ __forceinline__ short8 frag_rd(const ushort_t* __restrict__ s, int nc, int k0) {
    int sidx = (nc * 64 + k0) ^ ((nc & 7) << 3);
    return *reinterpret_cast<const short8*>(&s[sidx]);
}

__global__ __launch_bounds__(256) void k_mlp(const float* __restrict__ ea,
                                             const float* __restrict__ W1, const float* __restrict__ b1,
                                             const float* __restrict__ W2, const float* __restrict__ b2,
                                             const float* __restrict__ rp, const float* __restrict__ statsf,
                                             const int* __restrict__ pos,
                                             float* __restrict__ eout,
                                             ushort_t* __restrict__ es) {
    __shared__ __align__(16) ushort_t sW1h[4096], sW1l[4096], sW2h[4096], sW2l[4096];
    __shared__ __align__(16) ushort_t sH[4][1024];
    int tid = threadIdx.x;
    for (int i = tid; i < 4096; i += 256) {
        int k = i >> 6, nc = i & 63;
        int sidx = (nc * 64 + k) ^ ((nc & 7) << 3);
        float v1 = W1[i];
        ushort_t h1 = f2bf(v1); sW1h[sidx] = h1; sW1l[sidx] = f2bf(v1 - bf2f(h1));
        float v2 = W2[i];
        ushort_t h2 = f2bf(v2); sW2h[sidx] = h2; sW2l[sidx] = f2bf(v2 - bf2f(h2));
    }
    __syncthreads();

    int lane = tid & 63;
    int wid = tid >> 6;
    int col = lane & 15, kg = lane >> 4;
    float mean = statsf[0], inv = statsf[1];
    ushort_t* myH = sH[wid];

#pragma unroll 1
    for (int it = 0; it < 2; ++it) {
        int t = blockIdx.x * 8 + wid * 2 + it;
        if (t >= NTILE) continue;

        const float* ar = ea + (size_t)(t * 16 + col) * 64 + kg * 8;
        f32x4 f0 = *reinterpret_cast<const f32x4*>(ar);
        f32x4 f1 = *reinterpret_cast<const f32x4*>(ar + 4);
        f32x4 f2 = *reinterpret_cast<const f32x4*>(ar + 32);
        f32x4 f3 = *reinterpret_cast<const f32x4*>(ar + 36);
        short8 a0h, a0l, a1h, a1l;
#pragma unroll
        for (int j = 0; j < 4; ++j) {
            ushort_t h;
            h = f2bf(f0[j]); a0h[j]     = (short)h; a0l[j]     = (short)f2bf(f0[j] - bf2f(h));
            h = f2bf(f1[j]); a0h[4 + j] = (short)h; a0l[4 + j] = (short)f2bf(f1[j] - bf2f(h));
            h = f2bf(f2[j]); a1h[j]     = (short)h; a1l[j]     = (short)f2bf(f2[j] - bf2f(h));
            h = f2bf(f3[j]); a1h[4 + j] = (short)h; a1l[4 + j] = (short)f2bf(f3[j] - bf2f(h));
        }

        // stage 1: h = relu(e @ W1 + b1) -> Hh only (bf16) in dedicated LDS
#pragma unroll
        for (int n = 0; n < 4; ++n) {
            int nc = n * 16 + col;
            short8 b0h = frag_rd(sW1h, nc, kg * 8);
            short8 b0l = frag_rd(sW1l, nc, kg * 8);
            short8 b1h_ = frag_rd(sW1h, nc, 32 + kg * 8);
            short8 b1l_ = frag_rd(sW1l, nc, 32 + kg * 8);
            f32x4 acc = {0.f, 0.f, 0.f, 0.f};
            acc = __builtin_amdgcn_mfma_f32_16x16x32_bf16(a0h, b0h, acc, 0, 0, 0);
            acc = __builtin_amdgcn_mfma_f32_16x16x32_bf16(a0l, b0h, acc, 0, 0, 0);
            acc = __builtin_amdgcn_mfma_f32_16x16x32_bf16(a0h, b0l, acc, 0, 0, 0);
            acc = __builtin_amdgcn_mfma_f32_16x16x32_bf16(a1h, b1h_, acc, 0, 0, 0);
            acc = __builtin_amdgcn_mfma_f32_16x16x32_bf16(a1l, b1h_, acc, 0, 0, 0);
            acc = __builtin_amdgcn_mfma_f32_16x16x32_bf16(a1h, b1l_, acc, 0, 0, 0);
            float bv = b1[n * 16 + col];
#pragma unroll
            for (int r = 0; r < 4; ++r) {
                float hv = fmaxf(acc[r] + bv, 0.f);
                int row = kg * 4 + r;
                int sidx = (row * 64 + n * 16 + col) ^ ((row & 7) << 3);
                myH[sidx] = f2bf(hv);
            }
        }
        // same-wave LDS write->read
        short8 c0h = frag_rd(myH, col, kg * 8);
        short8 c1h = frag_rd(myH, col, 32 + kg * 8);

        float rps[4];
        int posr[4];
#pragma unroll
        for (int r = 0; r < 4; ++r) {
            rps[r] = (rp[t * 16 + kg * 4 + r] - mean) * inv;
            posr[r] = pos[t * 16 + kg * 4 + r];
        }

        float vals[4][4];
#pragma unroll
        for (int n = 0; n < 4; ++n) {
            int nc = n * 16 + col;
            short8 b0h = frag_rd(sW2h, nc, kg * 8);
            short8 b0l = frag_rd(sW2l, nc, kg * 8);
            short8 b1h_ = frag_rd(sW2h, nc, 32 + kg * 8);
            short8 b1l_ = frag_rd(sW2l, nc, 32 + kg * 8);
            f32x4 acc = {0.f, 0.f, 0.f, 0.f};
            acc = __builtin_amdgcn_mfma_f32_16x16x32_bf16(c0h, b0h, acc, 0, 0, 0);
            acc = __builtin_amdgcn_mfma_f32_16x16x32_bf16(c0h, b0l, acc, 0, 0, 0);
            acc = __builtin_amdgcn_mfma_f32_16x16x32_bf16(c1h, b1h_, acc, 0, 0, 0);
            acc = __builtin_amdgcn_mfma_f32_16x16x32_bf16(c1h, b1l_, acc, 0, 0, 0);
            float bv = b2[nc];
#pragma unroll
            for (int r = 0; r < 4; ++r) {
                float val = acc[r] + bv + rps[r];
                vals[n][r] = val;
                eout[(size_t)(t * 16 + kg * 4 + r) * 64 + nc] = val;
            }
        }
#pragma unroll
        for (int r = 0; r < 4; ++r) {
            us4 w;
            w[0] = f2bf(vals[0][r]); w[1] = f2bf(vals[1][r]);
            w[2] = f2bf(vals[2][r]); w[3] = f2bf(vals[3][r]);
            *reinterpret_cast<us4*>(es + (size_t)posr[r] * 64 + col * 4) = w;
        }
    }
}

// ---------------- CSR build ----------------
__global__ void k_zint(int* deg, int* cnt) {
    int i = blockIdx.x * 256 + threadIdx.x;
    if (i < NN) { deg[i] = 0; cnt[i] = 0; }
}

__global__ void k_deg(const int* __restrict__ ei, int* __restrict__ deg) {
    int e = blockIdx.x * 256 + threadIdx.x;
    if (e < EE) atomicAdd(&deg[ei[EE + e]], 1);
}

__global__ __launch_bounds__(1024) void k_scan(const int* __restrict__ deg, int* __restrict__ off) {
    __shared__ int part[1024];
    int t = threadIdx.x;
    const int chunk = (NN + 1023) / 1024;
    int lo = t * chunk, hi = min(lo + chunk, NN);
    int s = 0;
    for (int i = lo; i < hi; ++i) s += deg[i];
    part[t] = s;
    __syncthreads();
    for (int o = 1; o < 1024; o <<= 1) {
        int v = (t >= o) ? part[t - o] : 0;
        __syncthreads();
        part[t] += v;
        __syncthreads();
    }
    int base = (t == 0) ? 0 : part[t - 1];
    for (int i = lo; i < hi; ++i) { off[i] = base; base += deg[i]; }
    if (t == 0) off[NN] = EE;
}

__global__ void k_scatter(const int* __restrict__ ei, const int* __restrict__ off,
                          int* __restrict__ cnt, int* __restrict__ pos, int* __restrict__ rlist) {
    int e = blockIdx.x * 256 + threadIdx.x;
    if (e >= EE) return;
    int r = ei[e], c = ei[EE + e];
    int p = off[c] + atomicAdd(&cnt[c], 1);
    pos[e] = p;
    rlist[p] = r;
}

// ---------------- node-side GEMVs ----------------
__global__ __launch_bounds__(256) void k_node(const float* __restrict__ xin,
                                              const float* __restrict__ Wq, const float* __restrict__ bq,
                                              const float* __restrict__ Wk, const float* __restrict__ bk,
                                              const float* __restrict__ Wv, const float* __restrict__ bv,
                                              const float* __restrict__ Wsk, const float* __restrict__ bsk,
                                              float* __restrict__ q, float* __restrict__ kvb,
                                              float* __restrict__ sk) {
    int lane = threadIdx.x & 63;
    int w = __builtin_amdgcn_readfirstlane(threadIdx.x >> 6);
    size_t node = (size_t)blockIdx.x * 64 + lane;
    if (node >= (size_t)NN) return;
    float xv[64];
    const float4* px = reinterpret_cast<const float4*>(xin + node * 64);
#pragma unroll
    for (int i = 0; i < 16; ++i) {
        float4 t = px[i];
        xv[4 * i] = t.x; xv[4 * i + 1] = t.y; xv[4 * i + 2] = t.z; xv[4 * i + 3] = t.w;
    }
    if (w == 0)      gemv64(xv, Wq, bq, q + node * 64);
    else if (w == 1) gemv64_s2(xv, Wk, bk, kvb + node * 128);
    else if (w == 2) gemv64_s2(xv, Wv, bv, kvb + node * 128 + 1);
    else             gemv64(xv, Wsk, bsk, sk + node * 64);
}

// ---------------- fused per-destination attention: 16 nodes/block (4/wave, unroll 1) ----------------
__global__ __launch_bounds__(256) void k_edge(const int* __restrict__ off,
                                              const int* __restrict__ rlist,
                                              const ushort_t* __restrict__ es,
                                              const float* __restrict__ Wep,
                                              const float* __restrict__ q,
                                              const float* __restrict__ kvb,
                                              const float* __restrict__ skp,
                                              float* __restrict__ outb) {
    __shared__ float sWT[64 * 65];
    __shared__ float sA[4][264];
    int tid = threadIdx.x;
    for (int i = tid; i < 4096; i += 256) {
        int kr = i >> 6, kc = i & 63;
        sWT[kc * 65 + kr] = Wep[i];
    }
    __syncthreads();

    int lane = tid & 63;
    int wid = tid >> 6;
    int col = lane & 15, hs = lane >> 4, hb = lane & 48;
    const float THR = 8.f;
    float* myA = sA[wid];
    const float* wl = sWT + (size_t)lane * 65;

#pragma unroll 1
    for (int ni = 0; ni < 4; ++ni) {
        size_t node = (size_t)blockIdx.x * 16 + wid * 4 + ni;   // grid exact: NN/16

        float qv = q[node * 64 + lane];
        float t0 = 0.f, t1 = 0.f, t2 = 0.f, t3 = 0.f;
#pragma unroll
        for (int d = 0; d < 16; ++d) {
            float qd = __shfl(qv, hb + d);
            const float* wp = sWT + (hb + d) * 65 + col;
            t0 = fmaf(wp[0],  qd, t0);
            t1 = fmaf(wp[16], qd, t1);
            t2 = fmaf(wp[32], qd, t2);
            t3 = fmaf(wp[48], qd, t3);
        }

        int p0 = __builtin_amdgcn_readfirstlane(off[node]);
        int p1 = __builtin_amdgcn_readfirstlane(off[node + 1]);
        float m = -INFINITY, s = 0.f, o = 0.f;
        float A0 = 0.f, A1 = 0.f, A2 = 0.f, A3 = 0.f;

        int p = p0;
        for (; p + 8 <= p1; p += 8) {
            int rx[8];
#pragma unroll
            for (int j = 0; j < 8; ++j) rx[j] = __builtin_amdgcn_readfirstlane(rlist[p + j]);
            us4 ew[8];
            float2 kvp[8];
#pragma unroll
            for (int j = 0; j < 8; ++j) {
                ew[j] = *reinterpret_cast<const us4*>(es + (size_t)(p + j) * 64 + col * 4);
                kvp[j] = *reinterpret_cast<const float2*>(kvb + (size_t)rx[j] * 128 + lane * 2);
            }
            float er0[8], er1[8], er2[8], er3[8], al[8];
#pragma unroll
            for (int j = 0; j < 8; ++j) {
                er0[j] = bf2f(ew[j][0]); er1[j] = bf2f(ew[j][1]);
                er2[j] = bf2f(ew[j][2]); er3[j] = bf2f(ew[j][3]);
                float d = qv * kvp[j].x;
                d = fmaf(er0[j], t0, d); d = fmaf(er1[j], t1, d);
                d = fmaf(er2[j], t2, d); d = fmaf(er3[j], t3, d);
                d += __shfl_xor(d, 1); d += __shfl_xor(d, 2);
                d += __shfl_xor(d, 4); d += __shfl_xor(d, 8);
                al[j] = d * 0.25f;
            }
            float bm = fmaxf(fmaxf(fmaxf(al[0], al[1]), fmaxf(al[2], al[3])),
                             fmaxf(fmaxf(al[4], al[5]), fmaxf(al[6], al[7])));
            if (m == -INFINITY) m = bm;
            else if (bm > m + THR) {
                float sc = __expf(m - bm);
                s *= sc; o *= sc;
                A0 *= sc; A1 *= sc; A2 *= sc; A3 *= sc;
                m = bm;
            }
#pragma unroll
            for (int j = 0; j < 8; ++j) {
                float pe = __expf(al[j] - m);
                s += pe;
                o = fmaf(pe, kvp[j].y, o);
                A0 = fmaf(pe, er0[j], A0);
                A1 = fmaf(pe, er1[j], A1);
                A2 = fmaf(pe, er2[j], A2);
                A3 = fmaf(pe, er3[j], A3);
            }
        }
        for (; p < p1; ++p) {
            us4 ew = *reinterpret_cast<const us4*>(es + (size_t)p * 64 + col * 4);
            int rxx = __builtin_amdgcn_readfirstlane(rlist[p]);
            float2 kvp = *reinterpret_cast<const float2*>(kvb + (size_t)rxx * 128 + lane * 2);
            float e0 = bf2f(ew[0]), e1 = bf2f(ew[1]), e2 = bf2f(ew[2]), e3 = bf2f(ew[3]);
            float d = qv * kvp.x;
            d = fmaf(e0, t0, d); d = fmaf(e1, t1, d);
            d = fmaf(e2, t2, d); d = fmaf(e3, t3, d);
            d += __shfl_xor(d, 1); d += __shfl_xor(d, 2);
            d += __shfl_xor(d, 4); d += __shfl_xor(d, 8);
            float aa = d * 0.25f;
            if (m == -INFINITY) m = aa;
            else if (aa > m + THR) {
                float sc = __expf(m - aa);
                s *= sc; o *= sc;
                A0 *= sc; A1 *= sc; A2 *= sc; A3 *= sc;
                m = aa;
            }
            float pe = __expf(aa - m);
            s += pe;
            o = fmaf(pe, kvp.y, o);
            A0 = fmaf(pe, e0, A0);
            A1 = fmaf(pe, e1, A1);
            A2 = fmaf(pe, e2, A2);
            A3 = fmaf(pe, e3, A3);
        }

        // epilogue (same-wave LDS only; sequential reuse of myA is ordered by lgkmcnt)
        myA[hs * 65 + col]      = A0;
        myA[hs * 65 + 16 + col] = A1;
        myA[hs * 65 + 32 + col] = A2;
        myA[hs * 65 + 48 + col] = A3;
        const float* Ah = myA + hs * 65;
        float e0 = 0.f, e1 = 0.f, e2 = 0.f, e3 = 0.f;
#pragma unroll
        for (int kk = 0; kk < 64; kk += 4) {
            e0 = fmaf(Ah[kk],     wl[kk],     e0);
            e1 = fmaf(Ah[kk + 1], wl[kk + 1], e1);
            e2 = fmaf(Ah[kk + 2], wl[kk + 2], e2);
            e3 = fmaf(Ah[kk + 3], wl[kk + 3], e3);
        }
        float ex = (e0 + e1) + (e2 + e3);
        outb[node * 64 + lane] = (o + ex) / (s + 1e-16f) + skp[node * 64 + lane];
    }
}

// ---------------- BN stats + BN/ReLU/residual/LN ----------------
__global__ void k_zbn(float* bn) {
    if (threadIdx.x < 128) bn[threadIdx.x] = 0.f;
}

__global__ __launch_bounds__(256) void k_bnstat(const float* __restrict__ conv, float* __restrict__ bn) {
    int tid = threadIdx.x;
    size_t idx0 = (size_t)blockIdx.x * 256 + tid;
    size_t stride = (size_t)gridDim.x * 256;
    float s = 0.f, ss = 0.f;
    for (size_t i = idx0; i < NF; i += stride) {
        float val = conv[i];
        s += val; ss += val * val;
    }
    __shared__ float l1[256], l2[256];
    l1[tid] = s; l2[tid] = ss;
    __syncthreads();
    if (tid < 64) {
        float a = l1[tid] + l1[tid + 64] + l1[tid + 128] + l1[tid + 192];
        float b = l2[tid] + l2[tid + 64] + l2[tid + 128] + l2[tid + 192];
        atomicAdd(bn + tid, a);
        atomicAdd(bn + 64 + tid, b);
    }
}

__global__ __launch_bounds__(256) void k_bnln(const float* __restrict__ conv,
                                              const float* __restrict__ xres,
                                              const float* __restrict__ bn,
                                              const float* __restrict__ g, const float* __restrict__ b,
                                              const float* __restrict__ lg, const float* __restrict__ lb,
                                              float* __restrict__ xout) {
    int tid = threadIdx.x;
    int lane = tid & 63;
    size_t row = (size_t)blockIdx.x * 4 + (tid >> 6);
    if (row >= (size_t)NN) return;
    float val = conv[row * 64 + lane];
    float mu = bn[lane] * (1.f / NN);
    float var = bn[64 + lane] * (1.f / NN) - mu * mu;
    float hn = (val - mu) * rsqrtf(var + 1e-5f) * g[lane] + b[lane];
    hn = fmaxf(hn, 0.f);
    float t = hn + xres[row * 64 + lane];
    float s = t, ss = t * t;
#pragma unroll
    for (int o = 32; o >= 1; o >>= 1) { s += __shfl_xor(s, o); ss += __shfl_xor(ss, o); }
    float mu2 = s * (1.f / 64.f);
    float var2 = ss * (1.f / 64.f) - mu2 * mu2;
    xout[row * 64 + lane] = (t - mu2) * rsqrtf(var2 + 1e-5f) * lg[lane] + lb[lane];
}

// ---------------- launch ----------------
extern "C" void kernel_launch(void* const* d_in, const int* in_sizes, int n_in,
                              void* d_out, int out_size, void* d_ws, size_t ws_size,
                              hipStream_t stream) {
    (void)in_sizes; (void)n_in; (void)out_size; (void)ws_size;
    const float* x   = (const float*)d_in[0];
    const int*   ei  = (const int*)d_in[1];
    const float* ea  = (const float*)d_in[2];
    const float* Wq  = (const float*)d_in[3];  const float* bq = (const float*)d_in[4];
    const float* Wk  = (const float*)d_in[5];  const float* bk = (const float*)d_in[6];
    const float* Wv  = (const float*)d_in[7];  const float* bv = (const float*)d_in[8];
    const float* We  = (const float*)d_in[9];
    const float* Wsk = (const float*)d_in[10]; const float* bsk = (const float*)d_in[11];
    const float* eW1 = (const float*)d_in[12]; const float* eb1 = (const float*)d_in[13];
    const float* eW2 = (const float*)d_in[14]; const float* eb2 = (const float*)d_in[15];
    const float* bng = (const float*)d_in[16]; const float* bnb = (const float*)d_in[17];
    const float* lng = (const float*)d_in[18]; const float* lnb = (const float*)d_in[19];

    float* ws = (float*)d_ws;
    float* out_x = (float*)d_out;
    float* out_e = out_x + NF;

    float* q    = ws + OQ;
    float* kvb  = ws + OKV;
    float* sk   = ws + OSK;
    float* bufA = ws + OBA;
    float* bufB = ws + OBB;
    float* rp   = ws + ORP;
    double* partial = (double*)(ws + OPART);
    float* statsf   = ws + OSTF;
    float* bn   = ws + OBN;
    int* deg  = (int*)(ws + ODEG);
    int* off  = (int*)(ws + OOFF);
    int* cnt  = (int*)(ws + OCNT);
    int* pos  = (int*)(ws + OPOS);
    int* rlist= (int*)(ws + ORL);
    ushort_t* es = (ushort_t*)(ws + OES);

    // CSR build first (pos needed by k_mlp)
    k_zint<<<(NN + 255) / 256, 256, 0, stream>>>(deg, cnt);
    k_deg<<<(EE + 255) / 256, 256, 0, stream>>>(ei, deg);
    k_scan<<<1, 1024, 0, stream>>>(deg, off);
    k_scatter<<<(EE + 255) / 256, 256, 0, stream>>>(ei, off, cnt, pos, rlist);

    k_rp<<<NPART, 256, 0, stream>>>(x, ei, rp, partial);
    k_statsf<<<1, 256, 0, stream>>>(partial, statsf);
    k_mlp<<<(NTILE + 7) / 8, 256, 0, stream>>>(ea, eW1, eb1, eW2, eb2, rp, statsf, pos, out_e, es);

    const float* xin = x;
    for (int l = 0; l < 3; ++l) {
        k_node<<<(NN + 63) / 64, 256, 0, stream>>>(xin,
            Wq + (size_t)l * 4096, bq + (size_t)l * 64,
            Wk + (size_t)l * 4096, bk + (size_t)l * 64,
            Wv + (size_t)l * 4096, bv + (size_t)l * 64,
            Wsk + (size_t)l * 4096, bsk + (size_t)l * 64,
            q, kvb, sk);
        float* conv = (l == 2) ? out_x : sk;   // in-place skip add (same-element RMW only)
        k_edge<<<NN / 16, 256, 0, stream>>>(off, rlist, es,
            We + (size_t)l * 4096, q, kvb, sk, conv);
        if (l < 2) {
            k_zbn<<<1, 128, 0, stream>>>(bn);
            k_bnstat<<<1024, 256, 0, stream>>>(conv, bn);
            float* xout = (l == 0) ? bufA : bufB;
            k_bnln<<<(NN + 3) / 4, 256, 0, stream>>>(conv, xin, bn,
                bng + (size_t)l * 64, bnb + (size_t)l * 64,
                lng + (size_t)l * 64, lnb + (size_t)l * 64, xout);
            xin = xout;
        }
    }
}

// Round 17
// 850.076 us; speedup vs baseline: 1.1747x; 1.1747x over previous
//
#include <hip/hip_runtime.h>
#include <cstdint>
#include <cstddef>

#define NN 50000
#define EE 500000
#define NPART 1024
#define NTILE 31250   // EE/16

typedef unsigned short ushort_t;
typedef __attribute__((ext_vector_type(8))) short short8;
typedef __attribute__((ext_vector_type(4))) float f32x4;
typedef __attribute__((ext_vector_type(4))) unsigned short us4;

__device__ __forceinline__ ushort_t f2bf(float f) {
    unsigned u = __float_as_uint(f);
    unsigned r = (u + 0x7fffu + ((u >> 16) & 1u)) >> 16;
    return (ushort_t)r;
}
__device__ __forceinline__ float bf2f(ushort_t b) {
    return __uint_as_float(((unsigned)b) << 16);
}

// ---------------- workspace layout (float offsets) ----------------
static constexpr size_t NF   = (size_t)NN * 64;
static constexpr size_t OQ   = 0;                          // q   NF
static constexpr size_t OKV  = OQ   + NF;                  // kv  2*NF ([node][128] interleaved: 2d=k_d, 2d+1=v_d)
static constexpr size_t OSK  = OKV  + 2 * NF;              // sk  NF
static constexpr size_t OBA  = OSK  + NF;
static constexpr size_t OBB  = OBA  + NF;
static constexpr size_t ORP  = OBB  + NF;                  // rp EE
static constexpr size_t OPART= ORP  + (size_t)EE;          // 1024*2 doubles
static constexpr size_t OSTF = OPART+ 4096;                // statsf 2 floats
static constexpr size_t OBN  = OSTF + 2;                   // bn sums 128 floats
static constexpr size_t OI   = OBN  + 128;                 // int area
static constexpr size_t ODEG = OI;                         // NN
static constexpr size_t OOFF = ODEG + NN;                  // NN+2
static constexpr size_t OCNT = OOFF + NN + 2;              // NN
static constexpr size_t OPOS = OCNT + NN;                  // EE (pos[e] -> csr slot)
static constexpr size_t ORL  = OPOS + (size_t)EE;          // EE (rlist[slot] -> src row)
static constexpr size_t OES  = ORL  + (size_t)EE;          // e_srt bf16: EE*64 ushorts, [slot][col][j]

__device__ __forceinline__ void gemv64(const float (&xv)[64],
                                       const float* __restrict__ W,
                                       const float* __restrict__ b,
                                       float* __restrict__ dst) {
    for (int jch = 0; jch < 4; ++jch) {
        float ov[16];
#pragma unroll
        for (int jj = 0; jj < 16; ++jj) ov[jj] = b[jch * 16 + jj];
#pragma unroll
        for (int kk = 0; kk < 64; ++kk) {
            float xk = xv[kk];
            const float* wr = W + kk * 64 + jch * 16;
#pragma unroll
            for (int jj = 0; jj < 16; ++jj) ov[jj] = fmaf(xk, wr[jj], ov[jj]);
        }
        float4* pd = reinterpret_cast<float4*>(dst + jch * 16);
        pd[0] = make_float4(ov[0], ov[1], ov[2], ov[3]);
        pd[1] = make_float4(ov[4], ov[5], ov[6], ov[7]);
        pd[2] = make_float4(ov[8], ov[9], ov[10], ov[11]);
        pd[3] = make_float4(ov[12], ov[13], ov[14], ov[15]);
    }
}

__device__ __forceinline__ void gemv64_s2(const float (&xv)[64],
                                          const float* __restrict__ W,
                                          const float* __restrict__ b,
                                          float* __restrict__ dst) {
    for (int jch = 0; jch < 4; ++jch) {
        float ov[16];
#pragma unroll
        for (int jj = 0; jj < 16; ++jj) ov[jj] = b[jch * 16 + jj];
#pragma unroll
        for (int kk = 0; kk < 64; ++kk) {
            float xk = xv[kk];
            const float* wr = W + kk * 64 + jch * 16;
#pragma unroll
            for (int jj = 0; jj < 16; ++jj) ov[jj] = fmaf(xk, wr[jj], ov[jj]);
        }
#pragma unroll
        for (int jj = 0; jj < 16; ++jj) dst[(jch * 16 + jj) * 2] = ov[jj];
    }
}

// ---------------- rp: wave-per-8-edges, row-coalesced loads ----------------
__global__ __launch_bounds__(256) void k_rp(const float* __restrict__ x,
                                            const int* __restrict__ ei,
                                            float* __restrict__ rp,
                                            double* __restrict__ partial) {
    int tid = threadIdx.x;
    int lane = tid & 63;
    int wid = tid >> 6;
    size_t wgid = (size_t)blockIdx.x * 4 + wid;
    size_t nw = (size_t)gridDim.x * 4;
    double c1 = 0.0, c2 = 0.0;
    for (size_t e0 = wgid * 8; e0 < (size_t)EE; e0 += nw * 8) {   // EE % 8 == 0
        float rvs = 0.f;
#pragma unroll
        for (int j = 0; j < 8; ++j) {
            int r = __builtin_amdgcn_readfirstlane(ei[e0 + j]);
            int c = __builtin_amdgcn_readfirstlane(ei[EE + e0 + j]);
            float a = x[(size_t)r * 64 + lane];
            float b = x[(size_t)c * 64 + lane];
            float d = a - b;
            float ss = d * d;
            ss += __shfl_xor(ss, 1);  ss += __shfl_xor(ss, 2);
            ss += __shfl_xor(ss, 4);  ss += __shfl_xor(ss, 8);
            ss += __shfl_xor(ss, 16); ss += __shfl_xor(ss, 32);
            float rv = sqrtf(ss);
            c1 += (double)rv; c2 += (double)rv * (double)rv;
            rvs = (lane == j) ? rv : rvs;
        }
        if (lane < 8) rp[e0 + lane] = rvs;
    }
    __shared__ double l1[4], l2[4];
    if (lane == 0) { l1[wid] = c1; l2[wid] = c2; }
    __syncthreads();
    if (tid == 0) {
        partial[blockIdx.x * 2]     = l1[0] + l1[1] + l1[2] + l1[3];
        partial[blockIdx.x * 2 + 1] = l2[0] + l2[1] + l2[2] + l2[3];
    }
}

__global__ __launch_bounds__(256) void k_statsf(const double* __restrict__ partial,
                                                float* __restrict__ statsf) {
    __shared__ double l1[256], l2[256];
    int tid = threadIdx.x;
    double a = 0.0, b = 0.0;
    for (int i = tid; i < NPART; i += 256) { a += partial[2 * i]; b += partial[2 * i + 1]; }
    l1[tid] = a; l2[tid] = b;
    __syncthreads();
    for (int o = 128; o > 0; o >>= 1) {
        if (tid < o) { l1[tid] += l1[tid + o]; l2[tid] += l2[tid + o]; }
        __syncthreads();
    }
    if (tid == 0) {
        double s = l1[0], q = l2[0];
        double mean = s / (double)EE;
        double var = (q - (double)EE * mean * mean) / (double)(EE - 1);
        if (var < 0) var = 0;
        statsf[0] = (float)mean;
        statsf[1] = (float)(1.0 / (sqrt(var) + 1e-6));
    }
}

// ---------------- edge-encoder MLP via MFMA (hi/lo bf16 split ~= fp32) ----------------
// LDS: 32 KB — H overlays W1's region after a barrier (W1 dead post-stage-1).
__device__ __forceinline__ short8 frag_rd(const ushort_t* __restrict__ s, int nc, int k0) {
    int sidx = (nc * 64 + k0) ^ ((nc & 7) << 3);   // XOR swizzle (bank-conflict-free)
    return *reinterpret_cast<const short8*>(&s[sidx]);
}

__global__ __launch_bounds__(256) void k_mlp(const float* __restrict__ ea,
                                             const float* __restrict__ W1, const float* __restrict__ b1,
                                             const float* __restrict__ W2, const float* __restrict__ b2,
                                             const float* __restrict__ rp, const float* __restrict__ statsf,
                                             const int* __restrict__ pos,
                                             float* __restrict__ eout,
                                             ushort_t* __restrict__ es) {
    __shared__ __align__(16) ushort_t sW1h[4096], sW1l[4096], sW2h[4096], sW2l[4096];
    int tid = threadIdx.x;
    for (int i = tid; i < 4096; i += 256) {
        int k = i >> 6, nc = i & 63;
        int sidx = (nc * 64 + k) ^ ((nc & 7) << 3);
        float v1 = W1[i];
        ushort_t h1 = f2bf(v1); sW1h[sidx] = h1; sW1l[sidx] = f2bf(v1 - bf2f(h1));
        float v2 = W2[i];
        ushort_t h2 = f2bf(v2); sW2h[sidx] = h2; sW2l[sidx] = f2bf(v2 - bf2f(h2));
    }
    __syncthreads();

    int lane = tid & 63;
    int wid = tid >> 6;
    int col = lane & 15, kg = lane >> 4;
    int t = blockIdx.x * 4 + wid;
    bool act = t < NTILE;

    float hvals[4][4];   // [n][r] post-ReLU stage-1 results
    if (act) {
        const float* ar = ea + (size_t)(t * 16 + col) * 64 + kg * 8;
        f32x4 f0 = *reinterpret_cast<const f32x4*>(ar);
        f32x4 f1 = *reinterpret_cast<const f32x4*>(ar + 4);
        f32x4 f2 = *reinterpret_cast<const f32x4*>(ar + 32);
        f32x4 f3 = *reinterpret_cast<const f32x4*>(ar + 36);
        short8 a0h, a0l, a1h, a1l;
#pragma unroll
        for (int j = 0; j < 4; ++j) {
            ushort_t h;
            h = f2bf(f0[j]); a0h[j]     = (short)h; a0l[j]     = (short)f2bf(f0[j] - bf2f(h));
            h = f2bf(f1[j]); a0h[4 + j] = (short)h; a0l[4 + j] = (short)f2bf(f1[j] - bf2f(h));
            h = f2bf(f2[j]); a1h[j]     = (short)h; a1l[j]     = (short)f2bf(f2[j] - bf2f(h));
            h = f2bf(f3[j]); a1h[4 + j] = (short)h; a1l[4 + j] = (short)f2bf(f3[j] - bf2f(h));
        }
#pragma unroll
        for (int n = 0; n < 4; ++n) {
            int nc = n * 16 + col;
            short8 b0h = frag_rd(sW1h, nc, kg * 8);
            short8 b0l = frag_rd(sW1l, nc, kg * 8);
            short8 b1h_ = frag_rd(sW1h, nc, 32 + kg * 8);
            short8 b1l_ = frag_rd(sW1l, nc, 32 + kg * 8);
            f32x4 acc = {0.f, 0.f, 0.f, 0.f};
            acc = __builtin_amdgcn_mfma_f32_16x16x32_bf16(a0h, b0h, acc, 0, 0, 0);
            acc = __builtin_amdgcn_mfma_f32_16x16x32_bf16(a0l, b0h, acc, 0, 0, 0);
            acc = __builtin_amdgcn_mfma_f32_16x16x32_bf16(a0h, b0l, acc, 0, 0, 0);
            acc = __builtin_amdgcn_mfma_f32_16x16x32_bf16(a1h, b1h_, acc, 0, 0, 0);
            acc = __builtin_amdgcn_mfma_f32_16x16x32_bf16(a1l, b1h_, acc, 0, 0, 0);
            acc = __builtin_amdgcn_mfma_f32_16x16x32_bf16(a1h, b1l_, acc, 0, 0, 0);
            float bv = b1[n * 16 + col];
#pragma unroll
            for (int r = 0; r < 4; ++r) hvals[n][r] = fmaxf(acc[r] + bv, 0.f);
        }
    }
    __syncthreads();   // all waves done reading W1 -> overlay H

    if (!act) return;
    ushort_t* myHh = sW1h + wid * 1024;
    ushort_t* myHl = sW1l + wid * 1024;
#pragma unroll
    for (int n = 0; n < 4; ++n) {
        int nc = n * 16 + col;
#pragma unroll
        for (int r = 0; r < 4; ++r) {
            float hv = hvals[n][r];
            ushort_t hh = f2bf(hv);
            int row = kg * 4 + r;
            int sidx = (row * 64 + nc) ^ ((row & 7) << 3);
            myHh[sidx] = hh;
            myHl[sidx] = f2bf(hv - bf2f(hh));
        }
    }
    // same-wave LDS write->read (lgkmcnt orders; own region only)
    short8 c0h = frag_rd(myHh, col, kg * 8);
    short8 c0l = frag_rd(myHl, col, kg * 8);
    short8 c1h = frag_rd(myHh, col, 32 + kg * 8);
    short8 c1l = frag_rd(myHl, col, 32 + kg * 8);

    float mean = statsf[0], inv = statsf[1];
    float rps[4];
    int posr[4];
#pragma unroll
    for (int r = 0; r < 4; ++r) {
        rps[r] = (rp[t * 16 + kg * 4 + r] - mean) * inv;
        posr[r] = pos[t * 16 + kg * 4 + r];
    }

    float vals[4][4];   // vals[n][r]
#pragma unroll
    for (int n = 0; n < 4; ++n) {
        int nc = n * 16 + col;
        short8 b0h = frag_rd(sW2h, nc, kg * 8);
        short8 b0l = frag_rd(sW2l, nc, kg * 8);
        short8 b1h_ = frag_rd(sW2h, nc, 32 + kg * 8);
        short8 b1l_ = frag_rd(sW2l, nc, 32 + kg * 8);
        f32x4 acc = {0.f, 0.f, 0.f, 0.f};
        acc = __builtin_amdgcn_mfma_f32_16x16x32_bf16(c0h, b0h, acc, 0, 0, 0);
        acc = __builtin_amdgcn_mfma_f32_16x16x32_bf16(c0l, b0h, acc, 0, 0, 0);
        acc = __builtin_amdgcn_mfma_f32_16x16x32_bf16(c0h, b0l, acc, 0, 0, 0);
        acc = __builtin_amdgcn_mfma_f32_16x16x32_bf16(c1h, b1h_, acc, 0, 0, 0);
        acc = __builtin_amdgcn_mfma_f32_16x16x32_bf16(c1l, b1h_, acc, 0, 0, 0);
        acc = __builtin_amdgcn_mfma_f32_16x16x32_bf16(c1h, b1l_, acc, 0, 0, 0);
        float bv = b2[nc];
#pragma unroll
        for (int r = 0; r < 4; ++r) {
            float val = acc[r] + bv + rps[r];
            vals[n][r] = val;
            eout[(size_t)(t * 16 + kg * 4 + r) * 64 + nc] = val;
        }
    }
#pragma unroll
    for (int r = 0; r < 4; ++r) {
        us4 w;
        w[0] = f2bf(vals[0][r]); w[1] = f2bf(vals[1][r]);
        w[2] = f2bf(vals[2][r]); w[3] = f2bf(vals[3][r]);
        *reinterpret_cast<us4*>(es + (size_t)posr[r] * 64 + col * 4) = w;
    }
}

// ---------------- CSR build ----------------
__global__ void k_zint(int* deg, int* cnt) {
    int i = blockIdx.x * 256 + threadIdx.x;
    if (i < NN) { deg[i] = 0; cnt[i] = 0; }
}

__global__ void k_deg(const int* __restrict__ ei, int* __restrict__ deg) {
    int e = blockIdx.x * 256 + threadIdx.x;
    if (e < EE) atomicAdd(&deg[ei[EE + e]], 1);
}

__global__ __launch_bounds__(1024) void k_scan(const int* __restrict__ deg, int* __restrict__ off) {
    __shared__ int part[1024];
    int t = threadIdx.x;
    const int chunk = (NN + 1023) / 1024;
    int lo = t * chunk, hi = min(lo + chunk, NN);
    int s = 0;
    for (int i = lo; i < hi; ++i) s += deg[i];
    part[t] = s;
    __syncthreads();
    for (int o = 1; o < 1024; o <<= 1) {
        int v = (t >= o) ? part[t - o] : 0;
        __syncthreads();
        part[t] += v;
        __syncthreads();
    }
    int base = (t == 0) ? 0 : part[t - 1];
    for (int i = lo; i < hi; ++i) { off[i] = base; base += deg[i]; }
    if (t == 0) off[NN] = EE;
}

__global__ void k_scatter(const int* __restrict__ ei, const int* __restrict__ off,
                          int* __restrict__ cnt, int* __restrict__ pos, int* __restrict__ rlist) {
    int e = blockIdx.x * 256 + threadIdx.x;
    if (e >= EE) return;
    int r = ei[e], c = ei[EE + e];
    int p = off[c] + atomicAdd(&cnt[c], 1);
    pos[e] = p;
    rlist[p] = r;
}

// ---------------- node-side GEMVs: one wave = one matrix for 64 nodes ----------------
__global__ __launch_bounds__(256) void k_node(const float* __restrict__ xin,
                                              const float* __restrict__ Wq, const float* __restrict__ bq,
                                              const float* __restrict__ Wk, const float* __restrict__ bk,
                                              const float* __restrict__ Wv, const float* __restrict__ bv,
                                              const float* __restrict__ Wsk, const float* __restrict__ bsk,
                                              float* __restrict__ q, float* __restrict__ kvb,
                                              float* __restrict__ sk) {
    int lane = threadIdx.x & 63;
    int w = __builtin_amdgcn_readfirstlane(threadIdx.x >> 6);
    size_t node = (size_t)blockIdx.x * 64 + lane;
    if (node >= (size_t)NN) return;
    float xv[64];
    const float4* px = reinterpret_cast<const float4*>(xin + node * 64);
#pragma unroll
    for (int i = 0; i < 16; ++i) {
        float4 t = px[i];
        xv[4 * i] = t.x; xv[4 * i + 1] = t.y; xv[4 * i + 2] = t.z; xv[4 * i + 3] = t.w;
    }
    if (w == 0)      gemv64(xv, Wq, bq, q + node * 64);
    else if (w == 1) gemv64_s2(xv, Wk, bk, kvb + node * 128);        // k at even offsets
    else if (w == 2) gemv64_s2(xv, Wv, bv, kvb + node * 128 + 1);    // v at odd offsets
    else             gemv64(xv, Wsk, bsk, sk + node * 64);
}

// ---------------- fused per-destination attention (LDS-staged We, no epilogue barrier) ----------------
__global__ __launch_bounds__(256) void k_edge(const int* __restrict__ off,
                                              const int* __restrict__ rlist,
                                              const ushort_t* __restrict__ es,
                                              const float* __restrict__ Wep,
                                              const float* __restrict__ q,
                                              const float* __restrict__ kvb,
                                              const float* __restrict__ skp,
                                              float* __restrict__ outb) {
    __shared__ float sWT[64 * 65];   // sWT[kc*65+kr] = We[kr][kc]
    __shared__ float sA[4][264];
    int tid = threadIdx.x;
    for (int i = tid; i < 4096; i += 256) {
        int kr = i >> 6, kc = i & 63;
        sWT[kc * 65 + kr] = Wep[i];
    }
    __syncthreads();

    int lane = tid & 63;
    int wid = tid >> 6;
    int col = lane & 15, hs = lane >> 4, hb = lane & 48;
    size_t node = (size_t)blockIdx.x * 4 + wid;

    float qv = q[node * 64 + lane];
    float t0 = 0.f, t1 = 0.f, t2 = 0.f, t3 = 0.f;
#pragma unroll
    for (int d = 0; d < 16; ++d) {
        float qd = __shfl(qv, hb + d);
        const float* wp = sWT + (hb + d) * 65 + col;
        t0 = fmaf(wp[0],  qd, t0);
        t1 = fmaf(wp[16], qd, t1);
        t2 = fmaf(wp[32], qd, t2);
        t3 = fmaf(wp[48], qd, t3);
    }

    int p0 = __builtin_amdgcn_readfirstlane(off[node]);
    int p1 = __builtin_amdgcn_readfirstlane(off[node + 1]);
    float m = -INFINITY, s = 0.f, o = 0.f;
    float A0 = 0.f, A1 = 0.f, A2 = 0.f, A3 = 0.f;
    const float THR = 8.f;

    int p = p0;
    for (; p + 8 <= p1; p += 8) {
        int rx[8];
#pragma unroll
        for (int j = 0; j < 8; ++j) rx[j] = __builtin_amdgcn_readfirstlane(rlist[p + j]);
        us4 ew[8];
        float2 kvp[8];
#pragma unroll
        for (int j = 0; j < 8; ++j) {
            ew[j] = *reinterpret_cast<const us4*>(es + (size_t)(p + j) * 64 + col * 4);
            kvp[j] = *reinterpret_cast<const float2*>(kvb + (size_t)rx[j] * 128 + lane * 2);
        }
        float er0[8], er1[8], er2[8], er3[8], al[8];
#pragma unroll
        for (int j = 0; j < 8; ++j) {
            er0[j] = bf2f(ew[j][0]); er1[j] = bf2f(ew[j][1]);
            er2[j] = bf2f(ew[j][2]); er3[j] = bf2f(ew[j][3]);
            float d = qv * kvp[j].x;
            d = fmaf(er0[j], t0, d); d = fmaf(er1[j], t1, d);
            d = fmaf(er2[j], t2, d); d = fmaf(er3[j], t3, d);
            d += __shfl_xor(d, 1); d += __shfl_xor(d, 2);
            d += __shfl_xor(d, 4); d += __shfl_xor(d, 8);
            al[j] = d * 0.25f;
        }
        float bm = fmaxf(fmaxf(fmaxf(al[0], al[1]), fmaxf(al[2], al[3])),
                         fmaxf(fmaxf(al[4], al[5]), fmaxf(al[6], al[7])));
        if (m == -INFINITY) m = bm;
        else if (bm > m + THR) {
            float sc = __expf(m - bm);
            s *= sc; o *= sc;
            A0 *= sc; A1 *= sc; A2 *= sc; A3 *= sc;
            m = bm;
        }
#pragma unroll
        for (int j = 0; j < 8; ++j) {
            float pe = __expf(al[j] - m);
            s += pe;
            o = fmaf(pe, kvp[j].y, o);
            A0 = fmaf(pe, er0[j], A0);
            A1 = fmaf(pe, er1[j], A1);
            A2 = fmaf(pe, er2[j], A2);
            A3 = fmaf(pe, er3[j], A3);
        }
    }
    for (; p < p1; ++p) {
        us4 ew = *reinterpret_cast<const us4*>(es + (size_t)p * 64 + col * 4);
        int rxx = __builtin_amdgcn_readfirstlane(rlist[p]);
        float2 kvp = *reinterpret_cast<const float2*>(kvb + (size_t)rxx * 128 + lane * 2);
        float e0 = bf2f(ew[0]), e1 = bf2f(ew[1]), e2 = bf2f(ew[2]), e3 = bf2f(ew[3]);
        float d = qv * kvp.x;
        d = fmaf(e0, t0, d); d = fmaf(e1, t1, d);
        d = fmaf(e2, t2, d); d = fmaf(e3, t3, d);
        d += __shfl_xor(d, 1); d += __shfl_xor(d, 2);
        d += __shfl_xor(d, 4); d += __shfl_xor(d, 8);
        float aa = d * 0.25f;
        if (m == -INFINITY) m = aa;
        else if (aa > m + THR) {
            float sc = __expf(m - aa);
            s *= sc; o *= sc;
            A0 *= sc; A1 *= sc; A2 *= sc; A3 *= sc;
            m = aa;
        }
        float pe = __expf(aa - m);
        s += pe;
        o = fmaf(pe, kvp.y, o);
        A0 = fmaf(pe, e0, A0);
        A1 = fmaf(pe, e1, A1);
        A2 = fmaf(pe, e2, A2);
        A3 = fmaf(pe, e3, A3);
    }

    // epilogue (same-wave LDS only): ex[l] = sum_k A_{hs}[k] * We[k][l]
    float* myA = sA[wid];
    myA[hs * 65 + col]      = A0;
    myA[hs * 65 + 16 + col] = A1;
    myA[hs * 65 + 32 + col] = A2;
    myA[hs * 65 + 48 + col] = A3;
    const float* Ah = myA + hs * 65;
    const float* wl = sWT + (size_t)lane * 65;
    float e0 = 0.f, e1 = 0.f, e2 = 0.f, e3 = 0.f;
#pragma unroll
    for (int kk = 0; kk < 64; kk += 4) {
        e0 = fmaf(Ah[kk],     wl[kk],     e0);
        e1 = fmaf(Ah[kk + 1], wl[kk + 1], e1);
        e2 = fmaf(Ah[kk + 2], wl[kk + 2], e2);
        e3 = fmaf(Ah[kk + 3], wl[kk + 3], e3);
    }
    float ex = (e0 + e1) + (e2 + e3);
    outb[node * 64 + lane] = (o + ex) / (s + 1e-16f) + skp[node * 64 + lane];
}

// ---------------- BN stats + BN/ReLU/residual/LN ----------------
__global__ void k_zbn(float* bn) {
    if (threadIdx.x < 128) bn[threadIdx.x] = 0.f;
}

__global__ __launch_bounds__(256) void k_bnstat(const float* __restrict__ conv, float* __restrict__ bn) {
    int tid = threadIdx.x;
    size_t idx0 = (size_t)blockIdx.x * 256 + tid;
    size_t stride = (size_t)gridDim.x * 256;
    float s = 0.f, ss = 0.f;
    for (size_t i = idx0; i < NF; i += stride) {
        float val = conv[i];
        s += val; ss += val * val;
    }
    __shared__ float l1[256], l2[256];
    l1[tid] = s; l2[tid] = ss;
    __syncthreads();
    if (tid < 64) {
        float a = l1[tid] + l1[tid + 64] + l1[tid + 128] + l1[tid + 192];
        float b = l2[tid] + l2[tid + 64] + l2[tid + 128] + l2[tid + 192];
        atomicAdd(bn + tid, a);
        atomicAdd(bn + 64 + tid, b);
    }
}

__global__ __launch_bounds__(256) void k_bnln(const float* __restrict__ conv,
                                              const float* __restrict__ xres,
                                              const float* __restrict__ bn,
                                              const float* __restrict__ g, const float* __restrict__ b,
                                              const float* __restrict__ lg, const float* __restrict__ lb,
                                              float* __restrict__ xout) {
    int tid = threadIdx.x;
    int lane = tid & 63;
    size_t row = (size_t)blockIdx.x * 4 + (tid >> 6);
    if (row >= (size_t)NN) return;
    float val = conv[row * 64 + lane];
    float mu = bn[lane] * (1.f / NN);
    float var = bn[64 + lane] * (1.f / NN) - mu * mu;
    float hn = (val - mu) * rsqrtf(var + 1e-5f) * g[lane] + b[lane];
    hn = fmaxf(hn, 0.f);
    float t = hn + xres[row * 64 + lane];
    float s = t, ss = t * t;
#pragma unroll
    for (int o = 32; o >= 1; o >>= 1) { s += __shfl_xor(s, o); ss += __shfl_xor(ss, o); }
    float mu2 = s * (1.f / 64.f);
    float var2 = ss * (1.f / 64.f) - mu2 * mu2;
    xout[row * 64 + lane] = (t - mu2) * rsqrtf(var2 + 1e-5f) * lg[lane] + lb[lane];
}

// ---------------- launch ----------------
extern "C" void kernel_launch(void* const* d_in, const int* in_sizes, int n_in,
                              void* d_out, int out_size, void* d_ws, size_t ws_size,
                              hipStream_t stream) {
    (void)in_sizes; (void)n_in; (void)out_size; (void)ws_size;
    const float* x   = (const float*)d_in[0];
    const int*   ei  = (const int*)d_in[1];
    const float* ea  = (const float*)d_in[2];
    const float* Wq  = (const float*)d_in[3];  const float* bq = (const float*)d_in[4];
    const float* Wk  = (const float*)d_in[5];  const float* bk = (const float*)d_in[6];
    const float* Wv  = (const float*)d_in[7];  const float* bv = (const float*)d_in[8];
    const float* We  = (const float*)d_in[9];
    const float* Wsk = (const float*)d_in[10]; const float* bsk = (const float*)d_in[11];
    const float* eW1 = (const float*)d_in[12]; const float* eb1 = (const float*)d_in[13];
    const float* eW2 = (const float*)d_in[14]; const float* eb2 = (const float*)d_in[15];
    const float* bng = (const float*)d_in[16]; const float* bnb = (const float*)d_in[17];
    const float* lng = (const float*)d_in[18]; const float* lnb = (const float*)d_in[19];

    float* ws = (float*)d_ws;
    float* out_x = (float*)d_out;
    float* out_e = out_x + NF;

    float* q    = ws + OQ;
    float* kvb  = ws + OKV;
    float* sk   = ws + OSK;
    float* bufA = ws + OBA;
    float* bufB = ws + OBB;
    float* rp   = ws + ORP;
    double* partial = (double*)(ws + OPART);
    float* statsf   = ws + OSTF;
    float* bn   = ws + OBN;
    int* deg  = (int*)(ws + ODEG);
    int* off  = (int*)(ws + OOFF);
    int* cnt  = (int*)(ws + OCNT);
    int* pos  = (int*)(ws + OPOS);
    int* rlist= (int*)(ws + ORL);
    ushort_t* es = (ushort_t*)(ws + OES);

    // CSR build first (pos needed by k_mlp)
    k_zint<<<(NN + 255) / 256, 256, 0, stream>>>(deg, cnt);
    k_deg<<<(EE + 255) / 256, 256, 0, stream>>>(ei, deg);
    k_scan<<<1, 1024, 0, stream>>>(deg, off);
    k_scatter<<<(EE + 255) / 256, 256, 0, stream>>>(ei, off, cnt, pos, rlist);

    k_rp<<<NPART, 256, 0, stream>>>(x, ei, rp, partial);
    k_statsf<<<1, 256, 0, stream>>>(partial, statsf);
    k_mlp<<<(NTILE + 3) / 4, 256, 0, stream>>>(ea, eW1, eb1, eW2, eb2, rp, statsf, pos, out_e, es);

    const float* xin = x;
    for (int l = 0; l < 3; ++l) {
        k_node<<<(NN + 63) / 64, 256, 0, stream>>>(xin,
            Wq + (size_t)l * 4096, bq + (size_t)l * 64,
            Wk + (size_t)l * 4096, bk + (size_t)l * 64,
            Wv + (size_t)l * 4096, bv + (size_t)l * 64,
            Wsk + (size_t)l * 4096, bsk + (size_t)l * 64,
            q, kvb, sk);
        float* conv = (l == 2) ? out_x : sk;   // in-place skip add (same-element RMW only)
        k_edge<<<NN / 4, 256, 0, stream>>>(off, rlist, es,
            We + (size_t)l * 4096, q, kvb, sk, conv);
        if (l < 2) {
            k_zbn<<<1, 128, 0, stream>>>(bn);
            k_bnstat<<<1024, 256, 0, stream>>>(conv, bn);
            float* xout = (l == 0) ? bufA : bufB;
            k_bnln<<<(NN + 3) / 4, 256, 0, stream>>>(conv, xin, bn,
                bng + (size_t)l * 64, bnb + (size_t)l * 64,
                lng + (size_t)l * 64, lnb + (size_t)l * 64, xout);
            xin = xout;
        }
    }
}

// Round 18
// 728.906 us; speedup vs baseline: 1.3700x; 1.1662x over previous
//
#include <hip/hip_runtime.h>
#include <cstdint>
#include <cstddef>

#define NN 50000
#define EE 500000
#define NPART 1024
#define NTILE 31250   // EE/16
#define NODETILE 3125 // NN/16

typedef unsigned short ushort_t;
typedef __attribute__((ext_vector_type(8))) short short8;
typedef __attribute__((ext_vector_type(4))) float f32x4;
typedef __attribute__((ext_vector_type(4))) unsigned short us4;

__device__ __forceinline__ ushort_t f2bf(float f) {
    unsigned u = __float_as_uint(f);
    unsigned r = (u + 0x7fffu + ((u >> 16) & 1u)) >> 16;
    return (ushort_t)r;
}
__device__ __forceinline__ float bf2f(ushort_t b) {
    return __uint_as_float(((unsigned)b) << 16);
}

// ---------------- workspace layout (float offsets) ----------------
static constexpr size_t NF   = (size_t)NN * 64;
static constexpr size_t OQ   = 0;
static constexpr size_t OKV  = OQ   + NF;                  // kv 2*NF ([node][128] interleaved)
static constexpr size_t OSK  = OKV  + 2 * NF;
static constexpr size_t OBA  = OSK  + NF;
static constexpr size_t OBB  = OBA  + NF;
static constexpr size_t ORP  = OBB  + NF;
static constexpr size_t OPART= ORP  + (size_t)EE;
static constexpr size_t OSTF = OPART+ 4096;
static constexpr size_t OBN  = OSTF + 2;
static constexpr size_t OI   = OBN  + 128;
static constexpr size_t ODEG = OI;
static constexpr size_t OOFF = ODEG + NN;
static constexpr size_t OCNT = OOFF + NN + 2;
static constexpr size_t OPOS = OCNT + NN;
static constexpr size_t ORL  = OPOS + (size_t)EE;
static constexpr size_t OES  = ORL  + (size_t)EE;

// ---------------- rp ----------------
__global__ __launch_bounds__(256) void k_rp(const float* __restrict__ x,
                                            const int* __restrict__ ei,
                                            float* __restrict__ rp,
                                            double* __restrict__ partial) {
    int tid = threadIdx.x;
    int lane = tid & 63;
    int wid = tid >> 6;
    size_t wgid = (size_t)blockIdx.x * 4 + wid;
    size_t nw = (size_t)gridDim.x * 4;
    double c1 = 0.0, c2 = 0.0;
    for (size_t e0 = wgid * 8; e0 < (size_t)EE; e0 += nw * 8) {
        float rvs = 0.f;
#pragma unroll
        for (int j = 0; j < 8; ++j) {
            int r = __builtin_amdgcn_readfirstlane(ei[e0 + j]);
            int c = __builtin_amdgcn_readfirstlane(ei[EE + e0 + j]);
            float a = x[(size_t)r * 64 + lane];
            float b = x[(size_t)c * 64 + lane];
            float d = a - b;
            float ss = d * d;
            ss += __shfl_xor(ss, 1);  ss += __shfl_xor(ss, 2);
            ss += __shfl_xor(ss, 4);  ss += __shfl_xor(ss, 8);
            ss += __shfl_xor(ss, 16); ss += __shfl_xor(ss, 32);
            float rv = sqrtf(ss);
            c1 += (double)rv; c2 += (double)rv * (double)rv;
            rvs = (lane == j) ? rv : rvs;
        }
        if (lane < 8) rp[e0 + lane] = rvs;
    }
    __shared__ double l1[4], l2[4];
    if (lane == 0) { l1[wid] = c1; l2[wid] = c2; }
    __syncthreads();
    if (tid == 0) {
        partial[blockIdx.x * 2]     = l1[0] + l1[1] + l1[2] + l1[3];
        partial[blockIdx.x * 2 + 1] = l2[0] + l2[1] + l2[2] + l2[3];
    }
}

__global__ __launch_bounds__(256) void k_statsf(const double* __restrict__ partial,
                                                float* __restrict__ statsf) {
    __shared__ double l1[256], l2[256];
    int tid = threadIdx.x;
    double a = 0.0, b = 0.0;
    for (int i = tid; i < NPART; i += 256) { a += partial[2 * i]; b += partial[2 * i + 1]; }
    l1[tid] = a; l2[tid] = b;
    __syncthreads();
    for (int o = 128; o > 0; o >>= 1) {
        if (tid < o) { l1[tid] += l1[tid + o]; l2[tid] += l2[tid + o]; }
        __syncthreads();
    }
    if (tid == 0) {
        double s = l1[0], q = l2[0];
        double mean = s / (double)EE;
        double var = (q - (double)EE * mean * mean) / (double)(EE - 1);
        if (var < 0) var = 0;
        statsf[0] = (float)mean;
        statsf[1] = (float)(1.0 / (sqrt(var) + 1e-6));
    }
}

// ---------------- edge-encoder MLP via MFMA (hi/lo bf16 split ~= fp32) ----------------
__device__ __forceinline__ short8 frag_rd(const ushort_t* __restrict__ s, int nc, int k0) {
    int sidx = (nc * 64 + k0) ^ ((nc & 7) << 3);
    return *reinterpret_cast<const short8*>(&s[sidx]);
}

__global__ __launch_bounds__(256) void k_mlp(const float* __restrict__ ea,
                                             const float* __restrict__ W1, const float* __restrict__ b1,
                                             const float* __restrict__ W2, const float* __restrict__ b2,
                                             const float* __restrict__ rp, const float* __restrict__ statsf,
                                             const int* __restrict__ pos,
                                             float* __restrict__ eout,
                                             ushort_t* __restrict__ es) {
    __shared__ __align__(16) ushort_t sW1h[4096], sW1l[4096], sW2h[4096], sW2l[4096];
    int tid = threadIdx.x;
    for (int i = tid; i < 4096; i += 256) {
        int k = i >> 6, nc = i & 63;
        int sidx = (nc * 64 + k) ^ ((nc & 7) << 3);
        float v1 = W1[i];
        ushort_t h1 = f2bf(v1); sW1h[sidx] = h1; sW1l[sidx] = f2bf(v1 - bf2f(h1));
        float v2 = W2[i];
        ushort_t h2 = f2bf(v2); sW2h[sidx] = h2; sW2l[sidx] = f2bf(v2 - bf2f(h2));
    }
    __syncthreads();

    int lane = tid & 63;
    int wid = tid >> 6;
    int col = lane & 15, kg = lane >> 4;
    int t = blockIdx.x * 4 + wid;
    bool act = t < NTILE;

    float hvals[4][4];
    if (act) {
        const float* ar = ea + (size_t)(t * 16 + col) * 64 + kg * 8;
        f32x4 f0 = *reinterpret_cast<const f32x4*>(ar);
        f32x4 f1 = *reinterpret_cast<const f32x4*>(ar + 4);
        f32x4 f2 = *reinterpret_cast<const f32x4*>(ar + 32);
        f32x4 f3 = *reinterpret_cast<const f32x4*>(ar + 36);
        short8 a0h, a0l, a1h, a1l;
#pragma unroll
        for (int j = 0; j < 4; ++j) {
            ushort_t h;
            h = f2bf(f0[j]); a0h[j]     = (short)h; a0l[j]     = (short)f2bf(f0[j] - bf2f(h));
            h = f2bf(f1[j]); a0h[4 + j] = (short)h; a0l[4 + j] = (short)f2bf(f1[j] - bf2f(h));
            h = f2bf(f2[j]); a1h[j]     = (short)h; a1l[j]     = (short)f2bf(f2[j] - bf2f(h));
            h = f2bf(f3[j]); a1h[4 + j] = (short)h; a1l[4 + j] = (short)f2bf(f3[j] - bf2f(h));
        }
#pragma unroll
        for (int n = 0; n < 4; ++n) {
            int nc = n * 16 + col;
            short8 b0h = frag_rd(sW1h, nc, kg * 8);
            short8 b0l = frag_rd(sW1l, nc, kg * 8);
            short8 b1h_ = frag_rd(sW1h, nc, 32 + kg * 8);
            short8 b1l_ = frag_rd(sW1l, nc, 32 + kg * 8);
            f32x4 acc = {0.f, 0.f, 0.f, 0.f};
            acc = __builtin_amdgcn_mfma_f32_16x16x32_bf16(a0h, b0h, acc, 0, 0, 0);
            acc = __builtin_amdgcn_mfma_f32_16x16x32_bf16(a0l, b0h, acc, 0, 0, 0);
            acc = __builtin_amdgcn_mfma_f32_16x16x32_bf16(a0h, b0l, acc, 0, 0, 0);
            acc = __builtin_amdgcn_mfma_f32_16x16x32_bf16(a1h, b1h_, acc, 0, 0, 0);
            acc = __builtin_amdgcn_mfma_f32_16x16x32_bf16(a1l, b1h_, acc, 0, 0, 0);
            acc = __builtin_amdgcn_mfma_f32_16x16x32_bf16(a1h, b1l_, acc, 0, 0, 0);
            float bb = b1[n * 16 + col];
#pragma unroll
            for (int r = 0; r < 4; ++r) hvals[n][r] = fmaxf(acc[r] + bb, 0.f);
        }
    }
    __syncthreads();

    if (!act) return;
    ushort_t* myHh = sW1h + wid * 1024;
    ushort_t* myHl = sW1l + wid * 1024;
#pragma unroll
    for (int n = 0; n < 4; ++n) {
        int nc = n * 16 + col;
#pragma unroll
        for (int r = 0; r < 4; ++r) {
            float hv = hvals[n][r];
            ushort_t hh = f2bf(hv);
            int row = kg * 4 + r;
            int sidx = (row * 64 + nc) ^ ((row & 7) << 3);
            myHh[sidx] = hh;
            myHl[sidx] = f2bf(hv - bf2f(hh));
        }
    }
    short8 c0h = frag_rd(myHh, col, kg * 8);
    short8 c0l = frag_rd(myHl, col, kg * 8);
    short8 c1h = frag_rd(myHh, col, 32 + kg * 8);
    short8 c1l = frag_rd(myHl, col, 32 + kg * 8);

    float mean = statsf[0], inv = statsf[1];
    float rps[4];
    int posr[4];
#pragma unroll
    for (int r = 0; r < 4; ++r) {
        rps[r] = (rp[t * 16 + kg * 4 + r] - mean) * inv;
        posr[r] = pos[t * 16 + kg * 4 + r];
    }

    float vals[4][4];
#pragma unroll
    for (int n = 0; n < 4; ++n) {
        int nc = n * 16 + col;
        short8 b0h = frag_rd(sW2h, nc, kg * 8);
        short8 b0l = frag_rd(sW2l, nc, kg * 8);
        short8 b1h_ = frag_rd(sW2h, nc, 32 + kg * 8);
        short8 b1l_ = frag_rd(sW2l, nc, 32 + kg * 8);
        f32x4 acc = {0.f, 0.f, 0.f, 0.f};
        acc = __builtin_amdgcn_mfma_f32_16x16x32_bf16(c0h, b0h, acc, 0, 0, 0);
        acc = __builtin_amdgcn_mfma_f32_16x16x32_bf16(c0l, b0h, acc, 0, 0, 0);
        acc = __builtin_amdgcn_mfma_f32_16x16x32_bf16(c0h, b0l, acc, 0, 0, 0);
        acc = __builtin_amdgcn_mfma_f32_16x16x32_bf16(c1h, b1h_, acc, 0, 0, 0);
        acc = __builtin_amdgcn_mfma_f32_16x16x32_bf16(c1l, b1h_, acc, 0, 0, 0);
        acc = __builtin_amdgcn_mfma_f32_16x16x32_bf16(c1h, b1l_, acc, 0, 0, 0);
        float bb = b2[nc];
#pragma unroll
        for (int r = 0; r < 4; ++r) {
            float val = acc[r] + bb + rps[r];
            vals[n][r] = val;
            eout[(size_t)(t * 16 + kg * 4 + r) * 64 + nc] = val;
        }
    }
#pragma unroll
    for (int r = 0; r < 4; ++r) {
        us4 w;
        w[0] = f2bf(vals[0][r]); w[1] = f2bf(vals[1][r]);
        w[2] = f2bf(vals[2][r]); w[3] = f2bf(vals[3][r]);
        *reinterpret_cast<us4*>(es + (size_t)posr[r] * 64 + col * 4) = w;
    }
}

// ---------------- CSR build ----------------
__global__ void k_zint(int* deg, int* cnt) {
    int i = blockIdx.x * 256 + threadIdx.x;
    if (i < NN) { deg[i] = 0; cnt[i] = 0; }
}

__global__ void k_deg(const int* __restrict__ ei, int* __restrict__ deg) {
    int e = blockIdx.x * 256 + threadIdx.x;
    if (e < EE) atomicAdd(&deg[ei[EE + e]], 1);
}

__global__ __launch_bounds__(1024) void k_scan(const int* __restrict__ deg, int* __restrict__ off) {
    __shared__ int part[1024];
    int t = threadIdx.x;
    const int chunk = (NN + 1023) / 1024;
    int lo = t * chunk, hi = min(lo + chunk, NN);
    int s = 0;
    for (int i = lo; i < hi; ++i) s += deg[i];
    part[t] = s;
    __syncthreads();
    for (int o = 1; o < 1024; o <<= 1) {
        int v = (t >= o) ? part[t - o] : 0;
        __syncthreads();
        part[t] += v;
        __syncthreads();
    }
    int base = (t == 0) ? 0 : part[t - 1];
    for (int i = lo; i < hi; ++i) { off[i] = base; base += deg[i]; }
    if (t == 0) off[NN] = EE;
}

__global__ void k_scatter(const int* __restrict__ ei, const int* __restrict__ off,
                          int* __restrict__ cnt, int* __restrict__ pos, int* __restrict__ rlist) {
    int e = blockIdx.x * 256 + threadIdx.x;
    if (e >= EE) return;
    int r = ei[e], c = ei[EE + e];
    int p = off[c] + atomicAdd(&cnt[c], 1);
    pos[e] = p;
    rlist[p] = r;
}

// ---------------- node-side GEMMs via MFMA (bf16, all four matrices) ----------------
// wave = 16-node tile; C/D: node = kg*4+r, dim = n*16+col (same verified mapping as k_mlp)
__global__ __launch_bounds__(256) void k_node(const float* __restrict__ xin,
                                              const float* __restrict__ Wq, const float* __restrict__ bq,
                                              const float* __restrict__ Wk, const float* __restrict__ bk,
                                              const float* __restrict__ Wv, const float* __restrict__ bv,
                                              const float* __restrict__ Wsk, const float* __restrict__ bsk,
                                              float* __restrict__ q, float* __restrict__ kvb,
                                              float* __restrict__ sk) {
    __shared__ __align__(16) ushort_t sW[4][4096];
    int tid = threadIdx.x;
    for (int i = tid; i < 4096; i += 256) {
        int k = i >> 6, nc = i & 63;
        int sidx = (nc * 64 + k) ^ ((nc & 7) << 3);
        sW[0][sidx] = f2bf(Wq[i]);
        sW[1][sidx] = f2bf(Wk[i]);
        sW[2][sidx] = f2bf(Wv[i]);
        sW[3][sidx] = f2bf(Wsk[i]);
    }
    __syncthreads();

    int lane = tid & 63;
    int wid = tid >> 6;
    int col = lane & 15, kg = lane >> 4;
    int t = blockIdx.x * 4 + wid;
    if (t >= NODETILE) return;

    const float* ar = xin + (size_t)(t * 16 + col) * 64 + kg * 8;
    f32x4 f0 = *reinterpret_cast<const f32x4*>(ar);
    f32x4 f1 = *reinterpret_cast<const f32x4*>(ar + 4);
    f32x4 f2 = *reinterpret_cast<const f32x4*>(ar + 32);
    f32x4 f3 = *reinterpret_cast<const f32x4*>(ar + 36);
    short8 a0, a1;
#pragma unroll
    for (int j = 0; j < 4; ++j) {
        a0[j] = (short)f2bf(f0[j]); a0[4 + j] = (short)f2bf(f1[j]);
        a1[j] = (short)f2bf(f2[j]); a1[4 + j] = (short)f2bf(f3[j]);
    }

    size_t nodebase = (size_t)t * 16 + kg * 4;

#pragma unroll
    for (int n = 0; n < 4; ++n) {       // q
        int nc = n * 16 + col;
        short8 b0 = frag_rd(sW[0], nc, kg * 8);
        short8 b1 = frag_rd(sW[0], nc, 32 + kg * 8);
        f32x4 acc = {0.f, 0.f, 0.f, 0.f};
        acc = __builtin_amdgcn_mfma_f32_16x16x32_bf16(a0, b0, acc, 0, 0, 0);
        acc = __builtin_amdgcn_mfma_f32_16x16x32_bf16(a1, b1, acc, 0, 0, 0);
        float bb = bq[nc];
#pragma unroll
        for (int r = 0; r < 4; ++r) q[(nodebase + r) * 64 + nc] = acc[r] + bb;
    }
#pragma unroll
    for (int n = 0; n < 4; ++n) {       // k -> kvb even
        int nc = n * 16 + col;
        short8 b0 = frag_rd(sW[1], nc, kg * 8);
        short8 b1 = frag_rd(sW[1], nc, 32 + kg * 8);
        f32x4 acc = {0.f, 0.f, 0.f, 0.f};
        acc = __builtin_amdgcn_mfma_f32_16x16x32_bf16(a0, b0, acc, 0, 0, 0);
        acc = __builtin_amdgcn_mfma_f32_16x16x32_bf16(a1, b1, acc, 0, 0, 0);
        float bb = bk[nc];
#pragma unroll
        for (int r = 0; r < 4; ++r) kvb[(nodebase + r) * 128 + nc * 2] = acc[r] + bb;
    }
#pragma unroll
    for (int n = 0; n < 4; ++n) {       // v -> kvb odd
        int nc = n * 16 + col;
        short8 b0 = frag_rd(sW[2], nc, kg * 8);
        short8 b1 = frag_rd(sW[2], nc, 32 + kg * 8);
        f32x4 acc = {0.f, 0.f, 0.f, 0.f};
        acc = __builtin_amdgcn_mfma_f32_16x16x32_bf16(a0, b0, acc, 0, 0, 0);
        acc = __builtin_amdgcn_mfma_f32_16x16x32_bf16(a1, b1, acc, 0, 0, 0);
        float bb = bv[nc];
#pragma unroll
        for (int r = 0; r < 4; ++r) kvb[(nodebase + r) * 128 + nc * 2 + 1] = acc[r] + bb;
    }
#pragma unroll
    for (int n = 0; n < 4; ++n) {       // sk
        int nc = n * 16 + col;
        short8 b0 = frag_rd(sW[3], nc, kg * 8);
        short8 b1 = frag_rd(sW[3], nc, 32 + kg * 8);
        f32x4 acc = {0.f, 0.f, 0.f, 0.f};
        acc = __builtin_amdgcn_mfma_f32_16x16x32_bf16(a0, b0, acc, 0, 0, 0);
        acc = __builtin_amdgcn_mfma_f32_16x16x32_bf16(a1, b1, acc, 0, 0, 0);
        float bb = bsk[nc];
#pragma unroll
        for (int r = 0; r < 4; ++r) sk[(nodebase + r) * 64 + nc] = acc[r] + bb;
    }
}

// ---------------- fused per-destination attention (LDS-staged We, no epilogue barrier) ----------------
__global__ __launch_bounds__(256) void k_edge(const int* __restrict__ off,
                                              const int* __restrict__ rlist,
                                              const ushort_t* __restrict__ es,
                                              const float* __restrict__ Wep,
                                              const float* __restrict__ q,
                                              const float* __restrict__ kvb,
                                              const float* __restrict__ skp,
                                              float* __restrict__ outb) {
    __shared__ float sWT[64 * 65];
    __shared__ float sA[4][264];
    int tid = threadIdx.x;
    for (int i = tid; i < 4096; i += 256) {
        int kr = i >> 6, kc = i & 63;
        sWT[kc * 65 + kr] = Wep[i];
    }
    __syncthreads();

    int lane = tid & 63;
    int wid = tid >> 6;
    int col = lane & 15, hs = lane >> 4, hb = lane & 48;
    size_t node = (size_t)blockIdx.x * 4 + wid;

    float qv = q[node * 64 + lane];
    float t0 = 0.f, t1 = 0.f, t2 = 0.f, t3 = 0.f;
#pragma unroll
    for (int d = 0; d < 16; ++d) {
        float qd = __shfl(qv, hb + d);
        const float* wp = sWT + (hb + d) * 65 + col;
        t0 = fmaf(wp[0],  qd, t0);
        t1 = fmaf(wp[16], qd, t1);
        t2 = fmaf(wp[32], qd, t2);
        t3 = fmaf(wp[48], qd, t3);
    }

    int p0 = __builtin_amdgcn_readfirstlane(off[node]);
    int p1 = __builtin_amdgcn_readfirstlane(off[node + 1]);
    float m = -INFINITY, s = 0.f, o = 0.f;
    float A0 = 0.f, A1 = 0.f, A2 = 0.f, A3 = 0.f;
    const float THR = 8.f;

    int p = p0;
    for (; p + 8 <= p1; p += 8) {
        int rx[8];
#pragma unroll
        for (int j = 0; j < 8; ++j) rx[j] = __builtin_amdgcn_readfirstlane(rlist[p + j]);
        us4 ew[8];
        float2 kvp[8];
#pragma unroll
        for (int j = 0; j < 8; ++j) {
            ew[j] = *reinterpret_cast<const us4*>(es + (size_t)(p + j) * 64 + col * 4);
            kvp[j] = *reinterpret_cast<const float2*>(kvb + (size_t)rx[j] * 128 + lane * 2);
        }
        float er0[8], er1[8], er2[8], er3[8], al[8];
#pragma unroll
        for (int j = 0; j < 8; ++j) {
            er0[j] = bf2f(ew[j][0]); er1[j] = bf2f(ew[j][1]);
            er2[j] = bf2f(ew[j][2]); er3[j] = bf2f(ew[j][3]);
            float d = qv * kvp[j].x;
            d = fmaf(er0[j], t0, d); d = fmaf(er1[j], t1, d);
            d = fmaf(er2[j], t2, d); d = fmaf(er3[j], t3, d);
            d += __shfl_xor(d, 1); d += __shfl_xor(d, 2);
            d += __shfl_xor(d, 4); d += __shfl_xor(d, 8);
            al[j] = d * 0.25f;
        }
        float bm = fmaxf(fmaxf(fmaxf(al[0], al[1]), fmaxf(al[2], al[3])),
                         fmaxf(fmaxf(al[4], al[5]), fmaxf(al[6], al[7])));
        if (m == -INFINITY) m = bm;
        else if (bm > m + THR) {
            float sc = __expf(m - bm);
            s *= sc; o *= sc;
            A0 *= sc; A1 *= sc; A2 *= sc; A3 *= sc;
            m = bm;
        }
#pragma unroll
        for (int j = 0; j < 8; ++j) {
            float pe = __expf(al[j] - m);
            s += pe;
            o = fmaf(pe, kvp[j].y, o);
            A0 = fmaf(pe, er0[j], A0);
            A1 = fmaf(pe, er1[j], A1);
            A2 = fmaf(pe, er2[j], A2);
            A3 = fmaf(pe, er3[j], A3);
        }
    }
    for (; p < p1; ++p) {
        us4 ew = *reinterpret_cast<const us4*>(es + (size_t)p * 64 + col * 4);
        int rxx = __builtin_amdgcn_readfirstlane(rlist[p]);
        float2 kvp = *reinterpret_cast<const float2*>(kvb + (size_t)rxx * 128 + lane * 2);
        float e0 = bf2f(ew[0]), e1 = bf2f(ew[1]), e2 = bf2f(ew[2]), e3 = bf2f(ew[3]);
        float d = qv * kvp.x;
        d = fmaf(e0, t0, d); d = fmaf(e1, t1, d);
        d = fmaf(e2, t2, d); d = fmaf(e3, t3, d);
        d += __shfl_xor(d, 1); d += __shfl_xor(d, 2);
        d += __shfl_xor(d, 4); d += __shfl_xor(d, 8);
        float aa = d * 0.25f;
        if (m == -INFINITY) m = aa;
        else if (aa > m + THR) {
            float sc = __expf(m - aa);
            s *= sc; o *= sc;
            A0 *= sc; A1 *= sc; A2 *= sc; A3 *= sc;
            m = aa;
        }
        float pe = __expf(aa - m);
        s += pe;
        o = fmaf(pe, kvp.y, o);
        A0 = fmaf(pe, e0, A0);
        A1 = fmaf(pe, e1, A1);
        A2 = fmaf(pe, e2, A2);
        A3 = fmaf(pe, e3, A3);
    }

    float* myA = sA[wid];
    myA[hs * 65 + col]      = A0;
    myA[hs * 65 + 16 + col] = A1;
    myA[hs * 65 + 32 + col] = A2;
    myA[hs * 65 + 48 + col] = A3;
    const float* Ah = myA + hs * 65;
    const float* wl = sWT + (size_t)lane * 65;
    float e0 = 0.f, e1 = 0.f, e2 = 0.f, e3 = 0.f;
#pragma unroll
    for (int kk = 0; kk < 64; kk += 4) {
        e0 = fmaf(Ah[kk],     wl[kk],     e0);
        e1 = fmaf(Ah[kk + 1], wl[kk + 1], e1);
        e2 = fmaf(Ah[kk + 2], wl[kk + 2], e2);
        e3 = fmaf(Ah[kk + 3], wl[kk + 3], e3);
    }
    float ex = (e0 + e1) + (e2 + e3);
    outb[node * 64 + lane] = (o + ex) / (s + 1e-16f) + skp[node * 64 + lane];
}

// ---------------- BN stats + BN/ReLU/residual/LN ----------------
__global__ void k_zbn(float* bn) {
    if (threadIdx.x < 128) bn[threadIdx.x] = 0.f;
}

__global__ __launch_bounds__(256) void k_bnstat(const float* __restrict__ conv, float* __restrict__ bn) {
    int tid = threadIdx.x;
    size_t idx0 = (size_t)blockIdx.x * 256 + tid;
    size_t stride = (size_t)gridDim.x * 256;
    float s = 0.f, ss = 0.f;
    for (size_t i = idx0; i < NF; i += stride) {
        float val = conv[i];
        s += val; ss += val * val;
    }
    __shared__ float l1[256], l2[256];
    l1[tid] = s; l2[tid] = ss;
    __syncthreads();
    if (tid < 64) {
        float a = l1[tid] + l1[tid + 64] + l1[tid + 128] + l1[tid + 192];
        float b = l2[tid] + l2[tid + 64] + l2[tid + 128] + l2[tid + 192];
        atomicAdd(bn + tid, a);
        atomicAdd(bn + 64 + tid, b);
    }
}

__global__ __launch_bounds__(256) void k_bnln(const float* __restrict__ conv,
                                              const float* __restrict__ xres,
                                              const float* __restrict__ bn,
                                              const float* __restrict__ g, const float* __restrict__ b,
                                              const float* __restrict__ lg, const float* __restrict__ lb,
                                              float* __restrict__ xout) {
    int tid = threadIdx.x;
    int lane = tid & 63;
    size_t row = (size_t)blockIdx.x * 4 + (tid >> 6);
    if (row >= (size_t)NN) return;
    float val = conv[row * 64 + lane];
    float mu = bn[lane] * (1.f / NN);
    float var = bn[64 + lane] * (1.f / NN) - mu * mu;
    float hn = (val - mu) * rsqrtf(var + 1e-5f) * g[lane] + b[lane];
    hn = fmaxf(hn, 0.f);
    float t = hn + xres[row * 64 + lane];
    float s = t, ss = t * t;
#pragma unroll
    for (int o = 32; o >= 1; o >>= 1) { s += __shfl_xor(s, o); ss += __shfl_xor(ss, o); }
    float mu2 = s * (1.f / 64.f);
    float var2 = ss * (1.f / 64.f) - mu2 * mu2;
    xout[row * 64 + lane] = (t - mu2) * rsqrtf(var2 + 1e-5f) * lg[lane] + lb[lane];
}

// ---------------- launch ----------------
extern "C" void kernel_launch(void* const* d_in, const int* in_sizes, int n_in,
                              void* d_out, int out_size, void* d_ws, size_t ws_size,
                              hipStream_t stream) {
    (void)in_sizes; (void)n_in; (void)out_size; (void)ws_size;
    const float* x   = (const float*)d_in[0];
    const int*   ei  = (const int*)d_in[1];
    const float* ea  = (const float*)d_in[2];
    const float* Wq  = (const float*)d_in[3];  const float* bq = (const float*)d_in[4];
    const float* Wk  = (const float*)d_in[5];  const float* bk = (const float*)d_in[6];
    const float* Wv  = (const float*)d_in[7];  const float* bv = (const float*)d_in[8];
    const float* We  = (const float*)d_in[9];
    const float* Wsk = (const float*)d_in[10]; const float* bsk = (const float*)d_in[11];
    const float* eW1 = (const float*)d_in[12]; const float* eb1 = (const float*)d_in[13];
    const float* eW2 = (const float*)d_in[14]; const float* eb2 = (const float*)d_in[15];
    const float* bng = (const float*)d_in[16]; const float* bnb = (const float*)d_in[17];
    const float* lng = (const float*)d_in[18]; const float* lnb = (const float*)d_in[19];

    float* ws = (float*)d_ws;
    float* out_x = (float*)d_out;
    float* out_e = out_x + NF;

    float* q    = ws + OQ;
    float* kvb  = ws + OKV;
    float* sk   = ws + OSK;
    float* bufA = ws + OBA;
    float* bufB = ws + OBB;
    float* rp   = ws + ORP;
    double* partial = (double*)(ws + OPART);
    float* statsf   = ws + OSTF;
    float* bn   = ws + OBN;
    int* deg  = (int*)(ws + ODEG);
    int* off  = (int*)(ws + OOFF);
    int* cnt  = (int*)(ws + OCNT);
    int* pos  = (int*)(ws + OPOS);
    int* rlist= (int*)(ws + ORL);
    ushort_t* es = (ushort_t*)(ws + OES);

    // CSR build first (pos needed by k_mlp)
    k_zint<<<(NN + 255) / 256, 256, 0, stream>>>(deg, cnt);
    k_deg<<<(EE + 255) / 256, 256, 0, stream>>>(ei, deg);
    k_scan<<<1, 1024, 0, stream>>>(deg, off);
    k_scatter<<<(EE + 255) / 256, 256, 0, stream>>>(ei, off, cnt, pos, rlist);

    k_rp<<<NPART, 256, 0, stream>>>(x, ei, rp, partial);
    k_statsf<<<1, 256, 0, stream>>>(partial, statsf);
    k_mlp<<<(NTILE + 3) / 4, 256, 0, stream>>>(ea, eW1, eb1, eW2, eb2, rp, statsf, pos, out_e, es);

    const float* xin = x;
    for (int l = 0; l < 3; ++l) {
        k_node<<<(NODETILE + 3) / 4, 256, 0, stream>>>(xin,
            Wq + (size_t)l * 4096, bq + (size_t)l * 64,
            Wk + (size_t)l * 4096, bk + (size_t)l * 64,
            Wv + (size_t)l * 4096, bv + (size_t)l * 64,
            Wsk + (size_t)l * 4096, bsk + (size_t)l * 64,
            q, kvb, sk);
        float* conv = (l == 2) ? out_x : sk;   // in-place skip add (same-element RMW only)
        k_edge<<<NN / 4, 256, 0, stream>>>(off, rlist, es,
            We + (size_t)l * 4096, q, kvb, sk, conv);
        if (l < 2) {
            k_zbn<<<1, 128, 0, stream>>>(bn);
            k_bnstat<<<1024, 256, 0, stream>>>(conv, bn);
            float* xout = (l == 0) ? bufA : bufB;
            k_bnln<<<(NN + 3) / 4, 256, 0, stream>>>(conv, xin, bn,
                bng + (size_t)l * 64, bnb + (size_t)l * 64,
                lng + (size_t)l * 64, lnb + (size_t)l * 64, xout);
            xin = xout;
        }
    }
}

// Round 19
// 708.319 us; speedup vs baseline: 1.4098x; 1.0291x over previous
//
#include <hip/hip_runtime.h>
#include <cstdint>
#include <cstddef>

#define NN 50000
#define EE 500000
#define NPART 1024
#define NTILE 31250   // EE/16
#define NODETILE 3125 // NN/16

typedef unsigned short ushort_t;
typedef __attribute__((ext_vector_type(8))) short short8;
typedef __attribute__((ext_vector_type(4))) float f32x4;
typedef __attribute__((ext_vector_type(4))) unsigned short us4;

__device__ __forceinline__ ushort_t f2bf(float f) {
    unsigned u = __float_as_uint(f);
    unsigned r = (u + 0x7fffu + ((u >> 16) & 1u)) >> 16;
    return (ushort_t)r;
}
__device__ __forceinline__ float bf2f(ushort_t b) {
    return __uint_as_float(((unsigned)b) << 16);
}

// ---------------- workspace layout (float offsets) ----------------
static constexpr size_t NF   = (size_t)NN * 64;
static constexpr size_t OQ   = 0;
static constexpr size_t OKV  = OQ   + NF;                  // kv bf16: NN*128 ushorts ([node][2d]=k_d,[2d+1]=v_d)
static constexpr size_t OSK  = OKV  + 2 * NF;              // (region reserved 2*NF floats; only NF used)
static constexpr size_t OBA  = OSK  + NF;
static constexpr size_t OBB  = OBA  + NF;
static constexpr size_t ORP  = OBB  + NF;
static constexpr size_t OPART= ORP  + (size_t)EE;
static constexpr size_t OSTF = OPART+ 4096;
static constexpr size_t OBN  = OSTF + 2;
static constexpr size_t OI   = OBN  + 128;
static constexpr size_t ODEG = OI;
static constexpr size_t OOFF = ODEG + NN;
static constexpr size_t OCNT = OOFF + NN + 2;
static constexpr size_t OPOS = OCNT + NN;
static constexpr size_t ORL  = OPOS + (size_t)EE;
static constexpr size_t OES  = ORL  + (size_t)EE;

// ---------------- rp ----------------
__global__ __launch_bounds__(256) void k_rp(const float* __restrict__ x,
                                            const int* __restrict__ ei,
                                            float* __restrict__ rp,
                                            double* __restrict__ partial) {
    int tid = threadIdx.x;
    int lane = tid & 63;
    int wid = tid >> 6;
    size_t wgid = (size_t)blockIdx.x * 4 + wid;
    size_t nw = (size_t)gridDim.x * 4;
    double c1 = 0.0, c2 = 0.0;
    for (size_t e0 = wgid * 8; e0 < (size_t)EE; e0 += nw * 8) {
        float rvs = 0.f;
#pragma unroll
        for (int j = 0; j < 8; ++j) {
            int r = __builtin_amdgcn_readfirstlane(ei[e0 + j]);
            int c = __builtin_amdgcn_readfirstlane(ei[EE + e0 + j]);
            float a = x[(size_t)r * 64 + lane];
            float b = x[(size_t)c * 64 + lane];
            float d = a - b;
            float ss = d * d;
            ss += __shfl_xor(ss, 1);  ss += __shfl_xor(ss, 2);
            ss += __shfl_xor(ss, 4);  ss += __shfl_xor(ss, 8);
            ss += __shfl_xor(ss, 16); ss += __shfl_xor(ss, 32);
            float rv = sqrtf(ss);
            c1 += (double)rv; c2 += (double)rv * (double)rv;
            rvs = (lane == j) ? rv : rvs;
        }
        if (lane < 8) rp[e0 + lane] = rvs;
    }
    __shared__ double l1[4], l2[4];
    if (lane == 0) { l1[wid] = c1; l2[wid] = c2; }
    __syncthreads();
    if (tid == 0) {
        partial[blockIdx.x * 2]     = l1[0] + l1[1] + l1[2] + l1[3];
        partial[blockIdx.x * 2 + 1] = l2[0] + l2[1] + l2[2] + l2[3];
    }
}

__global__ __launch_bounds__(256) void k_statsf(const double* __restrict__ partial,
                                                float* __restrict__ statsf) {
    __shared__ double l1[256], l2[256];
    int tid = threadIdx.x;
    double a = 0.0, b = 0.0;
    for (int i = tid; i < NPART; i += 256) { a += partial[2 * i]; b += partial[2 * i + 1]; }
    l1[tid] = a; l2[tid] = b;
    __syncthreads();
    for (int o = 128; o > 0; o >>= 1) {
        if (tid < o) { l1[tid] += l1[tid + o]; l2[tid] += l2[tid + o]; }
        __syncthreads();
    }
    if (tid == 0) {
        double s = l1[0], q = l2[0];
        double mean = s / (double)EE;
        double var = (q - (double)EE * mean * mean) / (double)(EE - 1);
        if (var < 0) var = 0;
        statsf[0] = (float)mean;
        statsf[1] = (float)(1.0 / (sqrt(var) + 1e-6));
    }
}

// ---------------- edge-encoder MLP via MFMA (hi/lo bf16 split ~= fp32) ----------------
__device__ __forceinline__ short8 frag_rd(const ushort_t* __restrict__ s, int nc, int k0) {
    int sidx = (nc * 64 + k0) ^ ((nc & 7) << 3);
    return *reinterpret_cast<const short8*>(&s[sidx]);
}

__global__ __launch_bounds__(256) void k_mlp(const float* __restrict__ ea,
                                             const float* __restrict__ W1, const float* __restrict__ b1,
                                             const float* __restrict__ W2, const float* __restrict__ b2,
                                             const float* __restrict__ rp, const float* __restrict__ statsf,
                                             const int* __restrict__ pos,
                                             float* __restrict__ eout,
                                             ushort_t* __restrict__ es) {
    __shared__ __align__(16) ushort_t sW1h[4096], sW1l[4096], sW2h[4096], sW2l[4096];
    int tid = threadIdx.x;
    for (int i = tid; i < 4096; i += 256) {
        int k = i >> 6, nc = i & 63;
        int sidx = (nc * 64 + k) ^ ((nc & 7) << 3);
        float v1 = W1[i];
        ushort_t h1 = f2bf(v1); sW1h[sidx] = h1; sW1l[sidx] = f2bf(v1 - bf2f(h1));
        float v2 = W2[i];
        ushort_t h2 = f2bf(v2); sW2h[sidx] = h2; sW2l[sidx] = f2bf(v2 - bf2f(h2));
    }
    __syncthreads();

    int lane = tid & 63;
    int wid = tid >> 6;
    int col = lane & 15, kg = lane >> 4;
    int t = blockIdx.x * 4 + wid;
    bool act = t < NTILE;

    float hvals[4][4];
    if (act) {
        const float* ar = ea + (size_t)(t * 16 + col) * 64 + kg * 8;
        f32x4 f0 = *reinterpret_cast<const f32x4*>(ar);
        f32x4 f1 = *reinterpret_cast<const f32x4*>(ar + 4);
        f32x4 f2 = *reinterpret_cast<const f32x4*>(ar + 32);
        f32x4 f3 = *reinterpret_cast<const f32x4*>(ar + 36);
        short8 a0h, a0l, a1h, a1l;
#pragma unroll
        for (int j = 0; j < 4; ++j) {
            ushort_t h;
            h = f2bf(f0[j]); a0h[j]     = (short)h; a0l[j]     = (short)f2bf(f0[j] - bf2f(h));
            h = f2bf(f1[j]); a0h[4 + j] = (short)h; a0l[4 + j] = (short)f2bf(f1[j] - bf2f(h));
            h = f2bf(f2[j]); a1h[j]     = (short)h; a1l[j]     = (short)f2bf(f2[j] - bf2f(h));
            h = f2bf(f3[j]); a1h[4 + j] = (short)h; a1l[4 + j] = (short)f2bf(f3[j] - bf2f(h));
        }
#pragma unroll
        for (int n = 0; n < 4; ++n) {
            int nc = n * 16 + col;
            short8 b0h = frag_rd(sW1h, nc, kg * 8);
            short8 b0l = frag_rd(sW1l, nc, kg * 8);
            short8 b1h_ = frag_rd(sW1h, nc, 32 + kg * 8);
            short8 b1l_ = frag_rd(sW1l, nc, 32 + kg * 8);
            f32x4 acc = {0.f, 0.f, 0.f, 0.f};
            acc = __builtin_amdgcn_mfma_f32_16x16x32_bf16(a0h, b0h, acc, 0, 0, 0);
            acc = __builtin_amdgcn_mfma_f32_16x16x32_bf16(a0l, b0h, acc, 0, 0, 0);
            acc = __builtin_amdgcn_mfma_f32_16x16x32_bf16(a0h, b0l, acc, 0, 0, 0);
            acc = __builtin_amdgcn_mfma_f32_16x16x32_bf16(a1h, b1h_, acc, 0, 0, 0);
            acc = __builtin_amdgcn_mfma_f32_16x16x32_bf16(a1l, b1h_, acc, 0, 0, 0);
            acc = __builtin_amdgcn_mfma_f32_16x16x32_bf16(a1h, b1l_, acc, 0, 0, 0);
            float bb = b1[n * 16 + col];
#pragma unroll
            for (int r = 0; r < 4; ++r) hvals[n][r] = fmaxf(acc[r] + bb, 0.f);
        }
    }
    __syncthreads();

    if (!act) return;
    ushort_t* myHh = sW1h + wid * 1024;
    ushort_t* myHl = sW1l + wid * 1024;
#pragma unroll
    for (int n = 0; n < 4; ++n) {
        int nc = n * 16 + col;
#pragma unroll
        for (int r = 0; r < 4; ++r) {
            float hv = hvals[n][r];
            ushort_t hh = f2bf(hv);
            int row = kg * 4 + r;
            int sidx = (row * 64 + nc) ^ ((row & 7) << 3);
            myHh[sidx] = hh;
            myHl[sidx] = f2bf(hv - bf2f(hh));
        }
    }
    short8 c0h = frag_rd(myHh, col, kg * 8);
    short8 c0l = frag_rd(myHl, col, kg * 8);
    short8 c1h = frag_rd(myHh, col, 32 + kg * 8);
    short8 c1l = frag_rd(myHl, col, 32 + kg * 8);

    float mean = statsf[0], inv = statsf[1];
    float rps[4];
    int posr[4];
#pragma unroll
    for (int r = 0; r < 4; ++r) {
        rps[r] = (rp[t * 16 + kg * 4 + r] - mean) * inv;
        posr[r] = pos[t * 16 + kg * 4 + r];
    }

    float vals[4][4];
#pragma unroll
    for (int n = 0; n < 4; ++n) {
        int nc = n * 16 + col;
        short8 b0h = frag_rd(sW2h, nc, kg * 8);
        short8 b0l = frag_rd(sW2l, nc, kg * 8);
        short8 b1h_ = frag_rd(sW2h, nc, 32 + kg * 8);
        short8 b1l_ = frag_rd(sW2l, nc, 32 + kg * 8);
        f32x4 acc = {0.f, 0.f, 0.f, 0.f};
        acc = __builtin_amdgcn_mfma_f32_16x16x32_bf16(c0h, b0h, acc, 0, 0, 0);
        acc = __builtin_amdgcn_mfma_f32_16x16x32_bf16(c0l, b0h, acc, 0, 0, 0);
        acc = __builtin_amdgcn_mfma_f32_16x16x32_bf16(c0h, b0l, acc, 0, 0, 0);
        acc = __builtin_amdgcn_mfma_f32_16x16x32_bf16(c1h, b1h_, acc, 0, 0, 0);
        acc = __builtin_amdgcn_mfma_f32_16x16x32_bf16(c1l, b1h_, acc, 0, 0, 0);
        acc = __builtin_amdgcn_mfma_f32_16x16x32_bf16(c1h, b1l_, acc, 0, 0, 0);
        float bb = b2[nc];
#pragma unroll
        for (int r = 0; r < 4; ++r) {
            float val = acc[r] + bb + rps[r];
            vals[n][r] = val;
            eout[(size_t)(t * 16 + kg * 4 + r) * 64 + nc] = val;
        }
    }
#pragma unroll
    for (int r = 0; r < 4; ++r) {
        us4 w;
        w[0] = f2bf(vals[0][r]); w[1] = f2bf(vals[1][r]);
        w[2] = f2bf(vals[2][r]); w[3] = f2bf(vals[3][r]);
        *reinterpret_cast<us4*>(es + (size_t)posr[r] * 64 + col * 4) = w;
    }
}

// ---------------- CSR build ----------------
__global__ void k_zint(int* deg, int* cnt) {
    int i = blockIdx.x * 256 + threadIdx.x;
    if (i < NN) { deg[i] = 0; cnt[i] = 0; }
}

__global__ void k_deg(const int* __restrict__ ei, int* __restrict__ deg) {
    int e = blockIdx.x * 256 + threadIdx.x;
    if (e < EE) atomicAdd(&deg[ei[EE + e]], 1);
}

__global__ __launch_bounds__(1024) void k_scan(const int* __restrict__ deg, int* __restrict__ off) {
    __shared__ int part[1024];
    int t = threadIdx.x;
    const int chunk = (NN + 1023) / 1024;
    int lo = t * chunk, hi = min(lo + chunk, NN);
    int s = 0;
    for (int i = lo; i < hi; ++i) s += deg[i];
    part[t] = s;
    __syncthreads();
    for (int o = 1; o < 1024; o <<= 1) {
        int v = (t >= o) ? part[t - o] : 0;
        __syncthreads();
        part[t] += v;
        __syncthreads();
    }
    int base = (t == 0) ? 0 : part[t - 1];
    for (int i = lo; i < hi; ++i) { off[i] = base; base += deg[i]; }
    if (t == 0) off[NN] = EE;
}

__global__ void k_scatter(const int* __restrict__ ei, const int* __restrict__ off,
                          int* __restrict__ cnt, int* __restrict__ pos, int* __restrict__ rlist) {
    int e = blockIdx.x * 256 + threadIdx.x;
    if (e >= EE) return;
    int r = ei[e], c = ei[EE + e];
    int p = off[c] + atomicAdd(&cnt[c], 1);
    pos[e] = p;
    rlist[p] = r;
}

// ---------------- node-side GEMMs via MFMA (bf16); k/v output packed bf16 ----------------
__global__ __launch_bounds__(256) void k_node(const float* __restrict__ xin,
                                              const float* __restrict__ Wq, const float* __restrict__ bq,
                                              const float* __restrict__ Wk, const float* __restrict__ bk,
                                              const float* __restrict__ Wv, const float* __restrict__ bv,
                                              const float* __restrict__ Wsk, const float* __restrict__ bsk,
                                              float* __restrict__ q, ushort_t* __restrict__ kvh,
                                              float* __restrict__ sk) {
    __shared__ __align__(16) ushort_t sW[4][4096];
    int tid = threadIdx.x;
    for (int i = tid; i < 4096; i += 256) {
        int k = i >> 6, nc = i & 63;
        int sidx = (nc * 64 + k) ^ ((nc & 7) << 3);
        sW[0][sidx] = f2bf(Wq[i]);
        sW[1][sidx] = f2bf(Wk[i]);
        sW[2][sidx] = f2bf(Wv[i]);
        sW[3][sidx] = f2bf(Wsk[i]);
    }
    __syncthreads();

    int lane = tid & 63;
    int wid = tid >> 6;
    int col = lane & 15, kg = lane >> 4;
    int t = blockIdx.x * 4 + wid;
    if (t >= NODETILE) return;

    const float* ar = xin + (size_t)(t * 16 + col) * 64 + kg * 8;
    f32x4 f0 = *reinterpret_cast<const f32x4*>(ar);
    f32x4 f1 = *reinterpret_cast<const f32x4*>(ar + 4);
    f32x4 f2 = *reinterpret_cast<const f32x4*>(ar + 32);
    f32x4 f3 = *reinterpret_cast<const f32x4*>(ar + 36);
    short8 a0, a1;
#pragma unroll
    for (int j = 0; j < 4; ++j) {
        a0[j] = (short)f2bf(f0[j]); a0[4 + j] = (short)f2bf(f1[j]);
        a1[j] = (short)f2bf(f2[j]); a1[4 + j] = (short)f2bf(f3[j]);
    }

    size_t nodebase = (size_t)t * 16 + kg * 4;

#pragma unroll
    for (int n = 0; n < 4; ++n) {       // q (fp32)
        int nc = n * 16 + col;
        short8 b0 = frag_rd(sW[0], nc, kg * 8);
        short8 b1 = frag_rd(sW[0], nc, 32 + kg * 8);
        f32x4 acc = {0.f, 0.f, 0.f, 0.f};
        acc = __builtin_amdgcn_mfma_f32_16x16x32_bf16(a0, b0, acc, 0, 0, 0);
        acc = __builtin_amdgcn_mfma_f32_16x16x32_bf16(a1, b1, acc, 0, 0, 0);
        float bb = bq[nc];
#pragma unroll
        for (int r = 0; r < 4; ++r) q[(nodebase + r) * 64 + nc] = acc[r] + bb;
    }
#pragma unroll
    for (int n = 0; n < 4; ++n) {       // k -> kvh even (bf16)
        int nc = n * 16 + col;
        short8 b0 = frag_rd(sW[1], nc, kg * 8);
        short8 b1 = frag_rd(sW[1], nc, 32 + kg * 8);
        f32x4 acc = {0.f, 0.f, 0.f, 0.f};
        acc = __builtin_amdgcn_mfma_f32_16x16x32_bf16(a0, b0, acc, 0, 0, 0);
        acc = __builtin_amdgcn_mfma_f32_16x16x32_bf16(a1, b1, acc, 0, 0, 0);
        float bb = bk[nc];
#pragma unroll
        for (int r = 0; r < 4; ++r) kvh[(nodebase + r) * 128 + nc * 2] = f2bf(acc[r] + bb);
    }
#pragma unroll
    for (int n = 0; n < 4; ++n) {       // v -> kvh odd (bf16)
        int nc = n * 16 + col;
        short8 b0 = frag_rd(sW[2], nc, kg * 8);
        short8 b1 = frag_rd(sW[2], nc, 32 + kg * 8);
        f32x4 acc = {0.f, 0.f, 0.f, 0.f};
        acc = __builtin_amdgcn_mfma_f32_16x16x32_bf16(a0, b0, acc, 0, 0, 0);
        acc = __builtin_amdgcn_mfma_f32_16x16x32_bf16(a1, b1, acc, 0, 0, 0);
        float bb = bv[nc];
#pragma unroll
        for (int r = 0; r < 4; ++r) kvh[(nodebase + r) * 128 + nc * 2 + 1] = f2bf(acc[r] + bb);
    }
#pragma unroll
    for (int n = 0; n < 4; ++n) {       // sk (fp32)
        int nc = n * 16 + col;
        short8 b0 = frag_rd(sW[3], nc, kg * 8);
        short8 b1 = frag_rd(sW[3], nc, 32 + kg * 8);
        f32x4 acc = {0.f, 0.f, 0.f, 0.f};
        acc = __builtin_amdgcn_mfma_f32_16x16x32_bf16(a0, b0, acc, 0, 0, 0);
        acc = __builtin_amdgcn_mfma_f32_16x16x32_bf16(a1, b1, acc, 0, 0, 0);
        float bb = bsk[nc];
#pragma unroll
        for (int r = 0; r < 4; ++r) sk[(nodebase + r) * 64 + nc] = acc[r] + bb;
    }
}

// ---------------- fused per-destination attention (bf16 kv: one dword gather/edge) ----------------
__global__ __launch_bounds__(256) void k_edge(const int* __restrict__ off,
                                              const int* __restrict__ rlist,
                                              const ushort_t* __restrict__ es,
                                              const float* __restrict__ Wep,
                                              const float* __restrict__ q,
                                              const ushort_t* __restrict__ kvh,
                                              const float* __restrict__ skp,
                                              float* __restrict__ outb) {
    __shared__ float sWT[64 * 65];
    __shared__ float sA[4][264];
    int tid = threadIdx.x;
    for (int i = tid; i < 4096; i += 256) {
        int kr = i >> 6, kc = i & 63;
        sWT[kc * 65 + kr] = Wep[i];
    }
    __syncthreads();

    int lane = tid & 63;
    int wid = tid >> 6;
    int col = lane & 15, hs = lane >> 4, hb = lane & 48;
    size_t node = (size_t)blockIdx.x * 4 + wid;

    float qv = q[node * 64 + lane];
    float t0 = 0.f, t1 = 0.f, t2 = 0.f, t3 = 0.f;
#pragma unroll
    for (int d = 0; d < 16; ++d) {
        float qd = __shfl(qv, hb + d);
        const float* wp = sWT + (hb + d) * 65 + col;
        t0 = fmaf(wp[0],  qd, t0);
        t1 = fmaf(wp[16], qd, t1);
        t2 = fmaf(wp[32], qd, t2);
        t3 = fmaf(wp[48], qd, t3);
    }

    int p0 = __builtin_amdgcn_readfirstlane(off[node]);
    int p1 = __builtin_amdgcn_readfirstlane(off[node + 1]);
    float m = -INFINITY, s = 0.f, o = 0.f;
    float A0 = 0.f, A1 = 0.f, A2 = 0.f, A3 = 0.f;
    const float THR = 8.f;

    int p = p0;
    for (; p + 8 <= p1; p += 8) {
        int rx[8];
#pragma unroll
        for (int j = 0; j < 8; ++j) rx[j] = __builtin_amdgcn_readfirstlane(rlist[p + j]);
        us4 ew[8];
        unsigned kvw[8];
#pragma unroll
        for (int j = 0; j < 8; ++j) {
            ew[j] = *reinterpret_cast<const us4*>(es + (size_t)(p + j) * 64 + col * 4);
            kvw[j] = *reinterpret_cast<const unsigned*>(kvh + (size_t)rx[j] * 128 + lane * 2);
        }
        float er0[8], er1[8], er2[8], er3[8], al[8], vv[8];
#pragma unroll
        for (int j = 0; j < 8; ++j) {
            er0[j] = bf2f(ew[j][0]); er1[j] = bf2f(ew[j][1]);
            er2[j] = bf2f(ew[j][2]); er3[j] = bf2f(ew[j][3]);
            float kva = bf2f((ushort_t)(kvw[j] & 0xffffu));
            vv[j] = bf2f((ushort_t)(kvw[j] >> 16));
            float d = qv * kva;
            d = fmaf(er0[j], t0, d); d = fmaf(er1[j], t1, d);
            d = fmaf(er2[j], t2, d); d = fmaf(er3[j], t3, d);
            d += __shfl_xor(d, 1); d += __shfl_xor(d, 2);
            d += __shfl_xor(d, 4); d += __shfl_xor(d, 8);
            al[j] = d * 0.25f;
        }
        float bm = fmaxf(fmaxf(fmaxf(al[0], al[1]), fmaxf(al[2], al[3])),
                         fmaxf(fmaxf(al[4], al[5]), fmaxf(al[6], al[7])));
        if (m == -INFINITY) m = bm;
        else if (bm > m + THR) {
            float sc = __expf(m - bm);
            s *= sc; o *= sc;
            A0 *= sc; A1 *= sc; A2 *= sc; A3 *= sc;
            m = bm;
        }
#pragma unroll
        for (int j = 0; j < 8; ++j) {
            float pe = __expf(al[j] - m);
            s += pe;
            o = fmaf(pe, vv[j], o);
            A0 = fmaf(pe, er0[j], A0);
            A1 = fmaf(pe, er1[j], A1);
            A2 = fmaf(pe, er2[j], A2);
            A3 = fmaf(pe, er3[j], A3);
        }
    }
    for (; p < p1; ++p) {
        us4 ew = *reinterpret_cast<const us4*>(es + (size_t)p * 64 + col * 4);
        int rxx = __builtin_amdgcn_readfirstlane(rlist[p]);
        unsigned kvw = *reinterpret_cast<const unsigned*>(kvh + (size_t)rxx * 128 + lane * 2);
        float e0 = bf2f(ew[0]), e1 = bf2f(ew[1]), e2 = bf2f(ew[2]), e3 = bf2f(ew[3]);
        float kva = bf2f((ushort_t)(kvw & 0xffffu));
        float vva = bf2f((ushort_t)(kvw >> 16));
        float d = qv * kva;
        d = fmaf(e0, t0, d); d = fmaf(e1, t1, d);
        d = fmaf(e2, t2, d); d = fmaf(e3, t3, d);
        d += __shfl_xor(d, 1); d += __shfl_xor(d, 2);
        d += __shfl_xor(d, 4); d += __shfl_xor(d, 8);
        float aa = d * 0.25f;
        if (m == -INFINITY) m = aa;
        else if (aa > m + THR) {
            float sc = __expf(m - aa);
            s *= sc; o *= sc;
            A0 *= sc; A1 *= sc; A2 *= sc; A3 *= sc;
            m = aa;
        }
        float pe = __expf(aa - m);
        s += pe;
        o = fmaf(pe, vva, o);
        A0 = fmaf(pe, e0, A0);
        A1 = fmaf(pe, e1, A1);
        A2 = fmaf(pe, e2, A2);
        A3 = fmaf(pe, e3, A3);
    }

    float* myA = sA[wid];
    myA[hs * 65 + col]      = A0;
    myA[hs * 65 + 16 + col] = A1;
    myA[hs * 65 + 32 + col] = A2;
    myA[hs * 65 + 48 + col] = A3;
    const float* Ah = myA + hs * 65;
    const float* wl = sWT + (size_t)lane * 65;
    float e0 = 0.f, e1 = 0.f, e2 = 0.f, e3 = 0.f;
#pragma unroll
    for (int kk = 0; kk < 64; kk += 4) {
        e0 = fmaf(Ah[kk],     wl[kk],     e0);
        e1 = fmaf(Ah[kk + 1], wl[kk + 1], e1);
        e2 = fmaf(Ah[kk + 2], wl[kk + 2], e2);
        e3 = fmaf(Ah[kk + 3], wl[kk + 3], e3);
    }
    float ex = (e0 + e1) + (e2 + e3);
    outb[node * 64 + lane] = (o + ex) / (s + 1e-16f) + skp[node * 64 + lane];
}

// ---------------- BN stats + BN/ReLU/residual/LN ----------------
__global__ void k_zbn(float* bn) {
    if (threadIdx.x < 128) bn[threadIdx.x] = 0.f;
}

__global__ __launch_bounds__(256) void k_bnstat(const float* __restrict__ conv, float* __restrict__ bn) {
    int tid = threadIdx.x;
    size_t idx0 = (size_t)blockIdx.x * 256 + tid;
    size_t stride = (size_t)gridDim.x * 256;
    float s = 0.f, ss = 0.f;
    for (size_t i = idx0; i < NF; i += stride) {
        float val = conv[i];
        s += val; ss += val * val;
    }
    __shared__ float l1[256], l2[256];
    l1[tid] = s; l2[tid] = ss;
    __syncthreads();
    if (tid < 64) {
        float a = l1[tid] + l1[tid + 64] + l1[tid + 128] + l1[tid + 192];
        float b = l2[tid] + l2[tid + 64] + l2[tid + 128] + l2[tid + 192];
        atomicAdd(bn + tid, a);
        atomicAdd(bn + 64 + tid, b);
    }
}

__global__ __launch_bounds__(256) void k_bnln(const float* __restrict__ conv,
                                              const float* __restrict__ xres,
                                              const float* __restrict__ bn,
                                              const float* __restrict__ g, const float* __restrict__ b,
                                              const float* __restrict__ lg, const float* __restrict__ lb,
                                              float* __restrict__ xout) {
    int tid = threadIdx.x;
    int lane = tid & 63;
    size_t row = (size_t)blockIdx.x * 4 + (tid >> 6);
    if (row >= (size_t)NN) return;
    float val = conv[row * 64 + lane];
    float mu = bn[lane] * (1.f / NN);
    float var = bn[64 + lane] * (1.f / NN) - mu * mu;
    float hn = (val - mu) * rsqrtf(var + 1e-5f) * g[lane] + b[lane];
    hn = fmaxf(hn, 0.f);
    float t = hn + xres[row * 64 + lane];
    float s = t, ss = t * t;
#pragma unroll
    for (int o = 32; o >= 1; o >>= 1) { s += __shfl_xor(s, o); ss += __shfl_xor(ss, o); }
    float mu2 = s * (1.f / 64.f);
    float var2 = ss * (1.f / 64.f) - mu2 * mu2;
    xout[row * 64 + lane] = (t - mu2) * rsqrtf(var2 + 1e-5f) * lg[lane] + lb[lane];
}

// ---------------- launch ----------------
extern "C" void kernel_launch(void* const* d_in, const int* in_sizes, int n_in,
                              void* d_out, int out_size, void* d_ws, size_t ws_size,
                              hipStream_t stream) {
    (void)in_sizes; (void)n_in; (void)out_size; (void)ws_size;
    const float* x   = (const float*)d_in[0];
    const int*   ei  = (const int*)d_in[1];
    const float* ea  = (const float*)d_in[2];
    const float* Wq  = (const float*)d_in[3];  const float* bq = (const float*)d_in[4];
    const float* Wk  = (const float*)d_in[5];  const float* bk = (const float*)d_in[6];
    const float* Wv  = (const float*)d_in[7];  const float* bv = (const float*)d_in[8];
    const float* We  = (const float*)d_in[9];
    const float* Wsk = (const float*)d_in[10]; const float* bsk = (const float*)d_in[11];
    const float* eW1 = (const float*)d_in[12]; const float* eb1 = (const float*)d_in[13];
    const float* eW2 = (const float*)d_in[14]; const float* eb2 = (const float*)d_in[15];
    const float* bng = (const float*)d_in[16]; const float* bnb = (const float*)d_in[17];
    const float* lng = (const float*)d_in[18]; const float* lnb = (const float*)d_in[19];

    float* ws = (float*)d_ws;
    float* out_x = (float*)d_out;
    float* out_e = out_x + NF;

    float* q    = ws + OQ;
    ushort_t* kvh = (ushort_t*)(ws + OKV);
    float* sk   = ws + OSK;
    float* bufA = ws + OBA;
    float* bufB = ws + OBB;
    float* rp   = ws + ORP;
    double* partial = (double*)(ws + OPART);
    float* statsf   = ws + OSTF;
    float* bn   = ws + OBN;
    int* deg  = (int*)(ws + ODEG);
    int* off  = (int*)(ws + OOFF);
    int* cnt  = (int*)(ws + OCNT);
    int* pos  = (int*)(ws + OPOS);
    int* rlist= (int*)(ws + ORL);
    ushort_t* es = (ushort_t*)(ws + OES);

    // CSR build first (pos needed by k_mlp)
    k_zint<<<(NN + 255) / 256, 256, 0, stream>>>(deg, cnt);
    k_deg<<<(EE + 255) / 256, 256, 0, stream>>>(ei, deg);
    k_scan<<<1, 1024, 0, stream>>>(deg, off);
    k_scatter<<<(EE + 255) / 256, 256, 0, stream>>>(ei, off, cnt, pos, rlist);

    k_rp<<<NPART, 256, 0, stream>>>(x, ei, rp, partial);
    k_statsf<<<1, 256, 0, stream>>>(partial, statsf);
    k_mlp<<<(NTILE + 3) / 4, 256, 0, stream>>>(ea, eW1, eb1, eW2, eb2, rp, statsf, pos, out_e, es);

    const float* xin = x;
    for (int l = 0; l < 3; ++l) {
        k_node<<<(NODETILE + 3) / 4, 256, 0, stream>>>(xin,
            Wq + (size_t)l * 4096, bq + (size_t)l * 64,
            Wk + (size_t)l * 4096, bk + (size_t)l * 64,
            Wv + (size_t)l * 4096, bv + (size_t)l * 64,
            Wsk + (size_t)l * 4096, bsk + (size_t)l * 64,
            q, kvh, sk);
        float* conv = (l == 2) ? out_x : sk;   // in-place skip add (same-element RMW only)
        k_edge<<<NN / 4, 256, 0, stream>>>(off, rlist, es,
            We + (size_t)l * 4096, q, kvh, sk, conv);
        if (l < 2) {
            k_zbn<<<1, 128, 0, stream>>>(bn);
            k_bnstat<<<1024, 256, 0, stream>>>(conv, bn);
            float* xout = (l == 0) ? bufA : bufB;
            k_bnln<<<(NN + 3) / 4, 256, 0, stream>>>(conv, xin, bn,
                bng + (size_t)l * 64, bnb + (size_t)l * 64,
                lng + (size_t)l * 64, lnb + (size_t)l * 64, xout);
            xin = xout;
        }
    }
}

// Round 20
// 693.065 us; speedup vs baseline: 1.4408x; 1.0220x over previous
//
#include <hip/hip_runtime.h>
#include <cstdint>
#include <cstddef>

#define NN 50000
#define EE 500000
#define NPART 1024
#define NTILE 31250   // EE/16
#define NODETILE 3125 // NN/16

typedef unsigned short ushort_t;
typedef __attribute__((ext_vector_type(8))) short short8;
typedef __attribute__((ext_vector_type(4))) float f32x4;
typedef __attribute__((ext_vector_type(4))) unsigned short us4;

__device__ __forceinline__ ushort_t f2bf(float f) {
    unsigned u = __float_as_uint(f);
    unsigned r = (u + 0x7fffu + ((u >> 16) & 1u)) >> 16;
    return (ushort_t)r;
}
__device__ __forceinline__ float bf2f(ushort_t b) {
    return __uint_as_float(((unsigned)b) << 16);
}

// ---------------- workspace layout (float offsets) ----------------
static constexpr size_t NF   = (size_t)NN * 64;
static constexpr size_t OQ   = 0;
static constexpr size_t OKV  = OQ   + NF;                  // kv bf16: NN*128 ushorts
static constexpr size_t OSK  = OKV  + 2 * NF;
static constexpr size_t OBA  = OSK  + NF;
static constexpr size_t OBB  = OBA  + NF;
static constexpr size_t ORP  = OBB  + NF;
static constexpr size_t OPART= ORP  + (size_t)EE;
static constexpr size_t OSTF = OPART+ 4096;
static constexpr size_t OBN  = OSTF + 2;
static constexpr size_t OI   = OBN  + 128;
static constexpr size_t ODEG = OI;
static constexpr size_t OOFF = ODEG + NN;
static constexpr size_t OCNT = OOFF + NN + 2;
static constexpr size_t OPOS = OCNT + NN;
static constexpr size_t ORL  = OPOS + (size_t)EE;
static constexpr size_t OES  = ORL  + (size_t)EE;

// ---------------- rp ----------------
__global__ __launch_bounds__(256) void k_rp(const float* __restrict__ x,
                                            const int* __restrict__ ei,
                                            float* __restrict__ rp,
                                            double* __restrict__ partial) {
    int tid = threadIdx.x;
    int lane = tid & 63;
    int wid = tid >> 6;
    size_t wgid = (size_t)blockIdx.x * 4 + wid;
    size_t nw = (size_t)gridDim.x * 4;
    double c1 = 0.0, c2 = 0.0;
    for (size_t e0 = wgid * 8; e0 < (size_t)EE; e0 += nw * 8) {
        float rvs = 0.f;
#pragma unroll
        for (int j = 0; j < 8; ++j) {
            int r = __builtin_amdgcn_readfirstlane(ei[e0 + j]);
            int c = __builtin_amdgcn_readfirstlane(ei[EE + e0 + j]);
            float a = x[(size_t)r * 64 + lane];
            float b = x[(size_t)c * 64 + lane];
            float d = a - b;
            float ss = d * d;
            ss += __shfl_xor(ss, 1);  ss += __shfl_xor(ss, 2);
            ss += __shfl_xor(ss, 4);  ss += __shfl_xor(ss, 8);
            ss += __shfl_xor(ss, 16); ss += __shfl_xor(ss, 32);
            float rv = sqrtf(ss);
            c1 += (double)rv; c2 += (double)rv * (double)rv;
            rvs = (lane == j) ? rv : rvs;
        }
        if (lane < 8) rp[e0 + lane] = rvs;
    }
    __shared__ double l1[4], l2[4];
    if (lane == 0) { l1[wid] = c1; l2[wid] = c2; }
    __syncthreads();
    if (tid == 0) {
        partial[blockIdx.x * 2]     = l1[0] + l1[1] + l1[2] + l1[3];
        partial[blockIdx.x * 2 + 1] = l2[0] + l2[1] + l2[2] + l2[3];
    }
}

__global__ __launch_bounds__(256) void k_statsf(const double* __restrict__ partial,
                                                float* __restrict__ statsf) {
    __shared__ double l1[256], l2[256];
    int tid = threadIdx.x;
    double a = 0.0, b = 0.0;
    for (int i = tid; i < NPART; i += 256) { a += partial[2 * i]; b += partial[2 * i + 1]; }
    l1[tid] = a; l2[tid] = b;
    __syncthreads();
    for (int o = 128; o > 0; o >>= 1) {
        if (tid < o) { l1[tid] += l1[tid + o]; l2[tid] += l2[tid + o]; }
        __syncthreads();
    }
    if (tid == 0) {
        double s = l1[0], q = l2[0];
        double mean = s / (double)EE;
        double var = (q - (double)EE * mean * mean) / (double)(EE - 1);
        if (var < 0) var = 0;
        statsf[0] = (float)mean;
        statsf[1] = (float)(1.0 / (sqrt(var) + 1e-6));
    }
}

// ---------------- edge-encoder MLP via MFMA (hi/lo bf16 split ~= fp32) ----------------
__device__ __forceinline__ short8 frag_rd(const ushort_t* __restrict__ s, int nc, int k0) {
    int sidx = (nc * 64 + k0) ^ ((nc & 7) << 3);
    return *reinterpret_cast<const short8*>(&s[sidx]);
}

__global__ __launch_bounds__(256) void k_mlp(const float* __restrict__ ea,
                                             const float* __restrict__ W1, const float* __restrict__ b1,
                                             const float* __restrict__ W2, const float* __restrict__ b2,
                                             const float* __restrict__ rp, const float* __restrict__ statsf,
                                             const int* __restrict__ pos,
                                             float* __restrict__ eout,
                                             ushort_t* __restrict__ es) {
    __shared__ __align__(16) ushort_t sW1h[4096], sW1l[4096], sW2h[4096], sW2l[4096];
    int tid = threadIdx.x;
    for (int i = tid; i < 4096; i += 256) {
        int k = i >> 6, nc = i & 63;
        int sidx = (nc * 64 + k) ^ ((nc & 7) << 3);
        float v1 = W1[i];
        ushort_t h1 = f2bf(v1); sW1h[sidx] = h1; sW1l[sidx] = f2bf(v1 - bf2f(h1));
        float v2 = W2[i];
        ushort_t h2 = f2bf(v2); sW2h[sidx] = h2; sW2l[sidx] = f2bf(v2 - bf2f(h2));
    }
    __syncthreads();

    int lane = tid & 63;
    int wid = tid >> 6;
    int col = lane & 15, kg = lane >> 4;
    int t = blockIdx.x * 4 + wid;
    bool act = t < NTILE;

    float hvals[4][4];
    if (act) {
        const float* ar = ea + (size_t)(t * 16 + col) * 64 + kg * 8;
        f32x4 f0 = *reinterpret_cast<const f32x4*>(ar);
        f32x4 f1 = *reinterpret_cast<const f32x4*>(ar + 4);
        f32x4 f2 = *reinterpret_cast<const f32x4*>(ar + 32);
        f32x4 f3 = *reinterpret_cast<const f32x4*>(ar + 36);
        short8 a0h, a0l, a1h, a1l;
#pragma unroll
        for (int j = 0; j < 4; ++j) {
            ushort_t h;
            h = f2bf(f0[j]); a0h[j]     = (short)h; a0l[j]     = (short)f2bf(f0[j] - bf2f(h));
            h = f2bf(f1[j]); a0h[4 + j] = (short)h; a0l[4 + j] = (short)f2bf(f1[j] - bf2f(h));
            h = f2bf(f2[j]); a1h[j]     = (short)h; a1l[j]     = (short)f2bf(f2[j] - bf2f(h));
            h = f2bf(f3[j]); a1h[4 + j] = (short)h; a1l[4 + j] = (short)f2bf(f3[j] - bf2f(h));
        }
#pragma unroll
        for (int n = 0; n < 4; ++n) {
            int nc = n * 16 + col;
            short8 b0h = frag_rd(sW1h, nc, kg * 8);
            short8 b0l = frag_rd(sW1l, nc, kg * 8);
            short8 b1h_ = frag_rd(sW1h, nc, 32 + kg * 8);
            short8 b1l_ = frag_rd(sW1l, nc, 32 + kg * 8);
            f32x4 acc = {0.f, 0.f, 0.f, 0.f};
            acc = __builtin_amdgcn_mfma_f32_16x16x32_bf16(a0h, b0h, acc, 0, 0, 0);
            acc = __builtin_amdgcn_mfma_f32_16x16x32_bf16(a0l, b0h, acc, 0, 0, 0);
            acc = __builtin_amdgcn_mfma_f32_16x16x32_bf16(a0h, b0l, acc, 0, 0, 0);
            acc = __builtin_amdgcn_mfma_f32_16x16x32_bf16(a1h, b1h_, acc, 0, 0, 0);
            acc = __builtin_amdgcn_mfma_f32_16x16x32_bf16(a1l, b1h_, acc, 0, 0, 0);
            acc = __builtin_amdgcn_mfma_f32_16x16x32_bf16(a1h, b1l_, acc, 0, 0, 0);
            float bb = b1[n * 16 + col];
#pragma unroll
            for (int r = 0; r < 4; ++r) hvals[n][r] = fmaxf(acc[r] + bb, 0.f);
        }
    }
    __syncthreads();

    if (!act) return;
    ushort_t* myHh = sW1h + wid * 1024;
    ushort_t* myHl = sW1l + wid * 1024;
#pragma unroll
    for (int n = 0; n < 4; ++n) {
        int nc = n * 16 + col;
#pragma unroll
        for (int r = 0; r < 4; ++r) {
            float hv = hvals[n][r];
            ushort_t hh = f2bf(hv);
            int row = kg * 4 + r;
            int sidx = (row * 64 + nc) ^ ((row & 7) << 3);
            myHh[sidx] = hh;
            myHl[sidx] = f2bf(hv - bf2f(hh));
        }
    }
    short8 c0h = frag_rd(myHh, col, kg * 8);
    short8 c0l = frag_rd(myHl, col, kg * 8);
    short8 c1h = frag_rd(myHh, col, 32 + kg * 8);
    short8 c1l = frag_rd(myHl, col, 32 + kg * 8);

    float mean = statsf[0], inv = statsf[1];
    float rps[4];
    int posr[4];
#pragma unroll
    for (int r = 0; r < 4; ++r) {
        rps[r] = (rp[t * 16 + kg * 4 + r] - mean) * inv;
        posr[r] = pos[t * 16 + kg * 4 + r];
    }

    float vals[4][4];
#pragma unroll
    for (int n = 0; n < 4; ++n) {
        int nc = n * 16 + col;
        short8 b0h = frag_rd(sW2h, nc, kg * 8);
        short8 b0l = frag_rd(sW2l, nc, kg * 8);
        short8 b1h_ = frag_rd(sW2h, nc, 32 + kg * 8);
        short8 b1l_ = frag_rd(sW2l, nc, 32 + kg * 8);
        f32x4 acc = {0.f, 0.f, 0.f, 0.f};
        acc = __builtin_amdgcn_mfma_f32_16x16x32_bf16(c0h, b0h, acc, 0, 0, 0);
        acc = __builtin_amdgcn_mfma_f32_16x16x32_bf16(c0l, b0h, acc, 0, 0, 0);
        acc = __builtin_amdgcn_mfma_f32_16x16x32_bf16(c0h, b0l, acc, 0, 0, 0);
        acc = __builtin_amdgcn_mfma_f32_16x16x32_bf16(c1h, b1h_, acc, 0, 0, 0);
        acc = __builtin_amdgcn_mfma_f32_16x16x32_bf16(c1l, b1h_, acc, 0, 0, 0);
        acc = __builtin_amdgcn_mfma_f32_16x16x32_bf16(c1h, b1l_, acc, 0, 0, 0);
        float bb = b2[nc];
#pragma unroll
        for (int r = 0; r < 4; ++r) {
            float val = acc[r] + bb + rps[r];
            vals[n][r] = val;
            eout[(size_t)(t * 16 + kg * 4 + r) * 64 + nc] = val;
        }
    }
#pragma unroll
    for (int r = 0; r < 4; ++r) {
        us4 w;
        w[0] = f2bf(vals[0][r]); w[1] = f2bf(vals[1][r]);
        w[2] = f2bf(vals[2][r]); w[3] = f2bf(vals[3][r]);
        *reinterpret_cast<us4*>(es + (size_t)posr[r] * 64 + col * 4) = w;
    }
}

// ---------------- CSR build ----------------
__global__ void k_zint(int* deg, int* cnt) {
    int i = blockIdx.x * 256 + threadIdx.x;
    if (i < NN) { deg[i] = 0; cnt[i] = 0; }
}

__global__ void k_deg(const int* __restrict__ ei, int* __restrict__ deg) {
    int e = blockIdx.x * 256 + threadIdx.x;
    if (e < EE) atomicAdd(&deg[ei[EE + e]], 1);
}

__global__ __launch_bounds__(1024) void k_scan(const int* __restrict__ deg, int* __restrict__ off) {
    __shared__ int part[1024];
    int t = threadIdx.x;
    const int chunk = (NN + 1023) / 1024;
    int lo = t * chunk, hi = min(lo + chunk, NN);
    int s = 0;
    for (int i = lo; i < hi; ++i) s += deg[i];
    part[t] = s;
    __syncthreads();
    for (int o = 1; o < 1024; o <<= 1) {
        int v = (t >= o) ? part[t - o] : 0;
        __syncthreads();
        part[t] += v;
        __syncthreads();
    }
    int base = (t == 0) ? 0 : part[t - 1];
    for (int i = lo; i < hi; ++i) { off[i] = base; base += deg[i]; }
    if (t == 0) off[NN] = EE;
}

__global__ void k_scatter(const int* __restrict__ ei, const int* __restrict__ off,
                          int* __restrict__ cnt, int* __restrict__ pos, int* __restrict__ rlist) {
    int e = blockIdx.x * 256 + threadIdx.x;
    if (e >= EE) return;
    int r = ei[e], c = ei[EE + e];
    int p = off[c] + atomicAdd(&cnt[c], 1);
    pos[e] = p;
    rlist[p] = r;
}

// ---------------- node-side GEMMs via MFMA (bf16); k/v output packed bf16 ----------------
__global__ __launch_bounds__(256) void k_node(const float* __restrict__ xin,
                                              const float* __restrict__ Wq, const float* __restrict__ bq,
                                              const float* __restrict__ Wk, const float* __restrict__ bk,
                                              const float* __restrict__ Wv, const float* __restrict__ bv,
                                              const float* __restrict__ Wsk, const float* __restrict__ bsk,
                                              float* __restrict__ q, ushort_t* __restrict__ kvh,
                                              float* __restrict__ sk) {
    __shared__ __align__(16) ushort_t sW[4][4096];
    int tid = threadIdx.x;
    for (int i = tid; i < 4096; i += 256) {
        int k = i >> 6, nc = i & 63;
        int sidx = (nc * 64 + k) ^ ((nc & 7) << 3);
        sW[0][sidx] = f2bf(Wq[i]);
        sW[1][sidx] = f2bf(Wk[i]);
        sW[2][sidx] = f2bf(Wv[i]);
        sW[3][sidx] = f2bf(Wsk[i]);
    }
    __syncthreads();

    int lane = tid & 63;
    int wid = tid >> 6;
    int col = lane & 15, kg = lane >> 4;
    int t = blockIdx.x * 4 + wid;
    if (t >= NODETILE) return;

    const float* ar = xin + (size_t)(t * 16 + col) * 64 + kg * 8;
    f32x4 f0 = *reinterpret_cast<const f32x4*>(ar);
    f32x4 f1 = *reinterpret_cast<const f32x4*>(ar + 4);
    f32x4 f2 = *reinterpret_cast<const f32x4*>(ar + 32);
    f32x4 f3 = *reinterpret_cast<const f32x4*>(ar + 36);
    short8 a0, a1;
#pragma unroll
    for (int j = 0; j < 4; ++j) {
        a0[j] = (short)f2bf(f0[j]); a0[4 + j] = (short)f2bf(f1[j]);
        a1[j] = (short)f2bf(f2[j]); a1[4 + j] = (short)f2bf(f3[j]);
    }

    size_t nodebase = (size_t)t * 16 + kg * 4;

#pragma unroll
    for (int n = 0; n < 4; ++n) {       // q (fp32)
        int nc = n * 16 + col;
        short8 b0 = frag_rd(sW[0], nc, kg * 8);
        short8 b1 = frag_rd(sW[0], nc, 32 + kg * 8);
        f32x4 acc = {0.f, 0.f, 0.f, 0.f};
        acc = __builtin_amdgcn_mfma_f32_16x16x32_bf16(a0, b0, acc, 0, 0, 0);
        acc = __builtin_amdgcn_mfma_f32_16x16x32_bf16(a1, b1, acc, 0, 0, 0);
        float bb = bq[nc];
#pragma unroll
        for (int r = 0; r < 4; ++r) q[(nodebase + r) * 64 + nc] = acc[r] + bb;
    }
#pragma unroll
    for (int n = 0; n < 4; ++n) {       // k -> kvh even (bf16)
        int nc = n * 16 + col;
        short8 b0 = frag_rd(sW[1], nc, kg * 8);
        short8 b1 = frag_rd(sW[1], nc, 32 + kg * 8);
        f32x4 acc = {0.f, 0.f, 0.f, 0.f};
        acc = __builtin_amdgcn_mfma_f32_16x16x32_bf16(a0, b0, acc, 0, 0, 0);
        acc = __builtin_amdgcn_mfma_f32_16x16x32_bf16(a1, b1, acc, 0, 0, 0);
        float bb = bk[nc];
#pragma unroll
        for (int r = 0; r < 4; ++r) kvh[(nodebase + r) * 128 + nc * 2] = f2bf(acc[r] + bb);
    }
#pragma unroll
    for (int n = 0; n < 4; ++n) {       // v -> kvh odd (bf16)
        int nc = n * 16 + col;
        short8 b0 = frag_rd(sW[2], nc, kg * 8);
        short8 b1 = frag_rd(sW[2], nc, 32 + kg * 8);
        f32x4 acc = {0.f, 0.f, 0.f, 0.f};
        acc = __builtin_amdgcn_mfma_f32_16x16x32_bf16(a0, b0, acc, 0, 0, 0);
        acc = __builtin_amdgcn_mfma_f32_16x16x32_bf16(a1, b1, acc, 0, 0, 0);
        float bb = bv[nc];
#pragma unroll
        for (int r = 0; r < 4; ++r) kvh[(nodebase + r) * 128 + nc * 2 + 1] = f2bf(acc[r] + bb);
    }
#pragma unroll
    for (int n = 0; n < 4; ++n) {       // sk (fp32)
        int nc = n * 16 + col;
        short8 b0 = frag_rd(sW[3], nc, kg * 8);
        short8 b1 = frag_rd(sW[3], nc, 32 + kg * 8);
        f32x4 acc = {0.f, 0.f, 0.f, 0.f};
        acc = __builtin_amdgcn_mfma_f32_16x16x32_bf16(a0, b0, acc, 0, 0, 0);
        acc = __builtin_amdgcn_mfma_f32_16x16x32_bf16(a1, b1, acc, 0, 0, 0);
        float bb = bsk[nc];
#pragma unroll
        for (int r = 0; r < 4; ++r) sk[(nodebase + r) * 64 + nc] = acc[r] + bb;
    }
}

// ---------------- fused per-destination attention (all batches predicated, no serial tail) ----------------
__global__ __launch_bounds__(256) void k_edge(const int* __restrict__ off,
                                              const int* __restrict__ rlist,
                                              const ushort_t* __restrict__ es,
                                              const float* __restrict__ Wep,
                                              const float* __restrict__ q,
                                              const ushort_t* __restrict__ kvh,
                                              const float* __restrict__ skp,
                                              float* __restrict__ outb) {
    __shared__ float sWT[64 * 65];
    __shared__ float sA[4][264];
    int tid = threadIdx.x;
    for (int i = tid; i < 4096; i += 256) {
        int kr = i >> 6, kc = i & 63;
        sWT[kc * 65 + kr] = Wep[i];
    }
    __syncthreads();

    int lane = tid & 63;
    int wid = tid >> 6;
    int col = lane & 15, hs = lane >> 4, hb = lane & 48;
    size_t node = (size_t)blockIdx.x * 4 + wid;

    float qv = q[node * 64 + lane];
    float t0 = 0.f, t1 = 0.f, t2 = 0.f, t3 = 0.f;
#pragma unroll
    for (int d = 0; d < 16; ++d) {
        float qd = __shfl(qv, hb + d);
        const float* wp = sWT + (hb + d) * 65 + col;
        t0 = fmaf(wp[0],  qd, t0);
        t1 = fmaf(wp[16], qd, t1);
        t2 = fmaf(wp[32], qd, t2);
        t3 = fmaf(wp[48], qd, t3);
    }

    int p0 = __builtin_amdgcn_readfirstlane(off[node]);
    int p1 = __builtin_amdgcn_readfirstlane(off[node + 1]);
    float m = -INFINITY, s = 0.f, o = 0.f;
    float A0 = 0.f, A1 = 0.f, A2 = 0.f, A3 = 0.f;
    const float THR = 8.f;

    // all batches predicated: last batch clamps indices (duplicate reads) and zeroes invalid pe
    for (int p = p0; p < p1; p += 8) {
        int pj[8], rx[8];
#pragma unroll
        for (int j = 0; j < 8; ++j) {
            pj[j] = (p + j < p1) ? (p + j) : (p1 - 1);
            rx[j] = __builtin_amdgcn_readfirstlane(rlist[pj[j]]);
        }
        us4 ew[8];
        unsigned kvw[8];
#pragma unroll
        for (int j = 0; j < 8; ++j) {
            ew[j] = *reinterpret_cast<const us4*>(es + (size_t)pj[j] * 64 + col * 4);
            kvw[j] = *reinterpret_cast<const unsigned*>(kvh + (size_t)rx[j] * 128 + lane * 2);
        }
        float er0[8], er1[8], er2[8], er3[8], al[8], vv[8];
#pragma unroll
        for (int j = 0; j < 8; ++j) {
            er0[j] = bf2f(ew[j][0]); er1[j] = bf2f(ew[j][1]);
            er2[j] = bf2f(ew[j][2]); er3[j] = bf2f(ew[j][3]);
            float kva = bf2f((ushort_t)(kvw[j] & 0xffffu));
            vv[j] = bf2f((ushort_t)(kvw[j] >> 16));
            float d = qv * kva;
            d = fmaf(er0[j], t0, d); d = fmaf(er1[j], t1, d);
            d = fmaf(er2[j], t2, d); d = fmaf(er3[j], t3, d);
            d += __shfl_xor(d, 1); d += __shfl_xor(d, 2);
            d += __shfl_xor(d, 4); d += __shfl_xor(d, 8);
            al[j] = d * 0.25f;
        }
        float bm = fmaxf(fmaxf(fmaxf(al[0], al[1]), fmaxf(al[2], al[3])),
                         fmaxf(fmaxf(al[4], al[5]), fmaxf(al[6], al[7])));
        if (m == -INFINITY) m = bm;
        else if (bm > m + THR) {
            float sc = __expf(m - bm);
            s *= sc; o *= sc;
            A0 *= sc; A1 *= sc; A2 *= sc; A3 *= sc;
            m = bm;
        }
#pragma unroll
        for (int j = 0; j < 8; ++j) {
            float pe = (p + j < p1) ? __expf(al[j] - m) : 0.f;
            s += pe;
            o = fmaf(pe, vv[j], o);
            A0 = fmaf(pe, er0[j], A0);
            A1 = fmaf(pe, er1[j], A1);
            A2 = fmaf(pe, er2[j], A2);
            A3 = fmaf(pe, er3[j], A3);
        }
    }

    float* myA = sA[wid];
    myA[hs * 65 + col]      = A0;
    myA[hs * 65 + 16 + col] = A1;
    myA[hs * 65 + 32 + col] = A2;
    myA[hs * 65 + 48 + col] = A3;
    const float* Ah = myA + hs * 65;
    const float* wl = sWT + (size_t)lane * 65;
    float e0 = 0.f, e1 = 0.f, e2 = 0.f, e3 = 0.f;
#pragma unroll
    for (int kk = 0; kk < 64; kk += 4) {
        e0 = fmaf(Ah[kk],     wl[kk],     e0);
        e1 = fmaf(Ah[kk + 1], wl[kk + 1], e1);
        e2 = fmaf(Ah[kk + 2], wl[kk + 2], e2);
        e3 = fmaf(Ah[kk + 3], wl[kk + 3], e3);
    }
    float ex = (e0 + e1) + (e2 + e3);
    outb[node * 64 + lane] = (o + ex) / (s + 1e-16f) + skp[node * 64 + lane];
}

// ---------------- BN stats + BN/ReLU/residual/LN ----------------
__global__ void k_zbn(float* bn) {
    if (threadIdx.x < 128) bn[threadIdx.x] = 0.f;
}

__global__ __launch_bounds__(256) void k_bnstat(const float* __restrict__ conv, float* __restrict__ bn) {
    int tid = threadIdx.x;
    size_t idx0 = (size_t)blockIdx.x * 256 + tid;
    size_t stride = (size_t)gridDim.x * 256;
    float s = 0.f, ss = 0.f;
    for (size_t i = idx0; i < NF; i += stride) {
        float val = conv[i];
        s += val; ss += val * val;
    }
    __shared__ float l1[256], l2[256];
    l1[tid] = s; l2[tid] = ss;
    __syncthreads();
    if (tid < 64) {
        float a = l1[tid] + l1[tid + 64] + l1[tid + 128] + l1[tid + 192];
        float b = l2[tid] + l2[tid + 64] + l2[tid + 128] + l2[tid + 192];
        atomicAdd(bn + tid, a);
        atomicAdd(bn + 64 + tid, b);
    }
}

__global__ __launch_bounds__(256) void k_bnln(const float* __restrict__ conv,
                                              const float* __restrict__ xres,
                                              const float* __restrict__ bn,
                                              const float* __restrict__ g, const float* __restrict__ b,
                                              const float* __restrict__ lg, const float* __restrict__ lb,
                                              float* __restrict__ xout) {
    int tid = threadIdx.x;
    int lane = tid & 63;
    size_t row = (size_t)blockIdx.x * 4 + (tid >> 6);
    if (row >= (size_t)NN) return;
    float val = conv[row * 64 + lane];
    float mu = bn[lane] * (1.f / NN);
    float var = bn[64 + lane] * (1.f / NN) - mu * mu;
    float hn = (val - mu) * rsqrtf(var + 1e-5f) * g[lane] + b[lane];
    hn = fmaxf(hn, 0.f);
    float t = hn + xres[row * 64 + lane];
    float s = t, ss = t * t;
#pragma unroll
    for (int o = 32; o >= 1; o >>= 1) { s += __shfl_xor(s, o); ss += __shfl_xor(ss, o); }
    float mu2 = s * (1.f / 64.f);
    float var2 = ss * (1.f / 64.f) - mu2 * mu2;
    xout[row * 64 + lane] = (t - mu2) * rsqrtf(var2 + 1e-5f) * lg[lane] + lb[lane];
}

// ---------------- launch ----------------
extern "C" void kernel_launch(void* const* d_in, const int* in_sizes, int n_in,
                              void* d_out, int out_size, void* d_ws, size_t ws_size,
                              hipStream_t stream) {
    (void)in_sizes; (void)n_in; (void)out_size; (void)ws_size;
    const float* x   = (const float*)d_in[0];
    const int*   ei  = (const int*)d_in[1];
    const float* ea  = (const float*)d_in[2];
    const float* Wq  = (const float*)d_in[3];  const float* bq = (const float*)d_in[4];
    const float* Wk  = (const float*)d_in[5];  const float* bk = (const float*)d_in[6];
    const float* Wv  = (const float*)d_in[7];  const float* bv = (const float*)d_in[8];
    const float* We  = (const float*)d_in[9];
    const float* Wsk = (const float*)d_in[10]; const float* bsk = (const float*)d_in[11];
    const float* eW1 = (const float*)d_in[12]; const float* eb1 = (const float*)d_in[13];
    const float* eW2 = (const float*)d_in[14]; const float* eb2 = (const float*)d_in[15];
    const float* bng = (const float*)d_in[16]; const float* bnb = (const float*)d_in[17];
    const float* lng = (const float*)d_in[18]; const float* lnb = (const float*)d_in[19];

    float* ws = (float*)d_ws;
    float* out_x = (float*)d_out;
    float* out_e = out_x + NF;

    float* q    = ws + OQ;
    ushort_t* kvh = (ushort_t*)(ws + OKV);
    float* sk   = ws + OSK;
    float* bufA = ws + OBA;
    float* bufB = ws + OBB;
    float* rp   = ws + ORP;
    double* partial = (double*)(ws + OPART);
    float* statsf   = ws + OSTF;
    float* bn   = ws + OBN;
    int* deg  = (int*)(ws + ODEG);
    int* off  = (int*)(ws + OOFF);
    int* cnt  = (int*)(ws + OCNT);
    int* pos  = (int*)(ws + OPOS);
    int* rlist= (int*)(ws + ORL);
    ushort_t* es = (ushort_t*)(ws + OES);

    // CSR build first (pos needed by k_mlp)
    k_zint<<<(NN + 255) / 256, 256, 0, stream>>>(deg, cnt);
    k_deg<<<(EE + 255) / 256, 256, 0, stream>>>(ei, deg);
    k_scan<<<1, 1024, 0, stream>>>(deg, off);
    k_scatter<<<(EE + 255) / 256, 256, 0, stream>>>(ei, off, cnt, pos, rlist);

    k_rp<<<NPART, 256, 0, stream>>>(x, ei, rp, partial);
    k_statsf<<<1, 256, 0, stream>>>(partial, statsf);
    k_mlp<<<(NTILE + 3) / 4, 256, 0, stream>>>(ea, eW1, eb1, eW2, eb2, rp, statsf, pos, out_e, es);

    const float* xin = x;
    for (int l = 0; l < 3; ++l) {
        k_node<<<(NODETILE + 3) / 4, 256, 0, stream>>>(xin,
            Wq + (size_t)l * 4096, bq + (size_t)l * 64,
            Wk + (size_t)l * 4096, bk + (size_t)l * 64,
            Wv + (size_t)l * 4096, bv + (size_t)l * 64,
            Wsk + (size_t)l * 4096, bsk + (size_t)l * 64,
            q, kvh, sk);
        float* conv = (l == 2) ? out_x : sk;   // in-place skip add (same-element RMW only)
        k_edge<<<NN / 4, 256, 0, stream>>>(off, rlist, es,
            We + (size_t)l * 4096, q, kvh, sk, conv);
        if (l < 2) {
            k_zbn<<<1, 128, 0, stream>>>(bn);
            k_bnstat<<<1024, 256, 0, stream>>>(conv, bn);
            float* xout = (l == 0) ? bufA : bufB;
            k_bnln<<<(NN + 3) / 4, 256, 0, stream>>>(conv, xin, bn,
                bng + (size_t)l * 64, bnb + (size_t)l * 64,
                lng + (size_t)l * 64, lnb + (size_t)l * 64, xout);
            xin = xout;
        }
    }
}

// Round 22
// 678.005 us; speedup vs baseline: 1.4728x; 1.0222x over previous
//
#include <hip/hip_runtime.h>
#include <cstdint>
#include <cstddef>

#define NN 50000
#define EE 500000
#define NPART 1024
#define NTILE 31250   // EE/16
#define NODETILE 3125 // NN/16

typedef unsigned short ushort_t;
typedef __attribute__((ext_vector_type(8))) short short8;
typedef __attribute__((ext_vector_type(4))) float f32x4;
typedef __attribute__((ext_vector_type(4))) unsigned short us4;

__device__ __forceinline__ ushort_t f2bf(float f) {
    unsigned u = __float_as_uint(f);
    unsigned r = (u + 0x7fffu + ((u >> 16) & 1u)) >> 16;
    return (ushort_t)r;
}
__device__ __forceinline__ float bf2f(ushort_t b) {
    return __uint_as_float(((unsigned)b) << 16);
}

// ---------------- workspace layout (float offsets; identical to round-20 footprint) ----------------
static constexpr size_t NF   = (size_t)NN * 64;
static constexpr size_t OQ   = 0;
static constexpr size_t OKV  = OQ   + NF;                  // kv bf16: NN*128 ushorts
static constexpr size_t OSK  = OKV  + 2 * NF;
static constexpr size_t OBA  = OSK  + NF;
static constexpr size_t OBB  = OBA  + NF;
static constexpr size_t ORP  = OBB  + NF;
static constexpr size_t OPART= ORP  + (size_t)EE;
static constexpr size_t OSTF = OPART+ 4096;
static constexpr size_t OBN  = OSTF + 2;
static constexpr size_t OI   = OBN  + 128;
static constexpr size_t ODEG = OI;                         // deg NN ints; DEAD after k_scan -> reused as wn (49152 ushorts)
static constexpr size_t OOFF = ODEG + NN;
static constexpr size_t OCNT = OOFF + NN + 2;              // cnt NN ints; DEAD after k_scatter -> reused as wm (16384 ushorts)
static constexpr size_t OPOS = OCNT + NN;
static constexpr size_t ORL  = OPOS + (size_t)EE;
static constexpr size_t OES  = ORL  + (size_t)EE;          // es bf16: EE*64 ushorts

// ---------------- weight pre-conversion (bf16, pre-swizzled; into dead deg/cnt space) ----------------
__global__ void k_wprep(const float* __restrict__ Wq, const float* __restrict__ Wk,
                        const float* __restrict__ Wv, const float* __restrict__ Wsk,
                        const float* __restrict__ W1, const float* __restrict__ W2,
                        ushort_t* __restrict__ wn, ushort_t* __restrict__ wm) {
    int i = blockIdx.x * 256 + threadIdx.x;   // 0..4095, grid 16
    if (i >= 4096) return;
    int k = i >> 6, nc = i & 63;
    int sidx = (nc * 64 + k) ^ ((nc & 7) << 3);
#pragma unroll
    for (int l = 0; l < 3; ++l) {
        wn[(size_t)(l * 4 + 0) * 4096 + sidx] = f2bf(Wq[l * 4096 + i]);
        wn[(size_t)(l * 4 + 1) * 4096 + sidx] = f2bf(Wk[l * 4096 + i]);
        wn[(size_t)(l * 4 + 2) * 4096 + sidx] = f2bf(Wv[l * 4096 + i]);
        wn[(size_t)(l * 4 + 3) * 4096 + sidx] = f2bf(Wsk[l * 4096 + i]);
    }
    float v1 = W1[i]; ushort_t h1 = f2bf(v1);
    wm[sidx]         = h1;
    wm[4096 + sidx]  = f2bf(v1 - bf2f(h1));
    float v2 = W2[i]; ushort_t h2 = f2bf(v2);
    wm[8192 + sidx]  = h2;
    wm[12288 + sidx] = f2bf(v2 - bf2f(h2));
}

// ---------------- rp: wave-per-8-edges, all gathers issued up-front ----------------
__global__ __launch_bounds__(256) void k_rp(const float* __restrict__ x,
                                            const int* __restrict__ ei,
                                            float* __restrict__ rp,
                                            double* __restrict__ partial) {
    int tid = threadIdx.x;
    int lane = tid & 63;
    int wid = tid >> 6;
    size_t wgid = (size_t)blockIdx.x * 4 + wid;
    size_t nw = (size_t)gridDim.x * 4;
    double c1 = 0.0, c2 = 0.0;
    for (size_t e0 = wgid * 8; e0 < (size_t)EE; e0 += nw * 8) {
        int rr = (lane < 8) ? ei[e0 + lane] : 0;
        int cc = (lane < 8) ? ei[EE + e0 + lane] : 0;
        int r[8], c[8];
#pragma unroll
        for (int j = 0; j < 8; ++j) { r[j] = __shfl(rr, j); c[j] = __shfl(cc, j); }
        float a[8], b[8];
#pragma unroll
        for (int j = 0; j < 8; ++j) {
            a[j] = x[(size_t)r[j] * 64 + lane];
            b[j] = x[(size_t)c[j] * 64 + lane];
        }
        float rvs = 0.f;
#pragma unroll
        for (int j = 0; j < 8; ++j) {
            float d = a[j] - b[j];
            float ss = d * d;
            ss += __shfl_xor(ss, 1);  ss += __shfl_xor(ss, 2);
            ss += __shfl_xor(ss, 4);  ss += __shfl_xor(ss, 8);
            ss += __shfl_xor(ss, 16); ss += __shfl_xor(ss, 32);
            float rv = sqrtf(ss);
            c1 += (double)rv; c2 += (double)rv * (double)rv;
            rvs = (lane == j) ? rv : rvs;
        }
        if (lane < 8) rp[e0 + lane] = rvs;
    }
    __shared__ double l1[4], l2[4];
    if (lane == 0) { l1[wid] = c1; l2[wid] = c2; }
    __syncthreads();
    if (tid == 0) {
        partial[blockIdx.x * 2]     = l1[0] + l1[1] + l1[2] + l1[3];
        partial[blockIdx.x * 2 + 1] = l2[0] + l2[1] + l2[2] + l2[3];
    }
}

__global__ __launch_bounds__(256) void k_statsf(const double* __restrict__ partial,
                                                float* __restrict__ statsf) {
    __shared__ double l1[256], l2[256];
    int tid = threadIdx.x;
    double a = 0.0, b = 0.0;
    for (int i = tid; i < NPART; i += 256) { a += partial[2 * i]; b += partial[2 * i + 1]; }
    l1[tid] = a; l2[tid] = b;
    __syncthreads();
    for (int o = 128; o > 0; o >>= 1) {
        if (tid < o) { l1[tid] += l1[tid + o]; l2[tid] += l2[tid + o]; }
        __syncthreads();
    }
    if (tid == 0) {
        double s = l1[0], q = l2[0];
        double mean = s / (double)EE;
        double var = (q - (double)EE * mean * mean) / (double)(EE - 1);
        if (var < 0) var = 0;
        statsf[0] = (float)mean;
        statsf[1] = (float)(1.0 / (sqrt(var) + 1e-6));
    }
}

// ---------------- edge-encoder MLP via MFMA (hi/lo bf16 split ~= fp32) ----------------
__device__ __forceinline__ short8 frag_rd(const ushort_t* __restrict__ s, int nc, int k0) {
    int sidx = (nc * 64 + k0) ^ ((nc & 7) << 3);
    return *reinterpret_cast<const short8*>(&s[sidx]);
}

__global__ __launch_bounds__(256) void k_mlp(const float* __restrict__ ea,
                                             const ushort_t* __restrict__ wm,
                                             const float* __restrict__ b1, const float* __restrict__ b2,
                                             const float* __restrict__ rp, const float* __restrict__ statsf,
                                             const int* __restrict__ pos,
                                             float* __restrict__ eout,
                                             ushort_t* __restrict__ es) {
    __shared__ __align__(16) ushort_t sW1h[4096], sW1l[4096], sW2h[4096], sW2l[4096];
    int tid = threadIdx.x;
    // straight pre-swizzled copy: 1024 us4 per 4096-ushort array
    for (int i = tid; i < 1024; i += 256) {
        reinterpret_cast<us4*>(sW1h)[i] = reinterpret_cast<const us4*>(wm)[i];
        reinterpret_cast<us4*>(sW1l)[i] = reinterpret_cast<const us4*>(wm + 4096)[i];
        reinterpret_cast<us4*>(sW2h)[i] = reinterpret_cast<const us4*>(wm + 8192)[i];
        reinterpret_cast<us4*>(sW2l)[i] = reinterpret_cast<const us4*>(wm + 12288)[i];
    }
    __syncthreads();

    int lane = tid & 63;
    int wid = tid >> 6;
    int col = lane & 15, kg = lane >> 4;
    int t = blockIdx.x * 4 + wid;
    bool act = t < NTILE;

    float hvals[4][4];
    if (act) {
        const float* ar = ea + (size_t)(t * 16 + col) * 64 + kg * 8;
        f32x4 f0 = *reinterpret_cast<const f32x4*>(ar);
        f32x4 f1 = *reinterpret_cast<const f32x4*>(ar + 4);
        f32x4 f2 = *reinterpret_cast<const f32x4*>(ar + 32);
        f32x4 f3 = *reinterpret_cast<const f32x4*>(ar + 36);
        short8 a0h, a0l, a1h, a1l;
#pragma unroll
        for (int j = 0; j < 4; ++j) {
            ushort_t h;
            h = f2bf(f0[j]); a0h[j]     = (short)h; a0l[j]     = (short)f2bf(f0[j] - bf2f(h));
            h = f2bf(f1[j]); a0h[4 + j] = (short)h; a0l[4 + j] = (short)f2bf(f1[j] - bf2f(h));
            h = f2bf(f2[j]); a1h[j]     = (short)h; a1l[j]     = (short)f2bf(f2[j] - bf2f(h));
            h = f2bf(f3[j]); a1h[4 + j] = (short)h; a1l[4 + j] = (short)f2bf(f3[j] - bf2f(h));
        }
#pragma unroll
        for (int n = 0; n < 4; ++n) {
            int nc = n * 16 + col;
            short8 b0h = frag_rd(sW1h, nc, kg * 8);
            short8 b0l = frag_rd(sW1l, nc, kg * 8);
            short8 b1h_ = frag_rd(sW1h, nc, 32 + kg * 8);
            short8 b1l_ = frag_rd(sW1l, nc, 32 + kg * 8);
            f32x4 acc = {0.f, 0.f, 0.f, 0.f};
            acc = __builtin_amdgcn_mfma_f32_16x16x32_bf16(a0h, b0h, acc, 0, 0, 0);
            acc = __builtin_amdgcn_mfma_f32_16x16x32_bf16(a0l, b0h, acc, 0, 0, 0);
            acc = __builtin_amdgcn_mfma_f32_16x16x32_bf16(a0h, b0l, acc, 0, 0, 0);
            acc = __builtin_amdgcn_mfma_f32_16x16x32_bf16(a1h, b1h_, acc, 0, 0, 0);
            acc = __builtin_amdgcn_mfma_f32_16x16x32_bf16(a1l, b1h_, acc, 0, 0, 0);
            acc = __builtin_amdgcn_mfma_f32_16x16x32_bf16(a1h, b1l_, acc, 0, 0, 0);
            float bb = b1[n * 16 + col];
#pragma unroll
            for (int r = 0; r < 4; ++r) hvals[n][r] = fmaxf(acc[r] + bb, 0.f);
        }
    }
    __syncthreads();   // all waves done reading W1 -> overlay H

    if (!act) return;
    ushort_t* myHh = sW1h + wid * 1024;
    ushort_t* myHl = sW1l + wid * 1024;
#pragma unroll
    for (int n = 0; n < 4; ++n) {
        int nc = n * 16 + col;
#pragma unroll
        for (int r = 0; r < 4; ++r) {
            float hv = hvals[n][r];
            ushort_t hh = f2bf(hv);
            int row = kg * 4 + r;
            int sidx = (row * 64 + nc) ^ ((row & 7) << 3);
            myHh[sidx] = hh;
            myHl[sidx] = f2bf(hv - bf2f(hh));
        }
    }
    short8 c0h = frag_rd(myHh, col, kg * 8);
    short8 c0l = frag_rd(myHl, col, kg * 8);
    short8 c1h = frag_rd(myHh, col, 32 + kg * 8);
    short8 c1l = frag_rd(myHl, col, 32 + kg * 8);

    float mean = statsf[0], inv = statsf[1];
    float rps[4];
    int posr[4];
#pragma unroll
    for (int r = 0; r < 4; ++r) {
        rps[r] = (rp[t * 16 + kg * 4 + r] - mean) * inv;
        posr[r] = pos[t * 16 + kg * 4 + r];
    }

    float vals[4][4];
#pragma unroll
    for (int n = 0; n < 4; ++n) {
        int nc = n * 16 + col;
        short8 b0h = frag_rd(sW2h, nc, kg * 8);
        short8 b0l = frag_rd(sW2l, nc, kg * 8);
        short8 b1h_ = frag_rd(sW2h, nc, 32 + kg * 8);
        short8 b1l_ = frag_rd(sW2l, nc, 32 + kg * 8);
        f32x4 acc = {0.f, 0.f, 0.f, 0.f};
        acc = __builtin_amdgcn_mfma_f32_16x16x32_bf16(c0h, b0h, acc, 0, 0, 0);
        acc = __builtin_amdgcn_mfma_f32_16x16x32_bf16(c0l, b0h, acc, 0, 0, 0);
        acc = __builtin_amdgcn_mfma_f32_16x16x32_bf16(c0h, b0l, acc, 0, 0, 0);
        acc = __builtin_amdgcn_mfma_f32_16x16x32_bf16(c1h, b1h_, acc, 0, 0, 0);
        acc = __builtin_amdgcn_mfma_f32_16x16x32_bf16(c1l, b1h_, acc, 0, 0, 0);
        acc = __builtin_amdgcn_mfma_f32_16x16x32_bf16(c1h, b1l_, acc, 0, 0, 0);
        float bb = b2[nc];
#pragma unroll
        for (int r = 0; r < 4; ++r) {
            float val = acc[r] + bb + rps[r];
            vals[n][r] = val;
            eout[(size_t)(t * 16 + kg * 4 + r) * 64 + nc] = val;
        }
    }
#pragma unroll
    for (int r = 0; r < 4; ++r) {
        us4 w;
        w[0] = f2bf(vals[0][r]); w[1] = f2bf(vals[1][r]);
        w[2] = f2bf(vals[2][r]); w[3] = f2bf(vals[3][r]);
        *reinterpret_cast<us4*>(es + (size_t)posr[r] * 64 + col * 4) = w;
    }
}

// ---------------- CSR build ----------------
__global__ void k_zint(int* deg, int* cnt) {
    int i = blockIdx.x * 256 + threadIdx.x;
    if (i < NN) { deg[i] = 0; cnt[i] = 0; }
}

__global__ void k_deg(const int* __restrict__ ei, int* __restrict__ deg) {
    int e = blockIdx.x * 256 + threadIdx.x;
    if (e < EE) atomicAdd(&deg[ei[EE + e]], 1);
}

__global__ __launch_bounds__(1024) void k_scan(const int* __restrict__ deg, int* __restrict__ off) {
    __shared__ int part[1024];
    int t = threadIdx.x;
    const int chunk = (NN + 1023) / 1024;
    int lo = t * chunk, hi = min(lo + chunk, NN);
    int s = 0;
    for (int i = lo; i < hi; ++i) s += deg[i];
    part[t] = s;
    __syncthreads();
    for (int o = 1; o < 1024; o <<= 1) {
        int v = (t >= o) ? part[t - o] : 0;
        __syncthreads();
        part[t] += v;
        __syncthreads();
    }
    int base = (t == 0) ? 0 : part[t - 1];
    for (int i = lo; i < hi; ++i) { off[i] = base; base += deg[i]; }
    if (t == 0) off[NN] = EE;
}

__global__ void k_scatter(const int* __restrict__ ei, const int* __restrict__ off,
                          int* __restrict__ cnt, int* __restrict__ pos, int* __restrict__ rlist) {
    int e = blockIdx.x * 256 + threadIdx.x;
    if (e >= EE) return;
    int r = ei[e], c = ei[EE + e];
    int p = off[c] + atomicAdd(&cnt[c], 1);
    pos[e] = p;
    rlist[p] = r;
}

// ---------------- node-side GEMMs via MFMA (bf16, pre-staged weights) ----------------
__global__ __launch_bounds__(256) void k_node(const float* __restrict__ xin,
                                              const ushort_t* __restrict__ wnl,
                                              const float* __restrict__ bq, const float* __restrict__ bk,
                                              const float* __restrict__ bv, const float* __restrict__ bsk,
                                              float* __restrict__ q, ushort_t* __restrict__ kvh,
                                              float* __restrict__ sk) {
    __shared__ __align__(16) ushort_t sW[4][4096];
    int tid = threadIdx.x;
    for (int i = tid; i < 1024; i += 256) {
        reinterpret_cast<us4*>(sW[0])[i] = reinterpret_cast<const us4*>(wnl)[i];
        reinterpret_cast<us4*>(sW[1])[i] = reinterpret_cast<const us4*>(wnl + 4096)[i];
        reinterpret_cast<us4*>(sW[2])[i] = reinterpret_cast<const us4*>(wnl + 8192)[i];
        reinterpret_cast<us4*>(sW[3])[i] = reinterpret_cast<const us4*>(wnl + 12288)[i];
    }
    __syncthreads();

    int lane = tid & 63;
    int wid = tid >> 6;
    int col = lane & 15, kg = lane >> 4;
    int t = blockIdx.x * 4 + wid;
    if (t >= NODETILE) return;

    const float* ar = xin + (size_t)(t * 16 + col) * 64 + kg * 8;
    f32x4 f0 = *reinterpret_cast<const f32x4*>(ar);
    f32x4 f1 = *reinterpret_cast<const f32x4*>(ar + 4);
    f32x4 f2 = *reinterpret_cast<const f32x4*>(ar + 32);
    f32x4 f3 = *reinterpret_cast<const f32x4*>(ar + 36);
    short8 a0, a1;
#pragma unroll
    for (int j = 0; j < 4; ++j) {
        a0[j] = (short)f2bf(f0[j]); a0[4 + j] = (short)f2bf(f1[j]);
        a1[j] = (short)f2bf(f2[j]); a1[4 + j] = (short)f2bf(f3[j]);
    }

    size_t nodebase = (size_t)t * 16 + kg * 4;

#pragma unroll
    for (int n = 0; n < 4; ++n) {       // q (fp32)
        int nc = n * 16 + col;
        short8 b0 = frag_rd(sW[0], nc, kg * 8);
        short8 b1 = frag_rd(sW[0], nc, 32 + kg * 8);
        f32x4 acc = {0.f, 0.f, 0.f, 0.f};
        acc = __builtin_amdgcn_mfma_f32_16x16x32_bf16(a0, b0, acc, 0, 0, 0);
        acc = __builtin_amdgcn_mfma_f32_16x16x32_bf16(a1, b1, acc, 0, 0, 0);
        float bb = bq[nc];
#pragma unroll
        for (int r = 0; r < 4; ++r) q[(nodebase + r) * 64 + nc] = acc[r] + bb;
    }
#pragma unroll
    for (int n = 0; n < 4; ++n) {       // k -> kvh even (bf16)
        int nc = n * 16 + col;
        short8 b0 = frag_rd(sW[1], nc, kg * 8);
        short8 b1 = frag_rd(sW[1], nc, 32 + kg * 8);
        f32x4 acc = {0.f, 0.f, 0.f, 0.f};
        acc = __builtin_amdgcn_mfma_f32_16x16x32_bf16(a0, b0, acc, 0, 0, 0);
        acc = __builtin_amdgcn_mfma_f32_16x16x32_bf16(a1, b1, acc, 0, 0, 0);
        float bb = bk[nc];
#pragma unroll
        for (int r = 0; r < 4; ++r) kvh[(nodebase + r) * 128 + nc * 2] = f2bf(acc[r] + bb);
    }
#pragma unroll
    for (int n = 0; n < 4; ++n) {       // v -> kvh odd (bf16)
        int nc = n * 16 + col;
        short8 b0 = frag_rd(sW[2], nc, kg * 8);
        short8 b1 = frag_rd(sW[2], nc, 32 + kg * 8);
        f32x4 acc = {0.f, 0.f, 0.f, 0.f};
        acc = __builtin_amdgcn_mfma_f32_16x16x32_bf16(a0, b0, acc, 0, 0, 0);
        acc = __builtin_amdgcn_mfma_f32_16x16x32_bf16(a1, b1, acc, 0, 0, 0);
        float bb = bv[nc];
#pragma unroll
        for (int r = 0; r < 4; ++r) kvh[(nodebase + r) * 128 + nc * 2 + 1] = f2bf(acc[r] + bb);
    }
#pragma unroll
    for (int n = 0; n < 4; ++n) {       // sk (fp32)
        int nc = n * 16 + col;
        short8 b0 = frag_rd(sW[3], nc, kg * 8);
        short8 b1 = frag_rd(sW[3], nc, 32 + kg * 8);
        f32x4 acc = {0.f, 0.f, 0.f, 0.f};
        acc = __builtin_amdgcn_mfma_f32_16x16x32_bf16(a0, b0, acc, 0, 0, 0);
        acc = __builtin_amdgcn_mfma_f32_16x16x32_bf16(a1, b1, acc, 0, 0, 0);
        float bb = bsk[nc];
#pragma unroll
        for (int r = 0; r < 4; ++r) sk[(nodebase + r) * 64 + nc] = acc[r] + bb;
    }
}

// ---------------- fused per-destination attention (all batches predicated, no serial tail) ----------------
__global__ __launch_bounds__(256) void k_edge(const int* __restrict__ off,
                                              const int* __restrict__ rlist,
                                              const ushort_t* __restrict__ es,
                                              const float* __restrict__ Wep,
                                              const float* __restrict__ q,
                                              const ushort_t* __restrict__ kvh,
                                              const float* __restrict__ skp,
                                              float* __restrict__ outb) {
    __shared__ float sWT[64 * 65];
    __shared__ float sA[4][264];
    int tid = threadIdx.x;
    for (int i = tid; i < 4096; i += 256) {
        int kr = i >> 6, kc = i & 63;
        sWT[kc * 65 + kr] = Wep[i];
    }
    __syncthreads();

    int lane = tid & 63;
    int wid = tid >> 6;
    int col = lane & 15, hs = lane >> 4, hb = lane & 48;
    size_t node = (size_t)blockIdx.x * 4 + wid;

    float qv = q[node * 64 + lane];
    float t0 = 0.f, t1 = 0.f, t2 = 0.f, t3 = 0.f;
#pragma unroll
    for (int d = 0; d < 16; ++d) {
        float qd = __shfl(qv, hb + d);
        const float* wp = sWT + (hb + d) * 65 + col;
        t0 = fmaf(wp[0],  qd, t0);
        t1 = fmaf(wp[16], qd, t1);
        t2 = fmaf(wp[32], qd, t2);
        t3 = fmaf(wp[48], qd, t3);
    }

    int p0 = __builtin_amdgcn_readfirstlane(off[node]);
    int p1 = __builtin_amdgcn_readfirstlane(off[node + 1]);
    float m = -INFINITY, s = 0.f, o = 0.f;
    float A0 = 0.f, A1 = 0.f, A2 = 0.f, A3 = 0.f;
    const float THR = 8.f;

    for (int p = p0; p < p1; p += 8) {
        int pj[8], rx[8];
#pragma unroll
        for (int j = 0; j < 8; ++j) {
            pj[j] = (p + j < p1) ? (p + j) : (p1 - 1);
            rx[j] = __builtin_amdgcn_readfirstlane(rlist[pj[j]]);
        }
        us4 ew[8];
        unsigned kvw[8];
#pragma unroll
        for (int j = 0; j < 8; ++j) {
            ew[j] = *reinterpret_cast<const us4*>(es + (size_t)pj[j] * 64 + col * 4);
            kvw[j] = *reinterpret_cast<const unsigned*>(kvh + (size_t)rx[j] * 128 + lane * 2);
        }
        float er0[8], er1[8], er2[8], er3[8], al[8], vv[8];
#pragma unroll
        for (int j = 0; j < 8; ++j) {
            er0[j] = bf2f(ew[j][0]); er1[j] = bf2f(ew[j][1]);
            er2[j] = bf2f(ew[j][2]); er3[j] = bf2f(ew[j][3]);
            float kva = bf2f((ushort_t)(kvw[j] & 0xffffu));
            vv[j] = bf2f((ushort_t)(kvw[j] >> 16));
            float d = qv * kva;
            d = fmaf(er0[j], t0, d); d = fmaf(er1[j], t1, d);
            d = fmaf(er2[j], t2, d); d = fmaf(er3[j], t3, d);
            d += __shfl_xor(d, 1); d += __shfl_xor(d, 2);
            d += __shfl_xor(d, 4); d += __shfl_xor(d, 8);
            al[j] = d * 0.25f;
        }
        float bm = fmaxf(fmaxf(fmaxf(al[0], al[1]), fmaxf(al[2], al[3])),
                         fmaxf(fmaxf(al[4], al[5]), fmaxf(al[6], al[7])));
        if (m == -INFINITY) m = bm;
        else if (bm > m + THR) {
            float sc = __expf(m - bm);
            s *= sc; o *= sc;
            A0 *= sc; A1 *= sc; A2 *= sc; A3 *= sc;
            m = bm;
        }
#pragma unroll
        for (int j = 0; j < 8; ++j) {
            float pe = (p + j < p1) ? __expf(al[j] - m) : 0.f;
            s += pe;
            o = fmaf(pe, vv[j], o);
            A0 = fmaf(pe, er0[j], A0);
            A1 = fmaf(pe, er1[j], A1);
            A2 = fmaf(pe, er2[j], A2);
            A3 = fmaf(pe, er3[j], A3);
        }
    }

    float* myA = sA[wid];
    myA[hs * 65 + col]      = A0;
    myA[hs * 65 + 16 + col] = A1;
    myA[hs * 65 + 32 + col] = A2;
    myA[hs * 65 + 48 + col] = A3;
    const float* Ah = myA + hs * 65;
    const float* wl = sWT + (size_t)lane * 65;
    float e0 = 0.f, e1 = 0.f, e2 = 0.f, e3 = 0.f;
#pragma unroll
    for (int kk = 0; kk < 64; kk += 4) {
        e0 = fmaf(Ah[kk],     wl[kk],     e0);
        e1 = fmaf(Ah[kk + 1], wl[kk + 1], e1);
        e2 = fmaf(Ah[kk + 2], wl[kk + 2], e2);
        e3 = fmaf(Ah[kk + 3], wl[kk + 3], e3);
    }
    float ex = (e0 + e1) + (e2 + e3);
    outb[node * 64 + lane] = (o + ex) / (s + 1e-16f) + skp[node * 64 + lane];
}

// ---------------- BN stats + BN/ReLU/residual/LN ----------------
__global__ void k_zbn(float* bn) {
    if (threadIdx.x < 128) bn[threadIdx.x] = 0.f;
}

__global__ __launch_bounds__(256) void k_bnstat(const float* __restrict__ conv, float* __restrict__ bn) {
    int tid = threadIdx.x;
    size_t idx0 = (size_t)blockIdx.x * 256 + tid;
    size_t stride = (size_t)gridDim.x * 256;
    float s = 0.f, ss = 0.f;
    for (size_t i = idx0; i < NF; i += stride) {
        float val = conv[i];
        s += val; ss += val * val;
    }
    __shared__ float l1[256], l2[256];
    l1[tid] = s; l2[tid] = ss;
    __syncthreads();
    if (tid < 64) {
        float a = l1[tid] + l1[tid + 64] + l1[tid + 128] + l1[tid + 192];
        float b = l2[tid] + l2[tid + 64] + l2[tid + 128] + l2[tid + 192];
        atomicAdd(bn + tid, a);
        atomicAdd(bn + 64 + tid, b);
    }
}

__global__ __launch_bounds__(256) void k_bnln(const float* __restrict__ conv,
                                              const float* __restrict__ xres,
                                              const float* __restrict__ bn,
                                              const float* __restrict__ g, const float* __restrict__ b,
                                              const float* __restrict__ lg, const float* __restrict__ lb,
                                              float* __restrict__ xout) {
    int tid = threadIdx.x;
    int lane = tid & 63;
    size_t row = (size_t)blockIdx.x * 4 + (tid >> 6);
    if (row >= (size_t)NN) return;
    float val = conv[row * 64 + lane];
    float mu = bn[lane] * (1.f / NN);
    float var = bn[64 + lane] * (1.f / NN) - mu * mu;
    float hn = (val - mu) * rsqrtf(var + 1e-5f) * g[lane] + b[lane];
    hn = fmaxf(hn, 0.f);
    float t = hn + xres[row * 64 + lane];
    float s = t, ss = t * t;
#pragma unroll
    for (int o = 32; o >= 1; o >>= 1) { s += __shfl_xor(s, o); ss += __shfl_xor(ss, o); }
    float mu2 = s * (1.f / 64.f);
    float var2 = ss * (1.f / 64.f) - mu2 * mu2;
    xout[row * 64 + lane] = (t - mu2) * rsqrtf(var2 + 1e-5f) * lg[lane] + lb[lane];
}

// ---------------- launch ----------------
extern "C" void kernel_launch(void* const* d_in, const int* in_sizes, int n_in,
                              void* d_out, int out_size, void* d_ws, size_t ws_size,
                              hipStream_t stream) {
    (void)in_sizes; (void)n_in; (void)out_size; (void)ws_size;
    const float* x   = (const float*)d_in[0];
    const int*   ei  = (const int*)d_in[1];
    const float* ea  = (const float*)d_in[2];
    const float* Wq  = (const float*)d_in[3];  const float* bq = (const float*)d_in[4];
    const float* Wk  = (const float*)d_in[5];  const float* bk = (const float*)d_in[6];
    const float* Wv  = (const float*)d_in[7];  const float* bv = (const float*)d_in[8];
    const float* We  = (const float*)d_in[9];
    const float* Wsk = (const float*)d_in[10]; const float* bsk = (const float*)d_in[11];
    const float* eW1 = (const float*)d_in[12]; const float* eb1 = (const float*)d_in[13];
    const float* eW2 = (const float*)d_in[14]; const float* eb2 = (const float*)d_in[15];
    const float* bng = (const float*)d_in[16]; const float* bnb = (const float*)d_in[17];
    const float* lng = (const float*)d_in[18]; const float* lnb = (const float*)d_in[19];

    float* ws = (float*)d_ws;
    float* out_x = (float*)d_out;
    float* out_e = out_x + NF;

    float* q    = ws + OQ;
    ushort_t* kvh = (ushort_t*)(ws + OKV);
    float* sk   = ws + OSK;
    float* bufA = ws + OBA;
    float* bufB = ws + OBB;
    float* rp   = ws + ORP;
    double* partial = (double*)(ws + OPART);
    float* statsf   = ws + OSTF;
    float* bn   = ws + OBN;
    int* deg  = (int*)(ws + ODEG);
    int* off  = (int*)(ws + OOFF);
    int* cnt  = (int*)(ws + OCNT);
    int* pos  = (int*)(ws + OPOS);
    int* rlist= (int*)(ws + ORL);
    ushort_t* es = (ushort_t*)(ws + OES);
    // wn/wm alias the dead deg/cnt regions (dead after k_scatter)
    ushort_t* wn = (ushort_t*)(ws + ODEG);   // 49152 ushorts <= NN ints
    ushort_t* wm = (ushort_t*)(ws + OCNT);   // 16384 ushorts <= NN ints

    // CSR build first (deg/cnt die after k_scatter)
    k_zint<<<(NN + 255) / 256, 256, 0, stream>>>(deg, cnt);
    k_deg<<<(EE + 255) / 256, 256, 0, stream>>>(ei, deg);
    k_scan<<<1, 1024, 0, stream>>>(deg, off);
    k_scatter<<<(EE + 255) / 256, 256, 0, stream>>>(ei, off, cnt, pos, rlist);

    // weight pre-conversion into the now-dead deg/cnt space
    k_wprep<<<16, 256, 0, stream>>>(Wq, Wk, Wv, Wsk, eW1, eW2, wn, wm);

    k_rp<<<NPART, 256, 0, stream>>>(x, ei, rp, partial);
    k_statsf<<<1, 256, 0, stream>>>(partial, statsf);
    k_mlp<<<(NTILE + 3) / 4, 256, 0, stream>>>(ea, wm, eb1, eb2, rp, statsf, pos, out_e, es);

    const float* xin = x;
    for (int l = 0; l < 3; ++l) {
        k_node<<<(NODETILE + 3) / 4, 256, 0, stream>>>(xin,
            wn + (size_t)l * 16384,
            bq + (size_t)l * 64, bk + (size_t)l * 64,
            bv + (size_t)l * 64, bsk + (size_t)l * 64,
            q, kvh, sk);
        float* conv = (l == 2) ? out_x : sk;   // in-place skip add (same-element RMW only)
        k_edge<<<NN / 4, 256, 0, stream>>>(off, rlist, es,
            We + (size_t)l * 4096, q, kvh, sk, conv);
        if (l < 2) {
            k_zbn<<<1, 128, 0, stream>>>(bn);
            k_bnstat<<<1024, 256, 0, stream>>>(conv, bn);
            float* xout = (l == 0) ? bufA : bufB;
            k_bnln<<<(NN + 3) / 4, 256, 0, stream>>>(conv, xin, bn,
                bng + (size_t)l * 64, bnb + (size_t)l * 64,
                lng + (size_t)l * 64, lnb + (size_t)l * 64, xout);
            xin = xout;
        }
    }
}

// Round 23
// 669.031 us; speedup vs baseline: 1.4926x; 1.0134x over previous
//
#include <hip/hip_runtime.h>
#include <cstdint>
#include <cstddef>

#define NN 50000
#define EE 500000
#define NPART 1024
#define NTILE 31250   // EE/16
#define NODETILE 3125 // NN/16

typedef unsigned short ushort_t;
typedef __attribute__((ext_vector_type(8))) short short8;
typedef __attribute__((ext_vector_type(4))) float f32x4;
typedef __attribute__((ext_vector_type(4))) unsigned short us4;

__device__ __forceinline__ ushort_t f2bf(float f) {
    unsigned u = __float_as_uint(f);
    unsigned r = (u + 0x7fffu + ((u >> 16) & 1u)) >> 16;
    return (ushort_t)r;
}
__device__ __forceinline__ float bf2f(ushort_t b) {
    return __uint_as_float(((unsigned)b) << 16);
}

// ---------------- workspace layout (float offsets; identical to round-20 footprint) ----------------
static constexpr size_t NF   = (size_t)NN * 64;
static constexpr size_t OQ   = 0;
static constexpr size_t OKV  = OQ   + NF;                  // kv bf16: NN*128 ushorts
static constexpr size_t OSK  = OKV  + 2 * NF;
static constexpr size_t OBA  = OSK  + NF;
static constexpr size_t OBB  = OBA  + NF;
static constexpr size_t ORP  = OBB  + NF;
static constexpr size_t OPART= ORP  + (size_t)EE;
static constexpr size_t OSTF = OPART+ 4096;
static constexpr size_t OBN  = OSTF + 2;
static constexpr size_t OI   = OBN  + 128;
static constexpr size_t ODEG = OI;                         // deg NN ints; DEAD after k_scan -> reused as wn
static constexpr size_t OOFF = ODEG + NN;
static constexpr size_t OCNT = OOFF + NN + 2;              // cnt NN ints; DEAD after k_scatter -> reused as wm
static constexpr size_t OPOS = OCNT + NN;
static constexpr size_t ORL  = OPOS + (size_t)EE;
static constexpr size_t OES  = ORL  + (size_t)EE;          // es bf16: EE*64 ushorts

// ---------------- weight pre-conversion (bf16, pre-swizzled; into dead deg/cnt space) ----------------
__global__ void k_wprep(const float* __restrict__ Wq, const float* __restrict__ Wk,
                        const float* __restrict__ Wv, const float* __restrict__ Wsk,
                        const float* __restrict__ W1, const float* __restrict__ W2,
                        ushort_t* __restrict__ wn, ushort_t* __restrict__ wm) {
    int i = blockIdx.x * 256 + threadIdx.x;   // 0..4095, grid 16
    if (i >= 4096) return;
    int k = i >> 6, nc = i & 63;
    int sidx = (nc * 64 + k) ^ ((nc & 7) << 3);
#pragma unroll
    for (int l = 0; l < 3; ++l) {
        wn[(size_t)(l * 4 + 0) * 4096 + sidx] = f2bf(Wq[l * 4096 + i]);
        wn[(size_t)(l * 4 + 1) * 4096 + sidx] = f2bf(Wk[l * 4096 + i]);
        wn[(size_t)(l * 4 + 2) * 4096 + sidx] = f2bf(Wv[l * 4096 + i]);
        wn[(size_t)(l * 4 + 3) * 4096 + sidx] = f2bf(Wsk[l * 4096 + i]);
    }
    float v1 = W1[i]; ushort_t h1 = f2bf(v1);
    wm[sidx]         = h1;
    wm[4096 + sidx]  = f2bf(v1 - bf2f(h1));
    float v2 = W2[i]; ushort_t h2 = f2bf(v2);
    wm[8192 + sidx]  = h2;
    wm[12288 + sidx] = f2bf(v2 - bf2f(h2));   // written but unused (W2-lo dropped in k_mlp)
}

// ---------------- rp: wave-per-8-edges, all gathers issued up-front ----------------
__global__ __launch_bounds__(256) void k_rp(const float* __restrict__ x,
                                            const int* __restrict__ ei,
                                            float* __restrict__ rp,
                                            double* __restrict__ partial) {
    int tid = threadIdx.x;
    int lane = tid & 63;
    int wid = tid >> 6;
    size_t wgid = (size_t)blockIdx.x * 4 + wid;
    size_t nw = (size_t)gridDim.x * 4;
    double c1 = 0.0, c2 = 0.0;
    for (size_t e0 = wgid * 8; e0 < (size_t)EE; e0 += nw * 8) {
        int rr = (lane < 8) ? ei[e0 + lane] : 0;
        int cc = (lane < 8) ? ei[EE + e0 + lane] : 0;
        int r[8], c[8];
#pragma unroll
        for (int j = 0; j < 8; ++j) { r[j] = __shfl(rr, j); c[j] = __shfl(cc, j); }
        float a[8], b[8];
#pragma unroll
        for (int j = 0; j < 8; ++j) {
            a[j] = x[(size_t)r[j] * 64 + lane];
            b[j] = x[(size_t)c[j] * 64 + lane];
        }
        float rvs = 0.f;
#pragma unroll
        for (int j = 0; j < 8; ++j) {
            float d = a[j] - b[j];
            float ss = d * d;
            ss += __shfl_xor(ss, 1);  ss += __shfl_xor(ss, 2);
            ss += __shfl_xor(ss, 4);  ss += __shfl_xor(ss, 8);
            ss += __shfl_xor(ss, 16); ss += __shfl_xor(ss, 32);
            float rv = sqrtf(ss);
            c1 += (double)rv; c2 += (double)rv * (double)rv;
            rvs = (lane == j) ? rv : rvs;
        }
        if (lane < 8) rp[e0 + lane] = rvs;
    }
    __shared__ double l1[4], l2[4];
    if (lane == 0) { l1[wid] = c1; l2[wid] = c2; }
    __syncthreads();
    if (tid == 0) {
        partial[blockIdx.x * 2]     = l1[0] + l1[1] + l1[2] + l1[3];
        partial[blockIdx.x * 2 + 1] = l2[0] + l2[1] + l2[2] + l2[3];
    }
}

__global__ __launch_bounds__(256) void k_statsf(const double* __restrict__ partial,
                                                float* __restrict__ statsf) {
    __shared__ double l1[256], l2[256];
    int tid = threadIdx.x;
    double a = 0.0, b = 0.0;
    for (int i = tid; i < NPART; i += 256) { a += partial[2 * i]; b += partial[2 * i + 1]; }
    l1[tid] = a; l2[tid] = b;
    __syncthreads();
    for (int o = 128; o > 0; o >>= 1) {
        if (tid < o) { l1[tid] += l1[tid + o]; l2[tid] += l2[tid + o]; }
        __syncthreads();
    }
    if (tid == 0) {
        double s = l1[0], q = l2[0];
        double mean = s / (double)EE;
        double var = (q - (double)EE * mean * mean) / (double)(EE - 1);
        if (var < 0) var = 0;
        statsf[0] = (float)mean;
        statsf[1] = (float)(1.0 / (sqrt(var) + 1e-6));
    }
}

// ---------------- edge-encoder MLP via MFMA (A/W1 hi/lo; W2 bf16-only; 24 KB LDS) ----------------
__device__ __forceinline__ short8 frag_rd(const ushort_t* __restrict__ s, int nc, int k0) {
    int sidx = (nc * 64 + k0) ^ ((nc & 7) << 3);
    return *reinterpret_cast<const short8*>(&s[sidx]);
}

__global__ __launch_bounds__(256) void k_mlp(const float* __restrict__ ea,
                                             const ushort_t* __restrict__ wm,
                                             const float* __restrict__ b1, const float* __restrict__ b2,
                                             const float* __restrict__ rp, const float* __restrict__ statsf,
                                             const int* __restrict__ pos,
                                             float* __restrict__ eout,
                                             ushort_t* __restrict__ es) {
    __shared__ __align__(16) ushort_t sW1h[4096], sW1l[4096], sW2h[4096];
    int tid = threadIdx.x;
    // straight pre-swizzled copy: 1024 us4 per 4096-ushort array
    for (int i = tid; i < 1024; i += 256) {
        reinterpret_cast<us4*>(sW1h)[i] = reinterpret_cast<const us4*>(wm)[i];
        reinterpret_cast<us4*>(sW1l)[i] = reinterpret_cast<const us4*>(wm + 4096)[i];
        reinterpret_cast<us4*>(sW2h)[i] = reinterpret_cast<const us4*>(wm + 8192)[i];
    }
    __syncthreads();

    int lane = tid & 63;
    int wid = tid >> 6;
    int col = lane & 15, kg = lane >> 4;
    int t = blockIdx.x * 4 + wid;
    bool act = t < NTILE;

    float hvals[4][4];
    if (act) {
        const float* ar = ea + (size_t)(t * 16 + col) * 64 + kg * 8;
        f32x4 f0 = *reinterpret_cast<const f32x4*>(ar);
        f32x4 f1 = *reinterpret_cast<const f32x4*>(ar + 4);
        f32x4 f2 = *reinterpret_cast<const f32x4*>(ar + 32);
        f32x4 f3 = *reinterpret_cast<const f32x4*>(ar + 36);
        short8 a0h, a0l, a1h, a1l;
#pragma unroll
        for (int j = 0; j < 4; ++j) {
            ushort_t h;
            h = f2bf(f0[j]); a0h[j]     = (short)h; a0l[j]     = (short)f2bf(f0[j] - bf2f(h));
            h = f2bf(f1[j]); a0h[4 + j] = (short)h; a0l[4 + j] = (short)f2bf(f1[j] - bf2f(h));
            h = f2bf(f2[j]); a1h[j]     = (short)h; a1l[j]     = (short)f2bf(f2[j] - bf2f(h));
            h = f2bf(f3[j]); a1h[4 + j] = (short)h; a1l[4 + j] = (short)f2bf(f3[j] - bf2f(h));
        }
#pragma unroll
        for (int n = 0; n < 4; ++n) {
            int nc = n * 16 + col;
            short8 b0h = frag_rd(sW1h, nc, kg * 8);
            short8 b0l = frag_rd(sW1l, nc, kg * 8);
            short8 b1h_ = frag_rd(sW1h, nc, 32 + kg * 8);
            short8 b1l_ = frag_rd(sW1l, nc, 32 + kg * 8);
            f32x4 acc = {0.f, 0.f, 0.f, 0.f};
            acc = __builtin_amdgcn_mfma_f32_16x16x32_bf16(a0h, b0h, acc, 0, 0, 0);
            acc = __builtin_amdgcn_mfma_f32_16x16x32_bf16(a0l, b0h, acc, 0, 0, 0);
            acc = __builtin_amdgcn_mfma_f32_16x16x32_bf16(a0h, b0l, acc, 0, 0, 0);
            acc = __builtin_amdgcn_mfma_f32_16x16x32_bf16(a1h, b1h_, acc, 0, 0, 0);
            acc = __builtin_amdgcn_mfma_f32_16x16x32_bf16(a1l, b1h_, acc, 0, 0, 0);
            acc = __builtin_amdgcn_mfma_f32_16x16x32_bf16(a1h, b1l_, acc, 0, 0, 0);
            float bb = b1[n * 16 + col];
#pragma unroll
            for (int r = 0; r < 4; ++r) hvals[n][r] = fmaxf(acc[r] + bb, 0.f);
        }
    }
    __syncthreads();   // all waves done reading W1 -> overlay H

    if (!act) return;
    ushort_t* myHh = sW1h + wid * 1024;
    ushort_t* myHl = sW1l + wid * 1024;
#pragma unroll
    for (int n = 0; n < 4; ++n) {
        int nc = n * 16 + col;
#pragma unroll
        for (int r = 0; r < 4; ++r) {
            float hv = hvals[n][r];
            ushort_t hh = f2bf(hv);
            int row = kg * 4 + r;
            int sidx = (row * 64 + nc) ^ ((row & 7) << 3);
            myHh[sidx] = hh;
            myHl[sidx] = f2bf(hv - bf2f(hh));
        }
    }
    // same-wave LDS write->read (lgkmcnt orders; own region only)
    short8 c0h = frag_rd(myHh, col, kg * 8);
    short8 c0l = frag_rd(myHl, col, kg * 8);
    short8 c1h = frag_rd(myHh, col, 32 + kg * 8);
    short8 c1l = frag_rd(myHl, col, 32 + kg * 8);

    float mean = statsf[0], inv = statsf[1];
    float rps[4];
    int posr[4];
#pragma unroll
    for (int r = 0; r < 4; ++r) {
        rps[r] = (rp[t * 16 + kg * 4 + r] - mean) * inv;
        posr[r] = pos[t * 16 + kg * 4 + r];
    }

    float vals[4][4];
#pragma unroll
    for (int n = 0; n < 4; ++n) {
        int nc = n * 16 + col;
        short8 b0h = frag_rd(sW2h, nc, kg * 8);
        short8 b1h_ = frag_rd(sW2h, nc, 32 + kg * 8);
        f32x4 acc = {0.f, 0.f, 0.f, 0.f};
        acc = __builtin_amdgcn_mfma_f32_16x16x32_bf16(c0h, b0h, acc, 0, 0, 0);
        acc = __builtin_amdgcn_mfma_f32_16x16x32_bf16(c0l, b0h, acc, 0, 0, 0);
        acc = __builtin_amdgcn_mfma_f32_16x16x32_bf16(c1h, b1h_, acc, 0, 0, 0);
        acc = __builtin_amdgcn_mfma_f32_16x16x32_bf16(c1l, b1h_, acc, 0, 0, 0);
        float bb = b2[nc];
#pragma unroll
        for (int r = 0; r < 4; ++r) {
            float val = acc[r] + bb + rps[r];
            vals[n][r] = val;
            eout[(size_t)(t * 16 + kg * 4 + r) * 64 + nc] = val;
        }
    }
#pragma unroll
    for (int r = 0; r < 4; ++r) {
        us4 w;
        w[0] = f2bf(vals[0][r]); w[1] = f2bf(vals[1][r]);
        w[2] = f2bf(vals[2][r]); w[3] = f2bf(vals[3][r]);
        *reinterpret_cast<us4*>(es + (size_t)posr[r] * 64 + col * 4) = w;
    }
}

// ---------------- CSR build ----------------
__global__ void k_zint(int* deg, int* cnt) {
    int i = blockIdx.x * 256 + threadIdx.x;
    if (i < NN) { deg[i] = 0; cnt[i] = 0; }
}

__global__ void k_deg(const int* __restrict__ ei, int* __restrict__ deg) {
    int e = blockIdx.x * 256 + threadIdx.x;
    if (e < EE) atomicAdd(&deg[ei[EE + e]], 1);
}

__global__ __launch_bounds__(1024) void k_scan(const int* __restrict__ deg, int* __restrict__ off) {
    __shared__ int part[1024];
    int t = threadIdx.x;
    const int chunk = (NN + 1023) / 1024;
    int lo = t * chunk, hi = min(lo + chunk, NN);
    int s = 0;
    for (int i = lo; i < hi; ++i) s += deg[i];
    part[t] = s;
    __syncthreads();
    for (int o = 1; o < 1024; o <<= 1) {
        int v = (t >= o) ? part[t - o] : 0;
        __syncthreads();
        part[t] += v;
        __syncthreads();
    }
    int base = (t == 0) ? 0 : part[t - 1];
    for (int i = lo; i < hi; ++i) { off[i] = base; base += deg[i]; }
    if (t == 0) off[NN] = EE;
}

__global__ void k_scatter(const int* __restrict__ ei, const int* __restrict__ off,
                          int* __restrict__ cnt, int* __restrict__ pos, int* __restrict__ rlist) {
    int e = blockIdx.x * 256 + threadIdx.x;
    if (e >= EE) return;
    int r = ei[e], c = ei[EE + e];
    int p = off[c] + atomicAdd(&cnt[c], 1);
    pos[e] = p;
    rlist[p] = r;
}

// ---------------- node-side GEMMs via MFMA (bf16, pre-staged weights) ----------------
__global__ __launch_bounds__(256) void k_node(const float* __restrict__ xin,
                                              const ushort_t* __restrict__ wnl,
                                              const float* __restrict__ bq, const float* __restrict__ bk,
                                              const float* __restrict__ bv, const float* __restrict__ bsk,
                                              float* __restrict__ q, ushort_t* __restrict__ kvh,
                                              float* __restrict__ sk) {
    __shared__ __align__(16) ushort_t sW[4][4096];
    int tid = threadIdx.x;
    for (int i = tid; i < 1024; i += 256) {
        reinterpret_cast<us4*>(sW[0])[i] = reinterpret_cast<const us4*>(wnl)[i];
        reinterpret_cast<us4*>(sW[1])[i] = reinterpret_cast<const us4*>(wnl + 4096)[i];
        reinterpret_cast<us4*>(sW[2])[i] = reinterpret_cast<const us4*>(wnl + 8192)[i];
        reinterpret_cast<us4*>(sW[3])[i] = reinterpret_cast<const us4*>(wnl + 12288)[i];
    }
    __syncthreads();

    int lane = tid & 63;
    int wid = tid >> 6;
    int col = lane & 15, kg = lane >> 4;
    int t = blockIdx.x * 4 + wid;
    if (t >= NODETILE) return;

    const float* ar = xin + (size_t)(t * 16 + col) * 64 + kg * 8;
    f32x4 f0 = *reinterpret_cast<const f32x4*>(ar);
    f32x4 f1 = *reinterpret_cast<const f32x4*>(ar + 4);
    f32x4 f2 = *reinterpret_cast<const f32x4*>(ar + 32);
    f32x4 f3 = *reinterpret_cast<const f32x4*>(ar + 36);
    short8 a0, a1;
#pragma unroll
    for (int j = 0; j < 4; ++j) {
        a0[j] = (short)f2bf(f0[j]); a0[4 + j] = (short)f2bf(f1[j]);
        a1[j] = (short)f2bf(f2[j]); a1[4 + j] = (short)f2bf(f3[j]);
    }

    size_t nodebase = (size_t)t * 16 + kg * 4;

#pragma unroll
    for (int n = 0; n < 4; ++n) {       // q (fp32)
        int nc = n * 16 + col;
        short8 b0 = frag_rd(sW[0], nc, kg * 8);
        short8 b1 = frag_rd(sW[0], nc, 32 + kg * 8);
        f32x4 acc = {0.f, 0.f, 0.f, 0.f};
        acc = __builtin_amdgcn_mfma_f32_16x16x32_bf16(a0, b0, acc, 0, 0, 0);
        acc = __builtin_amdgcn_mfma_f32_16x16x32_bf16(a1, b1, acc, 0, 0, 0);
        float bb = bq[nc];
#pragma unroll
        for (int r = 0; r < 4; ++r) q[(nodebase + r) * 64 + nc] = acc[r] + bb;
    }
#pragma unroll
    for (int n = 0; n < 4; ++n) {       // k -> kvh even (bf16)
        int nc = n * 16 + col;
        short8 b0 = frag_rd(sW[1], nc, kg * 8);
        short8 b1 = frag_rd(sW[1], nc, 32 + kg * 8);
        f32x4 acc = {0.f, 0.f, 0.f, 0.f};
        acc = __builtin_amdgcn_mfma_f32_16x16x32_bf16(a0, b0, acc, 0, 0, 0);
        acc = __builtin_amdgcn_mfma_f32_16x16x32_bf16(a1, b1, acc, 0, 0, 0);
        float bb = bk[nc];
#pragma unroll
        for (int r = 0; r < 4; ++r) kvh[(nodebase + r) * 128 + nc * 2] = f2bf(acc[r] + bb);
    }
#pragma unroll
    for (int n = 0; n < 4; ++n) {       // v -> kvh odd (bf16)
        int nc = n * 16 + col;
        short8 b0 = frag_rd(sW[2], nc, kg * 8);
        short8 b1 = frag_rd(sW[2], nc, 32 + kg * 8);
        f32x4 acc = {0.f, 0.f, 0.f, 0.f};
        acc = __builtin_amdgcn_mfma_f32_16x16x32_bf16(a0, b0, acc, 0, 0, 0);
        acc = __builtin_amdgcn_mfma_f32_16x16x32_bf16(a1, b1, acc, 0, 0, 0);
        float bb = bv[nc];
#pragma unroll
        for (int r = 0; r < 4; ++r) kvh[(nodebase + r) * 128 + nc * 2 + 1] = f2bf(acc[r] + bb);
    }
#pragma unroll
    for (int n = 0; n < 4; ++n) {       // sk (fp32)
        int nc = n * 16 + col;
        short8 b0 = frag_rd(sW[3], nc, kg * 8);
        short8 b1 = frag_rd(sW[3], nc, 32 + kg * 8);
        f32x4 acc = {0.f, 0.f, 0.f, 0.f};
        acc = __builtin_amdgcn_mfma_f32_16x16x32_bf16(a0, b0, acc, 0, 0, 0);
        acc = __builtin_amdgcn_mfma_f32_16x16x32_bf16(a1, b1, acc, 0, 0, 0);
        float bb = bsk[nc];
#pragma unroll
        for (int r = 0; r < 4; ++r) sk[(nodebase + r) * 64 + nc] = acc[r] + bb;
    }
}

// ---------------- fused per-destination attention (all batches predicated, no serial tail) ----------------
__global__ __launch_bounds__(256) void k_edge(const int* __restrict__ off,
                                              const int* __restrict__ rlist,
                                              const ushort_t* __restrict__ es,
                                              const float* __restrict__ Wep,
                                              const float* __restrict__ q,
                                              const ushort_t* __restrict__ kvh,
                                              const float* __restrict__ skp,
                                              float* __restrict__ outb) {
    __shared__ float sWT[64 * 65];
    __shared__ float sA[4][264];
    int tid = threadIdx.x;
    for (int i = tid; i < 4096; i += 256) {
        int kr = i >> 6, kc = i & 63;
        sWT[kc * 65 + kr] = Wep[i];
    }
    __syncthreads();

    int lane = tid & 63;
    int wid = tid >> 6;
    int col = lane & 15, hs = lane >> 4, hb = lane & 48;
    size_t node = (size_t)blockIdx.x * 4 + wid;

    float qv = q[node * 64 + lane];
    float t0 = 0.f, t1 = 0.f, t2 = 0.f, t3 = 0.f;
#pragma unroll
    for (int d = 0; d < 16; ++d) {
        float qd = __shfl(qv, hb + d);
        const float* wp = sWT + (hb + d) * 65 + col;
        t0 = fmaf(wp[0],  qd, t0);
        t1 = fmaf(wp[16], qd, t1);
        t2 = fmaf(wp[32], qd, t2);
        t3 = fmaf(wp[48], qd, t3);
    }

    int p0 = __builtin_amdgcn_readfirstlane(off[node]);
    int p1 = __builtin_amdgcn_readfirstlane(off[node + 1]);
    float m = -INFINITY, s = 0.f, o = 0.f;
    float A0 = 0.f, A1 = 0.f, A2 = 0.f, A3 = 0.f;
    const float THR = 8.f;

    for (int p = p0; p < p1; p += 8) {
        int pj[8], rx[8];
#pragma unroll
        for (int j = 0; j < 8; ++j) {
            pj[j] = (p + j < p1) ? (p + j) : (p1 - 1);
            rx[j] = __builtin_amdgcn_readfirstlane(rlist[pj[j]]);
        }
        us4 ew[8];
        unsigned kvw[8];
#pragma unroll
        for (int j = 0; j < 8; ++j) {
            ew[j] = *reinterpret_cast<const us4*>(es + (size_t)pj[j] * 64 + col * 4);
            kvw[j] = *reinterpret_cast<const unsigned*>(kvh + (size_t)rx[j] * 128 + lane * 2);
        }
        float er0[8], er1[8], er2[8], er3[8], al[8], vv[8];
#pragma unroll
        for (int j = 0; j < 8; ++j) {
            er0[j] = bf2f(ew[j][0]); er1[j] = bf2f(ew[j][1]);
            er2[j] = bf2f(ew[j][2]); er3[j] = bf2f(ew[j][3]);
            float kva = bf2f((ushort_t)(kvw[j] & 0xffffu));
            vv[j] = bf2f((ushort_t)(kvw[j] >> 16));
            float d = qv * kva;
            d = fmaf(er0[j], t0, d); d = fmaf(er1[j], t1, d);
            d = fmaf(er2[j], t2, d); d = fmaf(er3[j], t3, d);
            d += __shfl_xor(d, 1); d += __shfl_xor(d, 2);
            d += __shfl_xor(d, 4); d += __shfl_xor(d, 8);
            al[j] = d * 0.25f;
        }
        float bm = fmaxf(fmaxf(fmaxf(al[0], al[1]), fmaxf(al[2], al[3])),
                         fmaxf(fmaxf(al[4], al[5]), fmaxf(al[6], al[7])));
        if (m == -INFINITY) m = bm;
        else if (bm > m + THR) {
            float sc = __expf(m - bm);
            s *= sc; o *= sc;
            A0 *= sc; A1 *= sc; A2 *= sc; A3 *= sc;
            m = bm;
        }
#pragma unroll
        for (int j = 0; j < 8; ++j) {
            float pe = (p + j < p1) ? __expf(al[j] - m) : 0.f;
            s += pe;
            o = fmaf(pe, vv[j], o);
            A0 = fmaf(pe, er0[j], A0);
            A1 = fmaf(pe, er1[j], A1);
            A2 = fmaf(pe, er2[j], A2);
            A3 = fmaf(pe, er3[j], A3);
        }
    }

    float* myA = sA[wid];
    myA[hs * 65 + col]      = A0;
    myA[hs * 65 + 16 + col] = A1;
    myA[hs * 65 + 32 + col] = A2;
    myA[hs * 65 + 48 + col] = A3;
    const float* Ah = myA + hs * 65;
    const float* wl = sWT + (size_t)lane * 65;
    float e0 = 0.f, e1 = 0.f, e2 = 0.f, e3 = 0.f;
#pragma unroll
    for (int kk = 0; kk < 64; kk += 4) {
        e0 = fmaf(Ah[kk],     wl[kk],     e0);
        e1 = fmaf(Ah[kk + 1], wl[kk + 1], e1);
        e2 = fmaf(Ah[kk + 2], wl[kk + 2], e2);
        e3 = fmaf(Ah[kk + 3], wl[kk + 3], e3);
    }
    float ex = (e0 + e1) + (e2 + e3);
    outb[node * 64 + lane] = (o + ex) / (s + 1e-16f) + skp[node * 64 + lane];
}

// ---------------- BN stats + BN/ReLU/residual/LN ----------------
__global__ void k_zbn(float* bn) {
    if (threadIdx.x < 128) bn[threadIdx.x] = 0.f;
}

__global__ __launch_bounds__(256) void k_bnstat(const float* __restrict__ conv, float* __restrict__ bn) {
    int tid = threadIdx.x;
    size_t idx0 = (size_t)blockIdx.x * 256 + tid;
    size_t stride = (size_t)gridDim.x * 256;
    float s = 0.f, ss = 0.f;
    for (size_t i = idx0; i < NF; i += stride) {
        float val = conv[i];
        s += val; ss += val * val;
    }
    __shared__ float l1[256], l2[256];
    l1[tid] = s; l2[tid] = ss;
    __syncthreads();
    if (tid < 64) {
        float a = l1[tid] + l1[tid + 64] + l1[tid + 128] + l1[tid + 192];
        float b = l2[tid] + l2[tid + 64] + l2[tid + 128] + l2[tid + 192];
        atomicAdd(bn + tid, a);
        atomicAdd(bn + 64 + tid, b);
    }
}

__global__ __launch_bounds__(256) void k_bnln(const float* __restrict__ conv,
                                              const float* __restrict__ xres,
                                              const float* __restrict__ bn,
                                              const float* __restrict__ g, const float* __restrict__ b,
                                              const float* __restrict__ lg, const float* __restrict__ lb,
                                              float* __restrict__ xout) {
    int tid = threadIdx.x;
    int lane = tid & 63;
    size_t row = (size_t)blockIdx.x * 4 + (tid >> 6);
    if (row >= (size_t)NN) return;
    float val = conv[row * 64 + lane];
    float mu = bn[lane] * (1.f / NN);
    float var = bn[64 + lane] * (1.f / NN) - mu * mu;
    float hn = (val - mu) * rsqrtf(var + 1e-5f) * g[lane] + b[lane];
    hn = fmaxf(hn, 0.f);
    float t = hn + xres[row * 64 + lane];
    float s = t, ss = t * t;
#pragma unroll
    for (int o = 32; o >= 1; o >>= 1) { s += __shfl_xor(s, o); ss += __shfl_xor(ss, o); }
    float mu2 = s * (1.f / 64.f);
    float var2 = ss * (1.f / 64.f) - mu2 * mu2;
    xout[row * 64 + lane] = (t - mu2) * rsqrtf(var2 + 1e-5f) * lg[lane] + lb[lane];
}

// ---------------- launch ----------------
extern "C" void kernel_launch(void* const* d_in, const int* in_sizes, int n_in,
                              void* d_out, int out_size, void* d_ws, size_t ws_size,
                              hipStream_t stream) {
    (void)in_sizes; (void)n_in; (void)out_size; (void)ws_size;
    const float* x   = (const float*)d_in[0];
    const int*   ei  = (const int*)d_in[1];
    const float* ea  = (const float*)d_in[2];
    const float* Wq  = (const float*)d_in[3];  const float* bq = (const float*)d_in[4];
    const float* Wk  = (const float*)d_in[5];  const float* bk = (const float*)d_in[6];
    const float* Wv  = (const float*)d_in[7];  const float* bv = (const float*)d_in[8];
    const float* We  = (const float*)d_in[9];
    const float* Wsk = (const float*)d_in[10]; const float* bsk = (const float*)d_in[11];
    const float* eW1 = (const float*)d_in[12]; const float* eb1 = (const float*)d_in[13];
    const float* eW2 = (const float*)d_in[14]; const float* eb2 = (const float*)d_in[15];
    const float* bng = (const float*)d_in[16]; const float* bnb = (const float*)d_in[17];
    const float* lng = (const float*)d_in[18]; const float* lnb = (const float*)d_in[19];

    float* ws = (float*)d_ws;
    float* out_x = (float*)d_out;
    float* out_e = out_x + NF;

    float* q    = ws + OQ;
    ushort_t* kvh = (ushort_t*)(ws + OKV);
    float* sk   = ws + OSK;
    float* bufA = ws + OBA;
    float* bufB = ws + OBB;
    float* rp   = ws + ORP;
    double* partial = (double*)(ws + OPART);
    float* statsf   = ws + OSTF;
    float* bn   = ws + OBN;
    int* deg  = (int*)(ws + ODEG);
    int* off  = (int*)(ws + OOFF);
    int* cnt  = (int*)(ws + OCNT);
    int* pos  = (int*)(ws + OPOS);
    int* rlist= (int*)(ws + ORL);
    ushort_t* es = (ushort_t*)(ws + OES);
    // wn/wm alias the dead deg/cnt regions (dead after k_scatter)
    ushort_t* wn = (ushort_t*)(ws + ODEG);   // 49152 ushorts <= NN ints
    ushort_t* wm = (ushort_t*)(ws + OCNT);   // 16384 ushorts <= NN ints

    // CSR build first (deg/cnt die after k_scatter)
    k_zint<<<(NN + 255) / 256, 256, 0, stream>>>(deg, cnt);
    k_deg<<<(EE + 255) / 256, 256, 0, stream>>>(ei, deg);
    k_scan<<<1, 1024, 0, stream>>>(deg, off);
    k_scatter<<<(EE + 255) / 256, 256, 0, stream>>>(ei, off, cnt, pos, rlist);

    // weight pre-conversion into the now-dead deg/cnt space
    k_wprep<<<16, 256, 0, stream>>>(Wq, Wk, Wv, Wsk, eW1, eW2, wn, wm);

    k_rp<<<NPART, 256, 0, stream>>>(x, ei, rp, partial);
    k_statsf<<<1, 256, 0, stream>>>(partial, statsf);
    k_mlp<<<(NTILE + 3) / 4, 256, 0, stream>>>(ea, wm, eb1, eb2, rp, statsf, pos, out_e, es);

    const float* xin = x;
    for (int l = 0; l < 3; ++l) {
        k_node<<<(NODETILE + 3) / 4, 256, 0, stream>>>(xin,
            wn + (size_t)l * 16384,
            bq + (size_t)l * 64, bk + (size_t)l * 64,
            bv + (size_t)l * 64, bsk + (size_t)l * 64,
            q, kvh, sk);
        float* conv = (l == 2) ? out_x : sk;   // in-place skip add (same-element RMW only)
        k_edge<<<NN / 4, 256, 0, stream>>>(off, rlist, es,
            We + (size_t)l * 4096, q, kvh, sk, conv);
        if (l < 2) {
            k_zbn<<<1, 128, 0, stream>>>(bn);
            k_bnstat<<<1024, 256, 0, stream>>>(conv, bn);
            float* xout = (l == 0) ? bufA : bufB;
            k_bnln<<<(NN + 3) / 4, 256, 0, stream>>>(conv, xin, bn,
                bng + (size_t)l * 64, bnb + (size_t)l * 64,
                lng + (size_t)l * 64, lnb + (size_t)l * 64, xout);
            xin = xout;
        }
    }
}